// Round 2
// baseline (1323.324 us; speedup 1.0000x reference)
//
#include <hip/hip_runtime.h>
#include <hip/hip_cooperative_groups.h>

namespace cg = cooperative_groups;

#define RC 130816   // 511*256
#define MT 512      // matT m-stride (511 zero-padded)

// bf16 weight cache layout (ushort offsets)
#define B16_FH   196608   // after 768*256 iou rows
#define B16_W1   262144   // 256*256 (W_attnh[:, :256])

#define SMEM_BYTES 25600  // max stage footprint: cd1<4> = 25600 B

__device__ __forceinline__ float rcpf(float x){ return __builtin_amdgcn_rcpf(x); }
__device__ __forceinline__ float sigmf(float x){ return rcpf(1.f + __expf(-x)); }
__device__ __forceinline__ float tanhfast(float x){
  return 1.f - 2.f*rcpf(1.f + __expf(2.f*x));
}

// ---- bf16-as-integer helpers ----
__device__ __forceinline__ float bfl(unsigned x){ return __uint_as_float(x << 16); }
__device__ __forceinline__ float bfh(unsigned x){ return __uint_as_float(x & 0xFFFF0000u); }
__device__ __forceinline__ unsigned bpack(float a, float b){
  unsigned ua = __float_as_uint(a), ub = __float_as_uint(b);
  return ((ua + 0x7FFFu + ((ua>>16)&1u)) >> 16)
       | ((ub + 0x7FFFu + ((ub>>16)&1u)) & 0xFFFF0000u);
}
__device__ __forceinline__ float dot8b(uint4 w, const float4* s4){
  float4 s0 = s4[0], s1 = s4[1];
  return bfl(w.x)*s0.x + bfh(w.x)*s0.y + bfl(w.y)*s0.z + bfh(w.y)*s0.w
       + bfl(w.z)*s1.x + bfh(w.z)*s1.y + bfl(w.w)*s1.z + bfh(w.w)*s1.w;
}

// ---------------------------------------------------------------------------
// Stage: pack W_iouh / W_fh / W1 to bf16. Grid-stride, all threads.
// ---------------------------------------------------------------------------
__device__ void pack_stage(int gid, int gs,
    const float* __restrict__ W_iouh, const float* __restrict__ W_fh,
    const float* __restrict__ W_attnh, unsigned* __restrict__ W16u)
{
  for (int k = gid; k < 98304; k += gs){
    int i = 2*k; W16u[k] = bpack(W_iouh[i], W_iouh[i+1]);
  }
  for (int k = gid; k < 32768; k += gs){
    int i = 2*k; W16u[98304 + k] = bpack(W_fh[i], W_fh[i+1]);
  }
  for (int k = gid; k < 32768; k += gs){
    int i = 2*k; int t = i>>8, e = i&255;
    const float* r = W_attnh + (size_t)t*512;
    W16u[131072 + k] = bpack(r[e], r[e+1]);
  }
}

// ---------------------------------------------------------------------------
// Stage: init. 256 blocks; block = (pass p, 2 rows). 512 threads.
// ---------------------------------------------------------------------------
__device__ void init_stage(char* smem, int bid, int tid,
    const int* __restrict__ l_idx, const int* __restrict__ r_idx,
    const float* __restrict__ emb, const float* __restrict__ W_ioux,
    const float* __restrict__ b_ioux, const float* __restrict__ b_iouh,
    float* __restrict__ cmatA, float* __restrict__ matA,
    float* __restrict__ cmatB, float* __restrict__ matB)
{
  int p = bid >> 7, n0 = (bid & 127) * 2;
  float* xs = (float*)smem;      // 2*304
  float* sg = xs + 608;          // 2*768
  for (int j = tid; j < 600; j += 512){
    int rr = j/300, d = j - rr*300;
    int row = p ? r_idx[n0+rr] : l_idx[n0+rr];
    xs[rr*304 + d] = emb[(size_t)row*300 + d];
  }
  __syncthreads();
  for (int gg = tid; gg < 768; gg += 512){
    const float4* w = (const float4*)(W_ioux + (size_t)gg*300);
    float a0 = 0.f, a1 = 0.f;
    #pragma unroll 5
    for (int k = 0; k < 75; ++k){
      float4 wv = w[k];
      const float* x0 = xs + 4*k;
      const float* x1 = xs + 304 + 4*k;
      a0 += wv.x*x0[0] + wv.y*x0[1] + wv.z*x0[2] + wv.w*x0[3];
      a1 += wv.x*x1[0] + wv.y*x1[1] + wv.z*x1[2] + wv.w*x1[3];
    }
    float bb = b_ioux[gg] + b_iouh[gg];
    sg[gg] = a0 + bb;
    sg[768 + gg] = a1 + bb;
  }
  __syncthreads();
  {
    int rr = tid >> 8, t = tid & 255;
    const float* g = sg + rr*768;
    float c = sigmf(g[t]) * tanhfast(g[512+t]);
    float h = sigmf(g[256+t]) * tanhfast(c);
    (p ? cmatB : cmatA)[(size_t)(n0+rr)*256 + t] = c;
    (p ? matB  : matA )[(size_t)(n0+rr)*256 + t] = h;
  }
}

// ---------------------------------------------------------------------------
// Stage: A/B tree level, column-split S=4, row-batched R. 512 threads/block.
// ---------------------------------------------------------------------------
template<int R>
__device__ void ab_stage(char* smem, int bid, int tid,
    const unsigned short* __restrict__ W16, const float* __restrict__ b_iouh,
    const float* __restrict__ b_fh,
    int Nc, int offPrev, int offCur,
    float* __restrict__ cmatA, float* __restrict__ matA,
    float* __restrict__ cmatB, float* __restrict__ matB)
{
  int groups = Nc / R;
  if (bid >= 8*groups) return;           // active = (2*Nc/R)*4
  int s = bid & 3, g2 = bid >> 2;
  int p = (g2 >= groups) ? 1 : 0;
  int n0 = (g2 - p*groups) * R;
  float* cmat = p ? cmatB : cmatA;
  float* hmat = p ? matB  : matA;

  float* hs0 = (float*)smem;             // R*256
  float* hs1 = hs0 + R*256;
  float* hss = hs1 + R*256;
  float* sP  = hss + R*256;              // [10][R][64] flattened

  for (int it = tid; it < R*2*256; it += 512){
    int j = it & 255, ch = (it>>8)&1, r = it>>9;
    float v = hmat[(size_t)(offPrev + 2*(n0+r) + ch)*256 + j];
    if (ch) hs1[r*256 + j] = v; else hs0[r*256 + j] = v;
  }
  __syncthreads();
  for (int it = tid; it < R*256; it += 512){
    hss[it] = hs0[it] + hs1[it];
  }
  __syncthreads();

  {
    int role = tid >> 6, cl = tid & 63;
    int gate = role & 3, dh = role >> 2;
    int col = s*64 + cl;
    if (gate < 3){
      const unsigned short* wrow = W16 + (size_t)(col + gate*256)*256;
      const uint4* w4 = (const uint4*)(wrow + dh*128);
      float acc[R];
      #pragma unroll
      for (int r = 0; r < R; ++r) acc[r] = 0.f;
      #pragma unroll 4
      for (int k = 0; k < 16; ++k){
        uint4 w = w4[k];
        #pragma unroll
        for (int r = 0; r < R; ++r)
          acc[r] += dot8b(w, (const float4*)(hss + r*256 + dh*128 + k*8));
      }
      #pragma unroll
      for (int r = 0; r < R; ++r) sP[((gate*2+dh)*R + r)*64 + cl] = acc[r];
    } else {
      const uint4* w4 = (const uint4*)(W16 + B16_FH + (size_t)col*256 + dh*128);
      float a0[R], a1[R];
      #pragma unroll
      for (int r = 0; r < R; ++r){ a0[r] = 0.f; a1[r] = 0.f; }
      #pragma unroll 4
      for (int k = 0; k < 16; ++k){
        uint4 w = w4[k];
        #pragma unroll
        for (int r = 0; r < R; ++r){
          a0[r] += dot8b(w, (const float4*)(hs0 + r*256 + dh*128 + k*8));
          a1[r] += dot8b(w, (const float4*)(hs1 + r*256 + dh*128 + k*8));
        }
      }
      #pragma unroll
      for (int r = 0; r < R; ++r){
        sP[((6+dh)*R + r)*64 + cl] = a0[r];
        sP[((8+dh)*R + r)*64 + cl] = a1[r];
      }
    }
  }
  __syncthreads();
  if (tid < 64*R){
    int r = tid >> 6, cl = tid & 63;
    int t = s*64 + cl;
    int n = n0 + r;
    float ai  = sP[(0*R+r)*64+cl] + sP[(1*R+r)*64+cl];
    float ao  = sP[(2*R+r)*64+cl] + sP[(3*R+r)*64+cl];
    float au  = sP[(4*R+r)*64+cl] + sP[(5*R+r)*64+cl];
    float af0 = sP[(6*R+r)*64+cl] + sP[(7*R+r)*64+cl];
    float af1 = sP[(8*R+r)*64+cl] + sP[(9*R+r)*64+cl];
    float c0 = cmat[(size_t)(offPrev+2*n)*256 + t];
    float c1 = cmat[(size_t)(offPrev+2*n+1)*256 + t];
    float i_ = sigmf(ai + b_iouh[t]);
    float o_ = sigmf(ao + b_iouh[256+t]);
    float u_ = tanhfast(au + b_iouh[512+t]);
    float bf = b_fh[t];
    float c = i_*u_ + sigmf(af0+bf)*c0 + sigmf(af1+bf)*c1;
    float h = o_*tanhfast(c);
    cmat[(size_t)(offCur+n)*256 + t] = c;
    hmat[(size_t)(offCur+n)*256 + t] = h;
  }
}

// ---------------------------------------------------------------------------
// Stage: mid. 512 half-units of 256 threads (450 active).
// Branch boundaries (128/130/386/450) are even, so both halves of a block
// always take the same branch -> __syncthreads counts match.
// ---------------------------------------------------------------------------
__device__ void mid_stage(char* smem, int bid, int tid,
    const float* __restrict__ W_attnh, const float* __restrict__ b_attnh,
    const float* __restrict__ matA, const float* __restrict__ matB,
    float* __restrict__ projA, float* __restrict__ projB,
    float* __restrict__ colA, float* __restrict__ colB,
    float* __restrict__ matTA, float* __restrict__ matTB,
    float* __restrict__ php)
{
  int half = tid >> 8, lt = tid & 255;
  int u = bid*2 + half;
  char* hsm = smem + half*8192;
  if (u < 128){
    int p = u>>6, ch = u&63, m0 = ch*8, mc = min(8, 511-m0);
    const float* mat = p ? matB : matA;
    float* proj = p ? projB : projA;
    float* ms = (float*)hsm;   // ms[e*8+rr], 8 KB
    for (int j = lt; j < mc*256; j += 256){
      int rr = j>>8, e = j&255;
      ms[e*8+rr] = mat[(size_t)(m0+rr)*256 + e];
    }
    for (int j = lt + mc*256; j < 8*256; j += 256){
      int rr = j>>8, e = j&255; ms[e*8+rr] = 0.f;
    }
    __syncthreads();
    int t = lt;
    const float4* w2 = (const float4*)(W_attnh + (size_t)t*512 + 256);
    float acc[8] = {0,0,0,0,0,0,0,0};
    #pragma unroll 2
    for (int k = 0; k < 64; ++k){
      float4 w = w2[k];
      const float* base = ms + k*32;
      #pragma unroll
      for (int rr = 0; rr < 8; ++rr)
        acc[rr] += w.x*base[rr] + w.y*base[8+rr] + w.z*base[16+rr] + w.w*base[24+rr];
    }
    float ba = b_attnh[t];
    for (int rr = 0; rr < mc; ++rr) proj[(size_t)(m0+rr)*256 + t] = acc[rr] + ba;
  } else if (u < 130){
    int p = u - 128;
    const float* mat = p ? matB : matA;
    float* col = p ? colB : colA;
    float s = 0.f;
    #pragma unroll 8
    for (int m = 0; m < 511; ++m) s += mat[(size_t)m*256 + lt];
    col[lt] = s;
  } else if (u < 386){
    int idx = u - 130;
    int p = idx>>7, rem = idx&127, jt = rem>>4, mt = rem&15;
    const float* mat = p ? matB : matA;
    float* matT = p ? matTB : matTA;
    float (*tile)[33] = (float (*)[33])hsm;   // 32*33*4 = 4224 B
    int c = lt&31, r0 = lt>>5;
    int m0 = mt*32, j0 = jt*32;
    #pragma unroll
    for (int k = 0; k < 4; ++k){
      int m = m0 + r0 + 8*k;
      tile[r0+8*k][c] = (m < 511) ? mat[(size_t)m*256 + j0 + c] : 0.f;
    }
    __syncthreads();
    #pragma unroll
    for (int k = 0; k < 4; ++k){
      int jj = r0 + 8*k;
      matT[(size_t)(j0+jj)*MT + m0 + c] = tile[c][jj];
    }
  } else if (u < 450){
    int idx = u - 386;           // p (C/D) x 32 chunks of 8 rows
    int p = idx>>5, ch = idx&31, r0 = ch*8;
    const float* hsrc = p ? matA : matB;   // C<-B, D<-A
    float* ms = (float*)hsm;
    for (int j = lt; j < 8*256; j += 256){
      int rr = j>>8, e = j&255;
      ms[e*8+rr] = hsrc[(size_t)(r0+rr)*256 + e];
    }
    __syncthreads();
    int t = lt;
    const float4* w1 = (const float4*)(W_attnh + (size_t)t*512);
    float acc[8] = {0,0,0,0,0,0,0,0};
    #pragma unroll 2
    for (int k = 0; k < 64; ++k){
      float4 w = w1[k];
      const float* base = ms + k*32;
      #pragma unroll
      for (int rr = 0; rr < 8; ++rr)
        acc[rr] += w.x*base[rr] + w.y*base[8+rr] + w.z*base[16+rr] + w.w*base[24+rr];
    }
    #pragma unroll
    for (int rr = 0; rr < 8; ++rr)
      php[(((size_t)p*511 + r0+rr)*4 + 0)*256 + t] = acc[rr];
  }
}

// ---------------------------------------------------------------------------
// Stage: tiled scores. Half-units of 256 threads; unit count 2*(Nc/G)*4 is
// always even, so both halves of a block are active/idle together.
// ---------------------------------------------------------------------------
template<int G>
__device__ void scores_stage(char* smem, int bid, int tid,
    const float* __restrict__ php,
    const float* __restrict__ projA, const float* __restrict__ projB,
    const float* __restrict__ matTA, const float* __restrict__ matTB,
    const float* __restrict__ Wa, int Nc, int rowOff, int S,
    float* __restrict__ wsumP, float* __restrict__ esumP)
{
  int half = tid >> 8, lt = tid & 255;
  int u = bid*2 + half;
  int groups = Nc / G;
  int per = groups * 4;
  if (u >= 2*per) return;
  int p = u / per; int rem = u - p*per; int g = rem >> 2, ch = rem & 3;
  int row0 = rowOff + g*G;
  const float* proj = p ? projB : projA;
  const float* matT = p ? matTB : matTA;

  char* hsm = smem + half*11264;   // per-half arena (G=4: 11264 B)
  float* shp   = (float*)hsm;      // G*256
  float* swa   = shp + G*256;      // 256
  float* spart = swa + 256;        // G*256
  float* se    = spart + G*256;    // G*128

  for (int j = lt; j < G*256; j += 256){
    int row = row0 + (j>>8), jj = j&255;
    const float* base = php + (((size_t)p*511 + row)*4)*256 + jj;
    float v = base[0];
    if (S == 4) v += base[256] + base[512] + base[768];
    shp[j] = v;
  }
  swa[lt] = Wa[lt];
  __syncthreads();

  int ml = lt & 127, dh = lt >> 7;
  int m = ch*128 + ml;
  float part[G];
  #pragma unroll
  for (int r = 0; r < G; ++r) part[r] = 0.f;
  if (m < 511){
    const float4* pr  = (const float4*)(proj + (size_t)m*256 + dh*128);
    const float4* wa4 = (const float4*)(swa + dh*128);
    #pragma unroll 4
    for (int k = 0; k < 32; ++k){
      float4 pv = pr[k], wv = wa4[k];
      int dbase = dh*128 + k*4;
      #pragma unroll
      for (int r = 0; r < G; ++r){
        const float* hr = shp + r*256 + dbase;
        part[r] += wv.x*tanhfast(hr[0]+pv.x) + wv.y*tanhfast(hr[1]+pv.y)
                 + wv.z*tanhfast(hr[2]+pv.z) + wv.w*tanhfast(hr[3]+pv.w);
      }
    }
  }
  #pragma unroll
  for (int r = 0; r < G; ++r) spart[r*256 + lt] = part[r];
  __syncthreads();
  if (lt < 128){
    #pragma unroll
    for (int r = 0; r < G; ++r){
      float sv = spart[r*256 + ml] + spart[r*256 + 128 + ml];
      se[r*128 + ml] = (ch*128 + ml < 511) ? __expf(sv) : 0.f;
    }
  }
  __syncthreads();
  {
    const float4* mt = (const float4*)(matT + (size_t)lt*MT + ch*128);
    float acc[G];
    #pragma unroll
    for (int r = 0; r < G; ++r) acc[r] = 0.f;
    #pragma unroll 4
    for (int k = 0; k < 32; ++k){
      float4 mv = mt[k];
      #pragma unroll
      for (int r = 0; r < G; ++r){
        float4 ev = ((const float4*)(se + r*128))[k];
        acc[r] += mv.x*ev.x + mv.y*ev.y + mv.z*ev.z + mv.w*ev.w;
      }
    }
    #pragma unroll
    for (int r = 0; r < G; ++r)
      wsumP[(((size_t)p*511 + row0 + r)*4 + ch)*256 + lt] = acc[r];
  }
  if (lt < G){
    float sv = 0.f;
    const float* sr = se + lt*128;
    for (int k = 0; k < 128; ++k) sv += sr[k];
    esumP[((size_t)p*511 + row0 + lt)*4 + ch] = sv;
  }
}

// ---------------------------------------------------------------------------
// Stage: CD spine level. 512 threads/block, same phases as k_cd1.
// ---------------------------------------------------------------------------
template<int R>
__device__ void cd1_stage(char* smem, int bid, int tid,
    const unsigned short* __restrict__ W16, const float* __restrict__ b_iouh,
    const float* __restrict__ b_fh,
    int Nc, int offPrev, int offCur,
    const float* __restrict__ colA, const float* __restrict__ colB,
    const float* __restrict__ wsumP, const float* __restrict__ esumP,
    const float* __restrict__ childHC, const float* __restrict__ childHD,
    const float* __restrict__ childCC, const float* __restrict__ childCD_,
    float* __restrict__ cmatC, float* __restrict__ cmatD,
    float* __restrict__ hstageC, float* __restrict__ hstageD,
    float* __restrict__ php)
{
  int groups = Nc / R;
  if (bid >= 8*groups) return;
  int s = bid & 3, g2 = bid >> 2;
  int p = (g2 >= groups) ? 1 : 0;
  int n0 = (g2 - p*groups) * R;
  const float* colv   = p ? colB : colA;
  const float* childH = p ? childHD : childHC;
  const float* childC = p ? childCD_ : childCC;
  float* cmat   = p ? cmatD : cmatC;
  float* hstage = p ? hstageD : hstageC;

  float* hs0 = (float*)smem;               // R*256
  float* hs1 = hs0 + R*256;
  float* hss = hs1 + R*256;
  float* sP  = hss + R*256;                // 10*R*64
  float* sh  = sP + 10*R*64;               // R*64
  float* sHP = sh + R*64;                  // 2*256

  // Phase 1: attend-finish both children (full width)
  for (int it = tid; it < R*2*256; it += 512){
    int j = it & 255, ch = (it>>8)&1, r = it>>9;
    int rc = offPrev + 2*(n0+r) + ch;
    const float* wp = wsumP + (((size_t)p*511 + rc)*4)*256;
    const float* ep = esumP + ((size_t)p*511 + rc)*4;
    float w = wp[j] + wp[256+j] + wp[512+j] + wp[768+j];
    float esum = ep[0]+ep[1]+ep[2]+ep[3];
    float hatt = colv[j] - w*rcpf(esum) + childH[(size_t)rc*256 + j];
    if (ch) hs1[r*256 + j] = hatt; else hs0[r*256 + j] = hatt;
  }
  __syncthreads();
  for (int it = tid; it < R*256; it += 512){
    hss[it] = hs0[it] + hs1[it];
  }
  __syncthreads();

  // Phase 2: gate dots for own 64 columns
  {
    int role = tid >> 6, cl = tid & 63;
    int gate = role & 3, dh = role >> 2;
    int col = s*64 + cl;
    if (gate < 3){
      const unsigned short* wrow = W16 + (size_t)(col + gate*256)*256;
      const uint4* w4 = (const uint4*)(wrow + dh*128);
      float acc[R];
      #pragma unroll
      for (int r = 0; r < R; ++r) acc[r] = 0.f;
      #pragma unroll 4
      for (int k = 0; k < 16; ++k){
        uint4 w = w4[k];
        #pragma unroll
        for (int r = 0; r < R; ++r)
          acc[r] += dot8b(w, (const float4*)(hss + r*256 + dh*128 + k*8));
      }
      #pragma unroll
      for (int r = 0; r < R; ++r) sP[((gate*2+dh)*R + r)*64 + cl] = acc[r];
    } else {
      const uint4* w4 = (const uint4*)(W16 + B16_FH + (size_t)col*256 + dh*128);
      float a0[R], a1[R];
      #pragma unroll
      for (int r = 0; r < R; ++r){ a0[r] = 0.f; a1[r] = 0.f; }
      #pragma unroll 4
      for (int k = 0; k < 16; ++k){
        uint4 w = w4[k];
        #pragma unroll
        for (int r = 0; r < R; ++r){
          a0[r] += dot8b(w, (const float4*)(hs0 + r*256 + dh*128 + k*8));
          a1[r] += dot8b(w, (const float4*)(hs1 + r*256 + dh*128 + k*8));
        }
      }
      #pragma unroll
      for (int r = 0; r < R; ++r){
        sP[((6+dh)*R + r)*64 + cl] = a0[r];
        sP[((8+dh)*R + r)*64 + cl] = a1[r];
      }
    }
  }
  __syncthreads();

  // Phase 3: finalize c,h for own columns
  if (tid < 64*R){
    int r = tid >> 6, cl = tid & 63;
    int t = s*64 + cl;
    int n = n0 + r;
    float ai  = sP[(0*R+r)*64+cl] + sP[(1*R+r)*64+cl];
    float ao  = sP[(2*R+r)*64+cl] + sP[(3*R+r)*64+cl];
    float au  = sP[(4*R+r)*64+cl] + sP[(5*R+r)*64+cl];
    float af0 = sP[(6*R+r)*64+cl] + sP[(7*R+r)*64+cl];
    float af1 = sP[(8*R+r)*64+cl] + sP[(9*R+r)*64+cl];
    float c0 = childC[(size_t)(offPrev+2*n)*256 + t];
    float c1 = childC[(size_t)(offPrev+2*n+1)*256 + t];
    float i_ = sigmf(ai + b_iouh[t]);
    float o_ = sigmf(ao + b_iouh[256+t]);
    float u_ = tanhfast(au + b_iouh[512+t]);
    float bf = b_fh[t];
    float c = i_*u_ + sigmf(af0+bf)*c0 + sigmf(af1+bf)*c1;
    float h = o_*tanhfast(c);
    cmat[(size_t)(offCur+n)*256 + t] = c;
    hstage[(size_t)(offCur+n)*256 + t] = h;
    sh[r*64 + cl] = h;
  }
  __syncthreads();

  // Phase 4: hp partial over own e-slice -> php[p][row][s][:]
  {
    int j = tid & 255, eh = tid >> 8;
    const uint4* w1 = (const uint4*)(W16 + B16_W1 + (size_t)j*256 + s*64 + eh*32);
    uint4 wv[4];
    #pragma unroll
    for (int k = 0; k < 4; ++k) wv[k] = w1[k];
    float aacc[R];
    #pragma unroll
    for (int r = 0; r < R; ++r){
      float a = 0.f;
      #pragma unroll
      for (int k = 0; k < 4; ++k)
        a += dot8b(wv[k], (const float4*)(sh + r*64 + eh*32 + k*8));
      aacc[r] = a;
    }
    #pragma unroll
    for (int r = 0; r < R; ++r){
      sHP[eh*256 + j] = aacc[r];
      __syncthreads();
      if (tid < 256){
        int row = offCur + n0 + r;
        php[(((size_t)p*511 + row)*4 + s)*256 + tid] = sHP[tid] + sHP[256 + tid];
      }
      __syncthreads();
    }
  }
}

// ---------------------------------------------------------------------------
// Stage: head. Block 0 only.
// ---------------------------------------------------------------------------
__device__ void head_stage(char* smem, int tid,
    const float* __restrict__ W_wh, const float* __restrict__ b_wh,
    const float* __restrict__ W_wp, const float* __restrict__ b_wp,
    const float* __restrict__ matA, const float* __restrict__ matB,
    const float* __restrict__ colA, const float* __restrict__ colB,
    const float* __restrict__ wsumP, const float* __restrict__ esumP,
    const float* __restrict__ hstageC, const float* __restrict__ hstageD,
    float* __restrict__ out)
{
  float* v  = (float*)smem;   // 512
  float* og = v + 512;        // 128
  float* lg = og + 128;       // 5
  int t = tid;
  if (t < 256){
    const float* wpC = wsumP + (((size_t)0*511 + 510)*4)*256;
    const float* epC = esumP + ((size_t)0*511 + 510)*4;
    float wC = wpC[t] + wpC[256+t] + wpC[512+t] + wpC[768+t];
    float eC = epC[0]+epC[1]+epC[2]+epC[3];
    float hCf = colA[t] - wC*rcpf(eC) + hstageC[(size_t)510*256 + t];
    const float* wpD = wsumP + (((size_t)1*511 + 510)*4)*256;
    const float* epD = esumP + ((size_t)1*511 + 510)*4;
    float wD = wpD[t] + wpD[256+t] + wpD[512+t] + wpD[768+t];
    float eD = epD[0]+epD[1]+epD[2]+epD[3];
    float hDf = colB[t] - wD*rcpf(eD) + hstageD[(size_t)510*256 + t];
    float lh = tanhfast(matA[(size_t)510*256 + t] + hDf);
    float rh = tanhfast(hCf + matB[(size_t)510*256 + t]);
    v[t] = lh*rh;
    v[256+t] = fabsf(lh - rh);
  }
  __syncthreads();
  if (t < 128){
    const float4* w = (const float4*)(W_wh + (size_t)t*512);
    const float4* vv = (const float4*)v;
    float a = b_wh[t];
    #pragma unroll 4
    for (int k = 0; k < 128; ++k){
      float4 wv = w[k], x = vv[k];
      a += wv.x*x.x + wv.y*x.y + wv.z*x.z + wv.w*x.w;
    }
    og[t] = sigmf(a);
  }
  __syncthreads();
  if (t < 5){
    const float* wp = W_wp + (size_t)t*128;
    float a = b_wp[t];
    for (int j = 0; j < 128; ++j) a += og[j]*wp[j];
    lg[t] = a;
  }
  __syncthreads();
  if (t == 0){
    float M = -1e30f;
    for (int c = 0; c < 5; ++c) M = fmaxf(M, lg[c]);
    float S = 0.f;
    for (int c = 0; c < 5; ++c) S += __expf(lg[c] - M);
    float L = logf(S);
    for (int c = 0; c < 5; ++c) out[c] = lg[c] - M - L;
  }
}

// ---------------------------------------------------------------------------
// Mega kernel: whole forward in one cooperative launch.
// 256 blocks x 512 threads; grid.sync() between dependent stages.
// ---------------------------------------------------------------------------
__global__ void __launch_bounds__(512) k_mega(
    const int* l_idx, const int* r_idx, const float* emb,
    const float* W_ioux, const float* b_ioux,
    const float* W_iouh, const float* b_iouh,
    const float* W_fh, const float* b_fh,
    const float* Wa, const float* W_attnh, const float* b_attnh,
    const float* W_wh, const float* b_wh,
    const float* W_wp, const float* b_wp,
    float* ws, float* out)
{
  __shared__ __align__(16) char smem[SMEM_BYTES];
  int bid = blockIdx.x, tid = threadIdx.x;
  cg::grid_group grid = cg::this_grid();

  float* cmatA   = ws;               float* cmatB   = cmatA + RC;
  float* cmatC   = cmatB + RC;       float* cmatD   = cmatC + RC;
  float* matA    = cmatD + RC;       float* matB    = matA + RC;
  float* hstageC = matB + RC;        float* hstageD = hstageC + RC;
  float* projA   = hstageD + RC;     float* projB   = projA + RC;
  float* matTA   = projB + RC;       float* matTB   = matTA + 256*MT;
  float* colA    = matTB + 256*MT;   float* colB    = colA + 256;
  float* wsumP   = colB + 256;            // 2*511*4*256
  float* esumP   = wsumP + 2*511*4*256;   // 2*511*4
  float* php     = esumP + 2*511*4;       // 2*511*4*256
  unsigned short* W16 = (unsigned short*)(php + 2*511*4*256);

  // Stage 0: pack (grid-stride) + init (independent of W16)
  pack_stage(bid*512 + tid, 256*512, W_iouh, W_fh, W_attnh, (unsigned*)W16);
  init_stage(smem, bid, tid, l_idx, r_idx, emb, W_ioux, b_ioux, b_iouh,
             cmatA, matA, cmatB, matB);
  grid.sync();

  // A/B tree levels (offs: 0,256,384,448,480,496,504,508,510)
  ab_stage<4>(smem, bid, tid, W16, b_iouh, b_fh, 128,   0, 256, cmatA, matA, cmatB, matB); grid.sync();
  ab_stage<2>(smem, bid, tid, W16, b_iouh, b_fh,  64, 256, 384, cmatA, matA, cmatB, matB); grid.sync();
  ab_stage<1>(smem, bid, tid, W16, b_iouh, b_fh,  32, 384, 448, cmatA, matA, cmatB, matB); grid.sync();
  ab_stage<1>(smem, bid, tid, W16, b_iouh, b_fh,  16, 448, 480, cmatA, matA, cmatB, matB); grid.sync();
  ab_stage<1>(smem, bid, tid, W16, b_iouh, b_fh,   8, 480, 496, cmatA, matA, cmatB, matB); grid.sync();
  ab_stage<1>(smem, bid, tid, W16, b_iouh, b_fh,   4, 496, 504, cmatA, matA, cmatB, matB); grid.sync();
  ab_stage<1>(smem, bid, tid, W16, b_iouh, b_fh,   2, 504, 508, cmatA, matA, cmatB, matB); grid.sync();
  ab_stage<1>(smem, bid, tid, W16, b_iouh, b_fh,   1, 508, 510, cmatA, matA, cmatB, matB); grid.sync();

  mid_stage(smem, bid, tid, W_attnh, b_attnh, matA, matB,
            projA, projB, colA, colB, matTA, matTB, php);
  grid.sync();

  scores_stage<4>(smem, bid, tid, php, projA, projB, matTA, matTB, Wa,
                  256, 0, 1, wsumP, esumP);
  grid.sync();

  // CD spine: level 1 uses A/B mats as children
  cd1_stage<4>(smem, bid, tid, W16, b_iouh, b_fh, 128,   0, 256, colA, colB,
               wsumP, esumP, matB, matA, cmatB, cmatA,
               cmatC, cmatD, hstageC, hstageD, php); grid.sync();
  scores_stage<4>(smem, bid, tid, php, projA, projB, matTA, matTB, Wa,
                  128, 256, 4, wsumP, esumP); grid.sync();

  cd1_stage<2>(smem, bid, tid, W16, b_iouh, b_fh,  64, 256, 384, colA, colB,
               wsumP, esumP, hstageC, hstageD, cmatC, cmatD,
               cmatC, cmatD, hstageC, hstageD, php); grid.sync();
  scores_stage<4>(smem, bid, tid, php, projA, projB, matTA, matTB, Wa,
                  64, 384, 4, wsumP, esumP); grid.sync();

  cd1_stage<1>(smem, bid, tid, W16, b_iouh, b_fh,  32, 384, 448, colA, colB,
               wsumP, esumP, hstageC, hstageD, cmatC, cmatD,
               cmatC, cmatD, hstageC, hstageD, php); grid.sync();
  scores_stage<4>(smem, bid, tid, php, projA, projB, matTA, matTB, Wa,
                  32, 448, 4, wsumP, esumP); grid.sync();

  cd1_stage<1>(smem, bid, tid, W16, b_iouh, b_fh,  16, 448, 480, colA, colB,
               wsumP, esumP, hstageC, hstageD, cmatC, cmatD,
               cmatC, cmatD, hstageC, hstageD, php); grid.sync();
  scores_stage<4>(smem, bid, tid, php, projA, projB, matTA, matTB, Wa,
                  16, 480, 4, wsumP, esumP); grid.sync();

  cd1_stage<1>(smem, bid, tid, W16, b_iouh, b_fh,   8, 480, 496, colA, colB,
               wsumP, esumP, hstageC, hstageD, cmatC, cmatD,
               cmatC, cmatD, hstageC, hstageD, php); grid.sync();
  scores_stage<4>(smem, bid, tid, php, projA, projB, matTA, matTB, Wa,
                  8, 496, 4, wsumP, esumP); grid.sync();

  cd1_stage<1>(smem, bid, tid, W16, b_iouh, b_fh,   4, 496, 504, colA, colB,
               wsumP, esumP, hstageC, hstageD, cmatC, cmatD,
               cmatC, cmatD, hstageC, hstageD, php); grid.sync();
  scores_stage<4>(smem, bid, tid, php, projA, projB, matTA, matTB, Wa,
                  4, 504, 4, wsumP, esumP); grid.sync();

  cd1_stage<1>(smem, bid, tid, W16, b_iouh, b_fh,   2, 504, 508, colA, colB,
               wsumP, esumP, hstageC, hstageD, cmatC, cmatD,
               cmatC, cmatD, hstageC, hstageD, php); grid.sync();
  scores_stage<2>(smem, bid, tid, php, projA, projB, matTA, matTB, Wa,
                  2, 508, 4, wsumP, esumP); grid.sync();

  cd1_stage<1>(smem, bid, tid, W16, b_iouh, b_fh,   1, 508, 510, colA, colB,
               wsumP, esumP, hstageC, hstageD, cmatC, cmatD,
               cmatC, cmatD, hstageC, hstageD, php); grid.sync();
  scores_stage<1>(smem, bid, tid, php, projA, projB, matTA, matTB, Wa,
                  1, 510, 4, wsumP, esumP); grid.sync();

  if (bid == 0)
    head_stage(smem, tid, W_wh, b_wh, W_wp, b_wp, matA, matB,
               colA, colB, wsumP, esumP, hstageC, hstageD, out);
}

extern "C" void kernel_launch(void* const* d_in, const int* in_sizes, int n_in,
                              void* d_out, int out_size, void* d_ws, size_t ws_size,
                              hipStream_t stream)
{
  const int*   l_idx   = (const int*)  d_in[0];
  const int*   r_idx   = (const int*)  d_in[1];
  const float* emb     = (const float*)d_in[2];
  const float* W_ioux  = (const float*)d_in[3];
  const float* b_ioux  = (const float*)d_in[4];
  const float* W_iouh  = (const float*)d_in[5];
  const float* b_iouh  = (const float*)d_in[6];
  // d_in[7]=W_fx, d_in[8]=b_fx unused by the forward
  const float* W_fh    = (const float*)d_in[9];
  const float* b_fh    = (const float*)d_in[10];
  const float* Wa      = (const float*)d_in[11];
  const float* W_attnh = (const float*)d_in[12];
  const float* b_attnh = (const float*)d_in[13];
  const float* W_wh    = (const float*)d_in[14];
  const float* b_wh    = (const float*)d_in[15];
  const float* W_wp    = (const float*)d_in[16];
  const float* b_wp    = (const float*)d_in[17];

  float* ws  = (float*)d_ws;
  float* out = (float*)d_out;

  void* args[] = {
    (void*)&l_idx, (void*)&r_idx, (void*)&emb,
    (void*)&W_ioux, (void*)&b_ioux, (void*)&W_iouh, (void*)&b_iouh,
    (void*)&W_fh, (void*)&b_fh, (void*)&Wa, (void*)&W_attnh, (void*)&b_attnh,
    (void*)&W_wh, (void*)&b_wh, (void*)&W_wp, (void*)&b_wp,
    (void*)&ws, (void*)&out
  };
  hipLaunchCooperativeKernel((void*)k_mega, dim3(256), dim3(512), args, 0, stream);
}

// Round 5
// 924.003 us; speedup vs baseline: 1.4322x; 1.4322x over previous
//
#include <hip/hip_runtime.h>

#define RC 130816   // 511*256

// bf16 weight cache layout (ushort offsets)
#define B16_FH   196608   // after 768*256 iou rows
#define B16_W1   262144   // 256*256 (W_attnh[:, :256])

__device__ __forceinline__ float rcpf(float x){ return __builtin_amdgcn_rcpf(x); }
__device__ __forceinline__ float sigmf(float x){ return rcpf(1.f + __expf(-x)); }
__device__ __forceinline__ float tanhfast(float x){
  return 1.f - 2.f*rcpf(1.f + __expf(2.f*x));
}

// ---- bf16-as-integer helpers ----
__device__ __forceinline__ float bfl(unsigned x){ return __uint_as_float(x << 16); }
__device__ __forceinline__ float bfh(unsigned x){ return __uint_as_float(x & 0xFFFF0000u); }
__device__ __forceinline__ unsigned bpack(float a, float b){
  unsigned ua = __float_as_uint(a), ub = __float_as_uint(b);
  return ((ua + 0x7FFFu + ((ua>>16)&1u)) >> 16)
       | ((ub + 0x7FFFu + ((ub>>16)&1u)) & 0xFFFF0000u);
}
__device__ __forceinline__ float dot8b(uint4 w, const float4* s4){
  float4 s0 = s4[0], s1 = s4[1];
  return bfl(w.x)*s0.x + bfh(w.x)*s0.y + bfl(w.y)*s0.z + bfh(w.y)*s0.w
       + bfl(w.z)*s1.x + bfh(w.z)*s1.y + bfl(w.w)*s1.z + bfh(w.w)*s1.w;
}

// ---------------------------------------------------------------------------
// Block-local attention scores for one row. 512 threads.
// Input: h[256] in LDS. Computes hp = W1(bf16)·h, scores vs proj (tanh·Wa),
// e=exp(score), esum, unnormalized wsum = sum_m e_m * mat[m,:].
// Writes wsum[p*511+row][0..255] and esum[p*511+row]. Arena: 3136 floats.
// ---------------------------------------------------------------------------
__device__ void attend_scores_block(
    int tid, int p, int row,
    const float* sh_h,
    const float* __restrict__ proj, const float* __restrict__ mat,
    const unsigned short* __restrict__ W16, const float* __restrict__ Wa,
    float* __restrict__ wsum_g, float* __restrict__ esum_g,
    float* lds)
{
  float* sHP   = lds;           // 512  [eh][j]
  float* shp   = sHP + 512;     // 256
  float* swa   = shp + 256;     // 256
  float* spart = swa + 256;     // 1024 [(dh*4+ch)*128+ml]
  float* se    = spart + 1024;  // 512
  float* sw    = se + 512;      // 512  [mh][j]
  float* sred  = sw + 512;      // 64

  // hp = W1 (bf16) · h
  {
    int j = tid & 255, eh = tid >> 8;
    const uint4* w1 = (const uint4*)(W16 + B16_W1 + (size_t)j*256 + eh*128);
    float a = 0.f;
    #pragma unroll
    for (int k = 0; k < 16; ++k)
      a += dot8b(w1[k], (const float4*)(sh_h + eh*128 + k*8));
    sHP[eh*256 + j] = a;
  }
  if (tid < 256) swa[tid] = Wa[tid];
  __syncthreads();
  if (tid < 256) shp[tid] = sHP[tid] + sHP[256 + tid];
  __syncthreads();

  // scores: thread (ml, dh, hi) covers chunks ch = hi*2 + {0,1}
  {
    int ml = tid & 127, dh = (tid >> 7) & 1, hi = tid >> 8;
    #pragma unroll
    for (int chi = 0; chi < 2; ++chi){
      int ch = hi*2 + chi;
      int m = ch*128 + ml;
      float part = 0.f;
      if (m < 511){
        const float4* pr  = (const float4*)(proj + (size_t)m*256 + dh*128);
        const float4* wa4 = (const float4*)(swa + dh*128);
        #pragma unroll 4
        for (int k = 0; k < 32; ++k){
          float4 pv = pr[k], wv = wa4[k];
          const float* hr = shp + dh*128 + k*4;
          part += wv.x*tanhfast(hr[0]+pv.x) + wv.y*tanhfast(hr[1]+pv.y)
                + wv.z*tanhfast(hr[2]+pv.z) + wv.w*tanhfast(hr[3]+pv.w);
        }
      }
      spart[(dh*4 + ch)*128 + ml] = part;
    }
  }
  __syncthreads();
  // e[m] (m == tid)
  {
    int ch = tid >> 7, mml = tid & 127;
    float sv = spart[(0*4+ch)*128 + mml] + spart[(1*4+ch)*128 + mml];
    se[tid] = (tid < 511) ? __expf(sv) : 0.f;
  }
  __syncthreads();
  // esum reduce
  if (tid < 64){
    float s = 0.f;
    #pragma unroll
    for (int i = 0; i < 8; ++i) s += se[tid + 64*i];
    sred[tid] = s;
  }
  __syncthreads();
  if (tid == 0){
    float s = 0.f;
    #pragma unroll
    for (int i = 0; i < 64; ++i) s += sred[i];
    esum_g[(size_t)p*511 + row] = s;
  }
  // wsum[j] = sum_m e_m * mat[m][j]
  {
    int j = tid & 255, mh = tid >> 8;
    float acc = 0.f;
    int mbase = mh*256;
    int mcount = mh ? 255 : 256;   // m in [0,511)
    for (int mi = 0; mi < mcount; ++mi){
      int m = mbase + mi;
      acc += se[m] * mat[(size_t)m*256 + j];
    }
    sw[mh*256 + j] = acc;
  }
  __syncthreads();
  if (tid < 256)
    wsum_g[((size_t)p*511 + row)*256 + tid] = sw[tid] + sw[256 + tid];
}

// ---------------------------------------------------------------------------
// Init (blocks 0..255) + weight pack (blocks 256..287). 768 threads.
// ---------------------------------------------------------------------------
__global__ void __launch_bounds__(768) k_init(
    const int* __restrict__ l_idx, const int* __restrict__ r_idx,
    const float* __restrict__ emb, const float* __restrict__ W_ioux,
    const float* __restrict__ b_ioux, const float* __restrict__ b_iouh,
    const float* __restrict__ W_iouh, const float* __restrict__ W_fh,
    const float* __restrict__ W_attnh,
    float* __restrict__ cmatA, float* __restrict__ matA,
    float* __restrict__ cmatB, float* __restrict__ matB,
    unsigned* __restrict__ W16u)
{
  int b = blockIdx.x, tid = threadIdx.x;
  if (b >= 256){
    int gid = (b - 256)*768 + tid, gs = 32*768;
    for (int k = gid; k < 98304; k += gs){
      int i = 2*k; W16u[k] = bpack(W_iouh[i], W_iouh[i+1]);
    }
    for (int k = gid; k < 32768; k += gs){
      int i = 2*k; W16u[98304 + k] = bpack(W_fh[i], W_fh[i+1]);
    }
    for (int k = gid; k < 32768; k += gs){
      int i = 2*k; int t = i>>8, e = i&255;
      const float* r = W_attnh + (size_t)t*512;
      W16u[131072 + k] = bpack(r[e], r[e+1]);
    }
    return;
  }
  int p = b >> 7, n0 = (b & 127) * 2;
  __shared__ __align__(16) float xs[2*304];
  __shared__ float sg[2*768];
  for (int j = tid; j < 600; j += 768){
    int rr = j/300, d = j - rr*300;
    int row = p ? r_idx[n0+rr] : l_idx[n0+rr];
    xs[rr*304 + d] = emb[(size_t)row*300 + d];
  }
  __syncthreads();
  const float4* w = (const float4*)(W_ioux + (size_t)tid*300);
  float a0 = 0.f, a1 = 0.f;
  #pragma unroll 5
  for (int k = 0; k < 75; ++k){
    float4 wv = w[k];
    const float* x0 = xs + 4*k;
    const float* x1 = xs + 304 + 4*k;
    a0 += wv.x*x0[0] + wv.y*x0[1] + wv.z*x0[2] + wv.w*x0[3];
    a1 += wv.x*x1[0] + wv.y*x1[1] + wv.z*x1[2] + wv.w*x1[3];
  }
  float bb = b_ioux[tid] + b_iouh[tid];
  sg[tid] = a0 + bb;
  sg[768 + tid] = a1 + bb;
  __syncthreads();
  if (tid < 512){
    int rr = tid >> 8, t = tid & 255;
    const float* g = sg + rr*768;
    float c = sigmf(g[t]) * tanhfast(g[512+t]);
    float h = sigmf(g[256+t]) * tanhfast(c);
    (p ? cmatB : cmatA)[(size_t)(n0+rr)*256 + t] = c;
    (p ? matB  : matA )[(size_t)(n0+rr)*256 + t] = h;
  }
}

// ---------------------------------------------------------------------------
// A/B tree level (unchanged from verified 491us version).
// ---------------------------------------------------------------------------
template<int R>
__global__ void __launch_bounds__(512) k_levelAB(
    const unsigned short* __restrict__ W16, const float* __restrict__ b_iouh,
    const float* __restrict__ b_fh,
    int Nc, int offPrev, int offCur,
    float* __restrict__ cmatA, float* __restrict__ matA,
    float* __restrict__ cmatB, float* __restrict__ matB)
{
  int bid = blockIdx.x, tid = threadIdx.x;
  int s = bid & 3, g2 = bid >> 2;
  int groups = Nc / R;
  int p = (g2 >= groups) ? 1 : 0;
  int n0 = (g2 - p*groups) * R;
  float* cmat = p ? cmatB : cmatA;
  float* hmat = p ? matB  : matA;

  __shared__ __align__(16) float hs0[R][256], hs1[R][256], hss[R][256];
  __shared__ float sP[10][R][64];

  for (int it = tid; it < R*2*256; it += 512){
    int j = it & 255, ch = (it>>8)&1, r = it>>9;
    float v = hmat[(size_t)(offPrev + 2*(n0+r) + ch)*256 + j];
    if (ch) hs1[r][j] = v; else hs0[r][j] = v;
  }
  __syncthreads();
  for (int it = tid; it < R*256; it += 512){
    int j = it & 255, r = it>>8;
    hss[r][j] = hs0[r][j] + hs1[r][j];
  }
  __syncthreads();

  {
    int role = tid >> 6, cl = tid & 63;
    int gate = role & 3, dh = role >> 2;
    int col = s*64 + cl;
    if (gate < 3){
      const unsigned short* wrow = W16 + (size_t)(col + gate*256)*256;
      const uint4* w4 = (const uint4*)(wrow + dh*128);
      float acc[R];
      #pragma unroll
      for (int r = 0; r < R; ++r) acc[r] = 0.f;
      #pragma unroll 4
      for (int k = 0; k < 16; ++k){
        uint4 w = w4[k];
        #pragma unroll
        for (int r = 0; r < R; ++r)
          acc[r] += dot8b(w, (const float4*)(&hss[r][dh*128 + k*8]));
      }
      #pragma unroll
      for (int r = 0; r < R; ++r) sP[gate*2+dh][r][cl] = acc[r];
    } else {
      const uint4* w4 = (const uint4*)(W16 + B16_FH + (size_t)col*256 + dh*128);
      float a0[R], a1[R];
      #pragma unroll
      for (int r = 0; r < R; ++r){ a0[r] = 0.f; a1[r] = 0.f; }
      #pragma unroll 4
      for (int k = 0; k < 16; ++k){
        uint4 w = w4[k];
        #pragma unroll
        for (int r = 0; r < R; ++r){
          a0[r] += dot8b(w, (const float4*)(&hs0[r][dh*128 + k*8]));
          a1[r] += dot8b(w, (const float4*)(&hs1[r][dh*128 + k*8]));
        }
      }
      #pragma unroll
      for (int r = 0; r < R; ++r){ sP[6+dh][r][cl] = a0[r]; sP[8+dh][r][cl] = a1[r]; }
    }
  }
  __syncthreads();
  if (tid < 64*R){
    int r = tid >> 6, cl = tid & 63;
    int t = s*64 + cl;
    int n = n0 + r;
    float ai  = sP[0][r][cl] + sP[1][r][cl];
    float ao  = sP[2][r][cl] + sP[3][r][cl];
    float au  = sP[4][r][cl] + sP[5][r][cl];
    float af0 = sP[6][r][cl] + sP[7][r][cl];
    float af1 = sP[8][r][cl] + sP[9][r][cl];
    float c0 = cmat[(size_t)(offPrev+2*n)*256 + t];
    float c1 = cmat[(size_t)(offPrev+2*n+1)*256 + t];
    float i_ = sigmf(ai + b_iouh[t]);
    float o_ = sigmf(ao + b_iouh[256+t]);
    float u_ = tanhfast(au + b_iouh[512+t]);
    float bf = b_fh[t];
    float c = i_*u_ + sigmf(af0+bf)*c0 + sigmf(af1+bf)*c1;
    float h = o_*tanhfast(c);
    cmat[(size_t)(offCur+n)*256 + t] = c;
    hmat[(size_t)(offCur+n)*256 + t] = h;
  }
}

// ---------------------------------------------------------------------------
// Mid: proj rows (blocks 0..127) + colsums (128,129). 256 threads.
// ---------------------------------------------------------------------------
__global__ void __launch_bounds__(256) k_mid2(
    const float* __restrict__ W_attnh, const float* __restrict__ b_attnh,
    const float* __restrict__ matA, const float* __restrict__ matB,
    float* __restrict__ projA, float* __restrict__ projB,
    float* __restrict__ colA, float* __restrict__ colB)
{
  int b = blockIdx.x, tid = threadIdx.x;
  if (b < 128){
    int p = b>>6, ch = b&63, m0 = ch*8, mc = min(8, 511-m0);
    const float* mat = p ? matB : matA;
    float* proj = p ? projB : projA;
    __shared__ __align__(16) float ms[256*8];   // ms[e*8+rr]
    for (int j = tid; j < mc*256; j += 256){
      int rr = j>>8, e = j&255;
      ms[e*8+rr] = mat[(size_t)(m0+rr)*256 + e];
    }
    for (int j = tid + mc*256; j < 8*256; j += 256){
      int rr = j>>8, e = j&255; ms[e*8+rr] = 0.f;
    }
    __syncthreads();
    int t = tid;
    const float4* w2 = (const float4*)(W_attnh + (size_t)t*512 + 256);
    float acc[8] = {0,0,0,0,0,0,0,0};
    #pragma unroll 2
    for (int k = 0; k < 64; ++k){
      float4 w = w2[k];
      const float* base = ms + k*32;
      #pragma unroll
      for (int rr = 0; rr < 8; ++rr)
        acc[rr] += w.x*base[rr] + w.y*base[8+rr] + w.z*base[16+rr] + w.w*base[24+rr];
    }
    float ba = b_attnh[t];
    for (int rr = 0; rr < mc; ++rr) proj[(size_t)(m0+rr)*256 + t] = acc[rr] + ba;
  } else {
    int p = b - 128;
    const float* mat = p ? matB : matA;
    float* col = p ? colB : colA;
    float s = 0.f;
    #pragma unroll 8
    for (int m = 0; m < 511; ++m) s += mat[(size_t)m*256 + tid];
    col[tid] = s;
  }
}

// ---------------------------------------------------------------------------
// Leaf scores: one block per (pass, leaf row 0..255). 512 threads.
// ---------------------------------------------------------------------------
__global__ void __launch_bounds__(512) k_scores0(
    const unsigned short* __restrict__ W16, const float* __restrict__ Wa,
    const float* __restrict__ matA, const float* __restrict__ matB,
    const float* __restrict__ projA, const float* __restrict__ projB,
    float* __restrict__ wsum, float* __restrict__ esum)
{
  int bid = blockIdx.x, tid = threadIdx.x;
  int p = bid >> 8, row = bid & 255;
  const float* childH = p ? matA : matB;   // C<-B leaves, D<-A leaves
  const float* proj   = p ? projB : projA;
  const float* mat    = p ? matB  : matA;
  __shared__ __align__(16) float sh[256];
  __shared__ __align__(16) float arena[3136];
  if (tid < 256) sh[tid] = childH[(size_t)row*256 + tid];
  __syncthreads();
  attend_scores_block(tid, p, row, sh, proj, mat, W16, Wa, wsum, esum, arena);
}

// ---------------------------------------------------------------------------
// CD level: one block per output row (grid 2*Nc). 512 threads.
// Phase1 attend-finish children; phase2 gates (s-loop over col quarters);
// then block-local scores for the new row.
// ---------------------------------------------------------------------------
__global__ void __launch_bounds__(512) k_cdlevel(
    const unsigned short* __restrict__ W16, const float* __restrict__ b_iouh,
    const float* __restrict__ b_fh,
    int Nc, int offPrev, int offCur,
    const float* __restrict__ colA, const float* __restrict__ colB,
    float* __restrict__ wsum, float* __restrict__ esum,
    const float* __restrict__ childHC, const float* __restrict__ childHD,
    const float* __restrict__ childCC, const float* __restrict__ childCD_,
    float* __restrict__ cmatC, float* __restrict__ cmatD,
    float* __restrict__ hstageC, float* __restrict__ hstageD,
    const float* __restrict__ projA, const float* __restrict__ projB,
    const float* __restrict__ matA, const float* __restrict__ matB,
    const float* __restrict__ Wa)
{
  int bid = blockIdx.x, tid = threadIdx.x;
  int p = (bid >= Nc) ? 1 : 0;
  int n0 = bid - p*Nc;
  const float* colv   = p ? colB : colA;
  const float* childH = p ? childHD : childHC;
  const float* childC = p ? childCD_ : childCC;
  float* cmat   = p ? cmatD : cmatC;
  float* hstage = p ? hstageD : hstageC;
  const float* proj = p ? projB : projA;
  const float* mat  = p ? matB  : matA;

  __shared__ __align__(16) float hs0[256], hs1[256], hss[256];
  __shared__ __align__(16) float sP[640];
  __shared__ __align__(16) float sh[256];
  __shared__ __align__(16) float arena[3136];

  // Phase 1: attend-finish both children
  {
    int j = tid & 255, ch = tid >> 8;
    int rc = offPrev + 2*n0 + ch;
    float w  = wsum[((size_t)p*511 + rc)*256 + j];
    float es = esum[(size_t)p*511 + rc];
    float hatt = colv[j] - w*rcpf(es) + childH[(size_t)rc*256 + j];
    if (ch) hs1[j] = hatt; else hs0[j] = hatt;
  }
  __syncthreads();
  if (tid < 256) hss[tid] = hs0[tid] + hs1[tid];
  __syncthreads();

  // Phase 2: gates, s-loop over column quarters
  {
    int role = tid >> 6, cl = tid & 63;
    int gate = role & 3, dh = role >> 2;
    for (int s = 0; s < 4; ++s){
      int col = s*64 + cl;
      if (gate < 3){
        const unsigned short* wrow = W16 + (size_t)(col + gate*256)*256;
        const uint4* w4 = (const uint4*)(wrow + dh*128);
        float acc = 0.f;
        #pragma unroll 4
        for (int k = 0; k < 16; ++k)
          acc += dot8b(w4[k], (const float4*)(hss + dh*128 + k*8));
        sP[(gate*2+dh)*64 + cl] = acc;
      } else {
        const uint4* w4 = (const uint4*)(W16 + B16_FH + (size_t)col*256 + dh*128);
        float a0 = 0.f, a1 = 0.f;
        #pragma unroll 4
        for (int k = 0; k < 16; ++k){
          uint4 w = w4[k];
          a0 += dot8b(w, (const float4*)(hs0 + dh*128 + k*8));
          a1 += dot8b(w, (const float4*)(hs1 + dh*128 + k*8));
        }
        sP[(6+dh)*64 + cl] = a0;
        sP[(8+dh)*64 + cl] = a1;
      }
      __syncthreads();
      if (tid < 64){
        int t = s*64 + tid;
        float ai  = sP[0*64+tid] + sP[1*64+tid];
        float ao  = sP[2*64+tid] + sP[3*64+tid];
        float au  = sP[4*64+tid] + sP[5*64+tid];
        float af0 = sP[6*64+tid] + sP[7*64+tid];
        float af1 = sP[8*64+tid] + sP[9*64+tid];
        float c0 = childC[(size_t)(offPrev+2*n0)*256 + t];
        float c1 = childC[(size_t)(offPrev+2*n0+1)*256 + t];
        float i_ = sigmf(ai + b_iouh[t]);
        float o_ = sigmf(ao + b_iouh[256+t]);
        float u_ = tanhfast(au + b_iouh[512+t]);
        float bf = b_fh[t];
        float c = i_*u_ + sigmf(af0+bf)*c0 + sigmf(af1+bf)*c1;
        float h = o_*tanhfast(c);
        cmat[(size_t)(offCur+n0)*256 + t] = c;
        hstage[(size_t)(offCur+n0)*256 + t] = h;
        sh[t] = h;
      }
      __syncthreads();
    }
  }

  // Block-local scores for the new row (writes wsum/esum[offCur+n0];
  // disjoint from the child rows other blocks read -> no intra-kernel race).
  attend_scores_block(tid, p, offCur + n0, sh, proj, mat, W16, Wa,
                      wsum, esum, arena);
}

// ---------------------------------------------------------------------------
// Head: finish row 510 of C and D, then MLP + log_softmax. 1 block x 256.
// ---------------------------------------------------------------------------
__global__ void __launch_bounds__(256) k_head(
    const float* __restrict__ W_wh, const float* __restrict__ b_wh,
    const float* __restrict__ W_wp, const float* __restrict__ b_wp,
    const float* __restrict__ matA, const float* __restrict__ matB,
    const float* __restrict__ colA, const float* __restrict__ colB,
    const float* __restrict__ wsum, const float* __restrict__ esum,
    const float* __restrict__ hstageC, const float* __restrict__ hstageD,
    float* __restrict__ out)
{
  __shared__ __align__(16) float v[512];
  __shared__ float og[128], lg[5];
  int t = threadIdx.x;
  {
    float wC = wsum[((size_t)0*511 + 510)*256 + t];
    float eC = esum[(size_t)0*511 + 510];
    float hCf = colA[t] - wC*rcpf(eC) + hstageC[(size_t)510*256 + t];
    float wD = wsum[((size_t)1*511 + 510)*256 + t];
    float eD = esum[(size_t)1*511 + 510];
    float hDf = colB[t] - wD*rcpf(eD) + hstageD[(size_t)510*256 + t];
    float lh = tanhfast(matA[(size_t)510*256 + t] + hDf);
    float rh = tanhfast(hCf + matB[(size_t)510*256 + t]);
    v[t] = lh*rh;
    v[256+t] = fabsf(lh - rh);
  }
  __syncthreads();
  if (t < 128){
    const float4* w = (const float4*)(W_wh + (size_t)t*512);
    const float4* vv = (const float4*)v;
    float a = b_wh[t];
    #pragma unroll 4
    for (int k = 0; k < 128; ++k){
      float4 wv = w[k], x = vv[k];
      a += wv.x*x.x + wv.y*x.y + wv.z*x.z + wv.w*x.w;
    }
    og[t] = sigmf(a);
  }
  __syncthreads();
  if (t < 5){
    const float* wp = W_wp + (size_t)t*128;
    float a = b_wp[t];
    for (int j = 0; j < 128; ++j) a += og[j]*wp[j];
    lg[t] = a;
  }
  __syncthreads();
  if (t == 0){
    float M = -1e30f;
    for (int c = 0; c < 5; ++c) M = fmaxf(M, lg[c]);
    float S = 0.f;
    for (int c = 0; c < 5; ++c) S += __expf(lg[c] - M);
    float L = logf(S);
    for (int c = 0; c < 5; ++c) out[c] = lg[c] - M - L;
  }
}

extern "C" void kernel_launch(void* const* d_in, const int* in_sizes, int n_in,
                              void* d_out, int out_size, void* d_ws, size_t ws_size,
                              hipStream_t stream)
{
  const int*   l_idx   = (const int*)  d_in[0];
  const int*   r_idx   = (const int*)  d_in[1];
  const float* emb     = (const float*)d_in[2];
  const float* W_ioux  = (const float*)d_in[3];
  const float* b_ioux  = (const float*)d_in[4];
  const float* W_iouh  = (const float*)d_in[5];
  const float* b_iouh  = (const float*)d_in[6];
  // d_in[7]=W_fx, d_in[8]=b_fx unused by the forward
  const float* W_fh    = (const float*)d_in[9];
  const float* b_fh    = (const float*)d_in[10];
  const float* Wa      = (const float*)d_in[11];
  const float* W_attnh = (const float*)d_in[12];
  const float* b_attnh = (const float*)d_in[13];
  const float* W_wh    = (const float*)d_in[14];
  const float* b_wh    = (const float*)d_in[15];
  const float* W_wp    = (const float*)d_in[16];
  const float* b_wp    = (const float*)d_in[17];

  float* ws = (float*)d_ws;
  float* cmatA   = ws;               float* cmatB   = cmatA + RC;
  float* cmatC   = cmatB + RC;       float* cmatD   = cmatC + RC;
  float* matA    = cmatD + RC;       float* matB    = matA + RC;
  float* hstageC = matB + RC;        float* hstageD = hstageC + RC;
  float* projA   = hstageD + RC;     float* projB   = projA + RC;
  float* colA    = projB + RC;       float* colB    = colA + 256;
  float* wsum    = colB + 256;            // 2*511*256
  float* esum    = wsum + 2*511*256;      // 2*511 (padded to 1024)
  unsigned short* W16 = (unsigned short*)(esum + 1024);  // 327,680 ushorts

  static const int offs[9] = {0, 256, 384, 448, 480, 496, 504, 508, 510};

  k_init<<<288, 768, 0, stream>>>(l_idx, r_idx, emb, W_ioux, b_ioux, b_iouh,
                                  W_iouh, W_fh, W_attnh,
                                  cmatA, matA, cmatB, matB, (unsigned*)W16);
  for (int i = 1; i <= 8; ++i){
    int Nc = 256 >> i;
    int oP = offs[i-1], oC = offs[i];
    if (Nc >= 128)
      k_levelAB<4><<<(2*Nc/4)*4, 512, 0, stream>>>(W16, b_iouh, b_fh, Nc, oP, oC,
                                                   cmatA, matA, cmatB, matB);
    else if (Nc >= 64)
      k_levelAB<2><<<(2*Nc/2)*4, 512, 0, stream>>>(W16, b_iouh, b_fh, Nc, oP, oC,
                                                   cmatA, matA, cmatB, matB);
    else
      k_levelAB<1><<<(2*Nc)*4, 512, 0, stream>>>(W16, b_iouh, b_fh, Nc, oP, oC,
                                                 cmatA, matA, cmatB, matB);
  }
  k_mid2<<<130, 256, 0, stream>>>(W_attnh, b_attnh, matA, matB,
                                  projA, projB, colA, colB);
  k_scores0<<<512, 512, 0, stream>>>(W16, Wa, matA, matB, projA, projB,
                                     wsum, esum);
  for (int i = 1; i <= 8; ++i){
    int Nc = 256 >> i;
    const float* childHC = (i == 1) ? matB  : hstageC;  // C's children h
    const float* childHD = (i == 1) ? matA  : hstageD;
    const float* childCC = (i == 1) ? cmatB : cmatC;
    const float* childCD = (i == 1) ? cmatA : cmatD;
    k_cdlevel<<<2*Nc, 512, 0, stream>>>(W16, b_iouh, b_fh, Nc, offs[i-1], offs[i],
                                        colA, colB, wsum, esum,
                                        childHC, childHD, childCC, childCD,
                                        cmatC, cmatD, hstageC, hstageD,
                                        projA, projB, matA, matB, Wa);
  }
  k_head<<<1, 256, 0, stream>>>(W_wh, b_wh, W_wp, b_wp, matA, matB,
                                colA, colB, wsum, esum, hstageC, hstageD,
                                (float*)d_out);
}

// Round 6
// 734.575 us; speedup vs baseline: 1.8015x; 1.2579x over previous
//
#include <hip/hip_runtime.h>

#define RC 130816   // 511*256
#define MT 512      // matT m-stride (511 zero-padded)

// bf16 weight cache layout (ushort offsets)
#define B16_FH   196608   // after 768*256 iou rows
#define B16_W1   262144   // 256*256 (W_attnh[:, :256])

__device__ __forceinline__ float rcpf(float x){ return __builtin_amdgcn_rcpf(x); }
__device__ __forceinline__ float sigmf(float x){ return rcpf(1.f + __expf(-x)); }
__device__ __forceinline__ float tanhfast(float x){
  return 1.f - 2.f*rcpf(1.f + __expf(2.f*x));
}

// ---- bf16-as-integer helpers ----
__device__ __forceinline__ float bfl(unsigned x){ return __uint_as_float(x << 16); }
__device__ __forceinline__ float bfh(unsigned x){ return __uint_as_float(x & 0xFFFF0000u); }
__device__ __forceinline__ unsigned bpack(float a, float b){
  unsigned ua = __float_as_uint(a), ub = __float_as_uint(b);
  return ((ua + 0x7FFFu + ((ua>>16)&1u)) >> 16)
       | ((ub + 0x7FFFu + ((ub>>16)&1u)) & 0xFFFF0000u);
}
__device__ __forceinline__ float dot8b(uint4 w, const float4* s4){
  float4 s0 = s4[0], s1 = s4[1];
  return bfl(w.x)*s0.x + bfh(w.x)*s0.y + bfl(w.y)*s0.z + bfh(w.y)*s0.w
       + bfl(w.z)*s1.x + bfh(w.z)*s1.y + bfl(w.w)*s1.z + bfh(w.w)*s1.w;
}

// ---------------------------------------------------------------------------
// Init (blocks 0..255) + weight pack (blocks 256..287). 768 threads.
// (verified round 5)
// ---------------------------------------------------------------------------
__global__ void __launch_bounds__(768) k_init(
    const int* __restrict__ l_idx, const int* __restrict__ r_idx,
    const float* __restrict__ emb, const float* __restrict__ W_ioux,
    const float* __restrict__ b_ioux, const float* __restrict__ b_iouh,
    const float* __restrict__ W_iouh, const float* __restrict__ W_fh,
    const float* __restrict__ W_attnh,
    float* __restrict__ cmatA, float* __restrict__ matA,
    float* __restrict__ cmatB, float* __restrict__ matB,
    unsigned* __restrict__ W16u)
{
  int b = blockIdx.x, tid = threadIdx.x;
  if (b >= 256){
    int gid = (b - 256)*768 + tid, gs = 32*768;
    for (int k = gid; k < 98304; k += gs){
      int i = 2*k; W16u[k] = bpack(W_iouh[i], W_iouh[i+1]);
    }
    for (int k = gid; k < 32768; k += gs){
      int i = 2*k; W16u[98304 + k] = bpack(W_fh[i], W_fh[i+1]);
    }
    for (int k = gid; k < 32768; k += gs){
      int i = 2*k; int t = i>>8, e = i&255;
      const float* r = W_attnh + (size_t)t*512;
      W16u[131072 + k] = bpack(r[e], r[e+1]);
    }
    return;
  }
  int p = b >> 7, n0 = (b & 127) * 2;
  __shared__ __align__(16) float xs[2*304];
  __shared__ float sg[2*768];
  for (int j = tid; j < 600; j += 768){
    int rr = j/300, d = j - rr*300;
    int row = p ? r_idx[n0+rr] : l_idx[n0+rr];
    xs[rr*304 + d] = emb[(size_t)row*300 + d];
  }
  __syncthreads();
  const float4* w = (const float4*)(W_ioux + (size_t)tid*300);
  float a0 = 0.f, a1 = 0.f;
  #pragma unroll 5
  for (int k = 0; k < 75; ++k){
    float4 wv = w[k];
    const float* x0 = xs + 4*k;
    const float* x1 = xs + 304 + 4*k;
    a0 += wv.x*x0[0] + wv.y*x0[1] + wv.z*x0[2] + wv.w*x0[3];
    a1 += wv.x*x1[0] + wv.y*x1[1] + wv.z*x1[2] + wv.w*x1[3];
  }
  float bb = b_ioux[tid] + b_iouh[tid];
  sg[tid] = a0 + bb;
  sg[768 + tid] = a1 + bb;
  __syncthreads();
  if (tid < 512){
    int rr = tid >> 8, t = tid & 255;
    const float* g = sg + rr*768;
    float c = sigmf(g[t]) * tanhfast(g[512+t]);
    float h = sigmf(g[256+t]) * tanhfast(c);
    (p ? cmatB : cmatA)[(size_t)(n0+rr)*256 + t] = c;
    (p ? matB  : matA )[(size_t)(n0+rr)*256 + t] = h;
  }
}

// ---------------------------------------------------------------------------
// A/B tree level (verified baseline).
// ---------------------------------------------------------------------------
template<int R>
__global__ void __launch_bounds__(512) k_levelAB(
    const unsigned short* __restrict__ W16, const float* __restrict__ b_iouh,
    const float* __restrict__ b_fh,
    int Nc, int offPrev, int offCur,
    float* __restrict__ cmatA, float* __restrict__ matA,
    float* __restrict__ cmatB, float* __restrict__ matB)
{
  int bid = blockIdx.x, tid = threadIdx.x;
  int s = bid & 3, g2 = bid >> 2;
  int groups = Nc / R;
  int p = (g2 >= groups) ? 1 : 0;
  int n0 = (g2 - p*groups) * R;
  float* cmat = p ? cmatB : cmatA;
  float* hmat = p ? matB  : matA;

  __shared__ __align__(16) float hs0[R][256], hs1[R][256], hss[R][256];
  __shared__ float sP[10][R][64];

  for (int it = tid; it < R*2*256; it += 512){
    int j = it & 255, ch = (it>>8)&1, r = it>>9;
    float v = hmat[(size_t)(offPrev + 2*(n0+r) + ch)*256 + j];
    if (ch) hs1[r][j] = v; else hs0[r][j] = v;
  }
  __syncthreads();
  for (int it = tid; it < R*256; it += 512){
    int j = it & 255, r = it>>8;
    hss[r][j] = hs0[r][j] + hs1[r][j];
  }
  __syncthreads();

  {
    int role = tid >> 6, cl = tid & 63;
    int gate = role & 3, dh = role >> 2;
    int col = s*64 + cl;
    if (gate < 3){
      const unsigned short* wrow = W16 + (size_t)(col + gate*256)*256;
      const uint4* w4 = (const uint4*)(wrow + dh*128);
      float acc[R];
      #pragma unroll
      for (int r = 0; r < R; ++r) acc[r] = 0.f;
      #pragma unroll 4
      for (int k = 0; k < 16; ++k){
        uint4 w = w4[k];
        #pragma unroll
        for (int r = 0; r < R; ++r)
          acc[r] += dot8b(w, (const float4*)(&hss[r][dh*128 + k*8]));
      }
      #pragma unroll
      for (int r = 0; r < R; ++r) sP[gate*2+dh][r][cl] = acc[r];
    } else {
      const uint4* w4 = (const uint4*)(W16 + B16_FH + (size_t)col*256 + dh*128);
      float a0[R], a1[R];
      #pragma unroll
      for (int r = 0; r < R; ++r){ a0[r] = 0.f; a1[r] = 0.f; }
      #pragma unroll 4
      for (int k = 0; k < 16; ++k){
        uint4 w = w4[k];
        #pragma unroll
        for (int r = 0; r < R; ++r){
          a0[r] += dot8b(w, (const float4*)(&hs0[r][dh*128 + k*8]));
          a1[r] += dot8b(w, (const float4*)(&hs1[r][dh*128 + k*8]));
        }
      }
      #pragma unroll
      for (int r = 0; r < R; ++r){ sP[6+dh][r][cl] = a0[r]; sP[8+dh][r][cl] = a1[r]; }
    }
  }
  __syncthreads();
  if (tid < 64*R){
    int r = tid >> 6, cl = tid & 63;
    int t = s*64 + cl;
    int n = n0 + r;
    float ai  = sP[0][r][cl] + sP[1][r][cl];
    float ao  = sP[2][r][cl] + sP[3][r][cl];
    float au  = sP[4][r][cl] + sP[5][r][cl];
    float af0 = sP[6][r][cl] + sP[7][r][cl];
    float af1 = sP[8][r][cl] + sP[9][r][cl];
    float c0 = cmat[(size_t)(offPrev+2*n)*256 + t];
    float c1 = cmat[(size_t)(offPrev+2*n+1)*256 + t];
    float i_ = sigmf(ai + b_iouh[t]);
    float o_ = sigmf(ao + b_iouh[256+t]);
    float u_ = tanhfast(au + b_iouh[512+t]);
    float bf = b_fh[t];
    float c = i_*u_ + sigmf(af0+bf)*c0 + sigmf(af1+bf)*c1;
    float h = o_*tanhfast(c);
    cmat[(size_t)(offCur+n)*256 + t] = c;
    hmat[(size_t)(offCur+n)*256 + t] = h;
  }
}

// ---------------------------------------------------------------------------
// AB tail: levels 5-8 (Nc=8,4,2,1) in one kernel. Grid = 2 blocks (pass).
// Inter-level state kept in LDS (rows 496..510 -> allH/allC[row-496]).
// Level 5 children (rows 480..495) read from global (prior launch).
// Gates logic = verified round-5 phase-2 code.
// ---------------------------------------------------------------------------
__global__ void __launch_bounds__(512) k_ab_tail(
    const unsigned short* __restrict__ W16, const float* __restrict__ b_iouh,
    const float* __restrict__ b_fh,
    float* __restrict__ cmatA, float* __restrict__ matA,
    float* __restrict__ cmatB, float* __restrict__ matB)
{
  int p = blockIdx.x, tid = threadIdx.x;
  float* cmat = p ? cmatB : cmatA;
  float* hmat = p ? matB  : matA;
  __shared__ __align__(16) float allH[15][256], allC[15][256];
  __shared__ __align__(16) float hs0[256], hs1[256], hss[256];
  __shared__ float sP[640];
  const int offsL[5] = {480, 496, 504, 508, 510};

  for (int li = 0; li < 4; ++li){
    int Nc = 8 >> li;
    int oP = offsL[li], oC = offsL[li+1];
    for (int n = 0; n < Nc; ++n){
      {
        int j = tid & 255, ch = tid >> 8;
        int rc = oP + 2*n + ch;
        float v = (li == 0) ? hmat[(size_t)rc*256 + j] : allH[rc - 496][j];
        if (ch) hs1[j] = v; else hs0[j] = v;
      }
      __syncthreads();
      if (tid < 256) hss[tid] = hs0[tid] + hs1[tid];
      __syncthreads();
      int role = tid >> 6, cl = tid & 63;
      int gate = role & 3, dh = role >> 2;
      for (int s = 0; s < 4; ++s){
        int col = s*64 + cl;
        if (gate < 3){
          const uint4* w4 = (const uint4*)(W16 + (size_t)(col + gate*256)*256 + dh*128);
          float acc = 0.f;
          #pragma unroll 4
          for (int k = 0; k < 16; ++k)
            acc += dot8b(w4[k], (const float4*)(hss + dh*128 + k*8));
          sP[(gate*2+dh)*64 + cl] = acc;
        } else {
          const uint4* w4 = (const uint4*)(W16 + B16_FH + (size_t)col*256 + dh*128);
          float a0 = 0.f, a1 = 0.f;
          #pragma unroll 4
          for (int k = 0; k < 16; ++k){
            uint4 w = w4[k];
            a0 += dot8b(w, (const float4*)(hs0 + dh*128 + k*8));
            a1 += dot8b(w, (const float4*)(hs1 + dh*128 + k*8));
          }
          sP[(6+dh)*64 + cl] = a0;
          sP[(8+dh)*64 + cl] = a1;
        }
        __syncthreads();
        if (tid < 64){
          int t = s*64 + tid;
          float ai  = sP[0*64+tid] + sP[1*64+tid];
          float ao  = sP[2*64+tid] + sP[3*64+tid];
          float au  = sP[4*64+tid] + sP[5*64+tid];
          float af0 = sP[6*64+tid] + sP[7*64+tid];
          float af1 = sP[8*64+tid] + sP[9*64+tid];
          int rc0 = oP + 2*n;
          float c0 = (li==0) ? cmat[(size_t)rc0*256 + t]     : allC[rc0-496][t];
          float c1 = (li==0) ? cmat[(size_t)(rc0+1)*256 + t] : allC[rc0+1-496][t];
          float i_ = sigmf(ai + b_iouh[t]);
          float o_ = sigmf(ao + b_iouh[256+t]);
          float u_ = tanhfast(au + b_iouh[512+t]);
          float bf = b_fh[t];
          float c = i_*u_ + sigmf(af0+bf)*c0 + sigmf(af1+bf)*c1;
          float h = o_*tanhfast(c);
          cmat[(size_t)(oC+n)*256 + t] = c;
          hmat[(size_t)(oC+n)*256 + t] = h;
          allC[oC+n-496][t] = c;
          allH[oC+n-496][t] = h;
        }
        __syncthreads();
      }
    }
  }
}

// ---------------------------------------------------------------------------
// Mid: proj rows (0..127), colsums (128,129), matT transposes (130..385),
// hp (php slice 0) for the 512 init rows of C/D (386..449). (verified)
// ---------------------------------------------------------------------------
__global__ void __launch_bounds__(256) k_mid(
    const float* __restrict__ W_attnh, const float* __restrict__ b_attnh,
    const float* __restrict__ matA, const float* __restrict__ matB,
    float* __restrict__ projA, float* __restrict__ projB,
    float* __restrict__ colA, float* __restrict__ colB,
    float* __restrict__ matTA, float* __restrict__ matTB,
    float* __restrict__ php)
{
  int b = blockIdx.x, tid = threadIdx.x;
  if (b < 128){
    int p = b>>6, ch = b&63, m0 = ch*8, mc = min(8, 511-m0);
    const float* mat = p ? matB : matA;
    float* proj = p ? projB : projA;
    __shared__ __align__(16) float ms[256*8];   // ms[e*8+rr]
    for (int j = tid; j < mc*256; j += 256){
      int rr = j>>8, e = j&255;
      ms[e*8+rr] = mat[(size_t)(m0+rr)*256 + e];
    }
    for (int j = tid + mc*256; j < 8*256; j += 256){
      int rr = j>>8, e = j&255; ms[e*8+rr] = 0.f;
    }
    __syncthreads();
    int t = tid;
    const float4* w2 = (const float4*)(W_attnh + (size_t)t*512 + 256);
    float acc[8] = {0,0,0,0,0,0,0,0};
    #pragma unroll 2
    for (int k = 0; k < 64; ++k){
      float4 w = w2[k];
      const float* base = ms + k*32;
      #pragma unroll
      for (int rr = 0; rr < 8; ++rr)
        acc[rr] += w.x*base[rr] + w.y*base[8+rr] + w.z*base[16+rr] + w.w*base[24+rr];
    }
    float ba = b_attnh[t];
    for (int rr = 0; rr < mc; ++rr) proj[(size_t)(m0+rr)*256 + t] = acc[rr] + ba;
  } else if (b < 130){
    int p = b - 128;
    const float* mat = p ? matB : matA;
    float* col = p ? colB : colA;
    float s = 0.f;
    #pragma unroll 8
    for (int m = 0; m < 511; ++m) s += mat[(size_t)m*256 + tid];
    col[tid] = s;
  } else if (b < 386){
    int idx = b - 130;
    int p = idx>>7, rem = idx&127, jt = rem>>4, mt = rem&15;
    const float* mat = p ? matB : matA;
    float* matT = p ? matTB : matTA;
    __shared__ float tile[32][33];
    int c = tid&31, r0 = tid>>5;
    int m0 = mt*32, j0 = jt*32;
    #pragma unroll
    for (int k = 0; k < 4; ++k){
      int m = m0 + r0 + 8*k;
      tile[r0+8*k][c] = (m < 511) ? mat[(size_t)m*256 + j0 + c] : 0.f;
    }
    __syncthreads();
    #pragma unroll
    for (int k = 0; k < 4; ++k){
      int jj = r0 + 8*k;
      matT[(size_t)(j0+jj)*MT + m0 + c] = tile[c][jj];
    }
  } else {
    int idx = b - 386;           // 64 blocks: p (C/D) x 32 chunks of 8 rows
    int p = idx>>5, ch = idx&31, r0 = ch*8;
    const float* hsrc = p ? matA : matB;   // C<-B, D<-A
    __shared__ __align__(16) float ms[256*8];
    for (int j = tid; j < 8*256; j += 256){
      int rr = j>>8, e = j&255;
      ms[e*8+rr] = hsrc[(size_t)(r0+rr)*256 + e];
    }
    __syncthreads();
    int t = tid;
    const float4* w1 = (const float4*)(W_attnh + (size_t)t*512);
    float acc[8] = {0,0,0,0,0,0,0,0};
    #pragma unroll 2
    for (int k = 0; k < 64; ++k){
      float4 w = w1[k];
      const float* base = ms + k*32;
      #pragma unroll
      for (int rr = 0; rr < 8; ++rr)
        acc[rr] += w.x*base[rr] + w.y*base[8+rr] + w.z*base[16+rr] + w.w*base[24+rr];
    }
    #pragma unroll
    for (int rr = 0; rr < 8; ++rr)
      php[(((size_t)p*511 + r0+rr)*4 + 0)*256 + t] = acc[rr];
  }
}

// ---------------------------------------------------------------------------
// Tiled scores (verified baseline + tanh fold).
// tanh(x) = 1 - 2*rcp(1+exp2(C*x)), C = 2*log2(e). shp pre-scaled by C;
// proj scaled once per k-iter. score = SumWa - 2*partR; the constant
// exp(SumWa) factor scales wsum AND esum identically and cancels in the
// consumed ratio wsum/esum, so it is dropped: e_m = exp(-2*partR_m).
// ---------------------------------------------------------------------------
template<int G>
__global__ void __launch_bounds__(256) k_scores_t(
    const float* __restrict__ php,
    const float* __restrict__ projA, const float* __restrict__ projB,
    const float* __restrict__ matTA, const float* __restrict__ matTB,
    const float* __restrict__ Wa, int Nc, int rowOff, int S,
    float* __restrict__ wsumP, float* __restrict__ esumP)
{
  const float CE = 2.885390082f;   // 2*log2(e)
  int b = blockIdx.x, tid = threadIdx.x;
  int groups = Nc / G;
  int per = groups * 4;
  int p = b / per; int rem = b - p*per; int g = rem >> 2, ch = rem & 3;
  int row0 = rowOff + g*G;
  const float* proj = p ? projB : projA;
  const float* matT = p ? matTB : matTA;

  __shared__ __align__(16) float shp[G*256];
  __shared__ __align__(16) float swa[256];
  __shared__ __align__(16) float spart[G*256];
  __shared__ __align__(16) float se[G*128];

  for (int j = tid; j < G*256; j += 256){
    int row = row0 + (j>>8), jj = j&255;
    const float* base = php + (((size_t)p*511 + row)*4)*256 + jj;
    float v = base[0];
    if (S == 4) v += base[256] + base[512] + base[768];
    shp[j] = v * CE;
  }
  swa[tid] = Wa[tid];
  __syncthreads();

  int ml = tid & 127, dh = tid >> 7;
  int m = ch*128 + ml;
  float part[G];
  #pragma unroll
  for (int r = 0; r < G; ++r) part[r] = 0.f;
  if (m < 511){
    const float4* pr  = (const float4*)(proj + (size_t)m*256 + dh*128);
    const float4* wa4 = (const float4*)(swa + dh*128);
    #pragma unroll 4
    for (int k = 0; k < 32; ++k){
      float4 pv = pr[k], wv = wa4[k];
      float p0 = pv.x*CE, p1 = pv.y*CE, p2 = pv.z*CE, p3 = pv.w*CE;
      int dbase = dh*128 + k*4;
      #pragma unroll
      for (int r = 0; r < G; ++r){
        const float* hr = shp + r*256 + dbase;
        part[r] += wv.x*rcpf(1.f + exp2f(hr[0]+p0))
                 + wv.y*rcpf(1.f + exp2f(hr[1]+p1))
                 + wv.z*rcpf(1.f + exp2f(hr[2]+p2))
                 + wv.w*rcpf(1.f + exp2f(hr[3]+p3));
      }
    }
  }
  #pragma unroll
  for (int r = 0; r < G; ++r) spart[r*256 + tid] = part[r];
  __syncthreads();
  if (tid < 128){
    #pragma unroll
    for (int r = 0; r < G; ++r){
      float s = spart[r*256 + ml] + spart[r*256 + 128 + ml];
      se[r*128 + ml] = (ch*128 + ml < 511) ? __expf(-2.f*s) : 0.f;
    }
  }
  __syncthreads();
  {
    const float4* mt = (const float4*)(matT + (size_t)tid*MT + ch*128);
    float acc[G];
    #pragma unroll
    for (int r = 0; r < G; ++r) acc[r] = 0.f;
    #pragma unroll 4
    for (int k = 0; k < 32; ++k){
      float4 mv = mt[k];
      #pragma unroll
      for (int r = 0; r < G; ++r){
        float4 ev = ((const float4*)(se + r*128))[k];
        acc[r] += mv.x*ev.x + mv.y*ev.y + mv.z*ev.z + mv.w*ev.w;
      }
    }
    #pragma unroll
    for (int r = 0; r < G; ++r)
      wsumP[(((size_t)p*511 + row0 + r)*4 + ch)*256 + tid] = acc[r];
  }
  if (tid < G){
    float s = 0.f;
    const float* sr = se + tid*128;
    for (int k = 0; k < 128; ++k) s += sr[k];
    esumP[((size_t)p*511 + row0 + tid)*4 + ch] = s;
  }
}

// ---------------------------------------------------------------------------
// CD spine (verified baseline).
// ---------------------------------------------------------------------------
template<int R>
__global__ void __launch_bounds__(512) k_cd1(
    const unsigned short* __restrict__ W16, const float* __restrict__ b_iouh,
    const float* __restrict__ b_fh,
    int Nc, int offPrev, int offCur,
    const float* __restrict__ colA, const float* __restrict__ colB,
    const float* __restrict__ wsumP, const float* __restrict__ esumP,
    const float* __restrict__ childHC, const float* __restrict__ childHD,
    const float* __restrict__ childCC, const float* __restrict__ childCD_,
    float* __restrict__ cmatC, float* __restrict__ cmatD,
    float* __restrict__ hstageC, float* __restrict__ hstageD,
    float* __restrict__ php)
{
  int bid = blockIdx.x, tid = threadIdx.x;
  int s = bid & 3, g2 = bid >> 2;
  int groups = Nc / R;
  int p = (g2 >= groups) ? 1 : 0;
  int n0 = (g2 - p*groups) * R;
  const float* colv   = p ? colB : colA;
  const float* childH = p ? childHD : childHC;
  const float* childC = p ? childCD_ : childCC;
  float* cmat   = p ? cmatD : cmatC;
  float* hstage = p ? hstageD : hstageC;

  __shared__ __align__(16) float hs0[R][256], hs1[R][256], hss[R][256];
  __shared__ float sP[10][R][64];
  __shared__ __align__(16) float sh[R][64];
  __shared__ float sHP[2][256];

  for (int it = tid; it < R*2*256; it += 512){
    int j = it & 255, ch = (it>>8)&1, r = it>>9;
    int rc = offPrev + 2*(n0+r) + ch;
    const float* wp = wsumP + (((size_t)p*511 + rc)*4)*256;
    const float* ep = esumP + ((size_t)p*511 + rc)*4;
    float w = wp[j] + wp[256+j] + wp[512+j] + wp[768+j];
    float esum = ep[0]+ep[1]+ep[2]+ep[3];
    float hatt = colv[j] - w*rcpf(esum) + childH[(size_t)rc*256 + j];
    if (ch) hs1[r][j] = hatt; else hs0[r][j] = hatt;
  }
  __syncthreads();
  for (int it = tid; it < R*256; it += 512){
    int j = it & 255, r = it>>8;
    hss[r][j] = hs0[r][j] + hs1[r][j];
  }
  __syncthreads();

  {
    int role = tid >> 6, cl = tid & 63;
    int gate = role & 3, dh = role >> 2;
    int col = s*64 + cl;
    if (gate < 3){
      const unsigned short* wrow = W16 + (size_t)(col + gate*256)*256;
      const uint4* w4 = (const uint4*)(wrow + dh*128);
      float acc[R];
      #pragma unroll
      for (int r = 0; r < R; ++r) acc[r] = 0.f;
      #pragma unroll 4
      for (int k = 0; k < 16; ++k){
        uint4 w = w4[k];
        #pragma unroll
        for (int r = 0; r < R; ++r)
          acc[r] += dot8b(w, (const float4*)(&hss[r][dh*128 + k*8]));
      }
      #pragma unroll
      for (int r = 0; r < R; ++r) sP[gate*2+dh][r][cl] = acc[r];
    } else {
      const uint4* w4 = (const uint4*)(W16 + B16_FH + (size_t)col*256 + dh*128);
      float a0[R], a1[R];
      #pragma unroll
      for (int r = 0; r < R; ++r){ a0[r] = 0.f; a1[r] = 0.f; }
      #pragma unroll 4
      for (int k = 0; k < 16; ++k){
        uint4 w = w4[k];
        #pragma unroll
        for (int r = 0; r < R; ++r){
          a0[r] += dot8b(w, (const float4*)(&hs0[r][dh*128 + k*8]));
          a1[r] += dot8b(w, (const float4*)(&hs1[r][dh*128 + k*8]));
        }
      }
      #pragma unroll
      for (int r = 0; r < R; ++r){ sP[6+dh][r][cl] = a0[r]; sP[8+dh][r][cl] = a1[r]; }
    }
  }
  __syncthreads();

  if (tid < 64*R){
    int r = tid >> 6, cl = tid & 63;
    int t = s*64 + cl;
    int n = n0 + r;
    float ai  = sP[0][r][cl] + sP[1][r][cl];
    float ao  = sP[2][r][cl] + sP[3][r][cl];
    float au  = sP[4][r][cl] + sP[5][r][cl];
    float af0 = sP[6][r][cl] + sP[7][r][cl];
    float af1 = sP[8][r][cl] + sP[9][r][cl];
    float c0 = childC[(size_t)(offPrev+2*n)*256 + t];
    float c1 = childC[(size_t)(offPrev+2*n+1)*256 + t];
    float i_ = sigmf(ai + b_iouh[t]);
    float o_ = sigmf(ao + b_iouh[256+t]);
    float u_ = tanhfast(au + b_iouh[512+t]);
    float bf = b_fh[t];
    float c = i_*u_ + sigmf(af0+bf)*c0 + sigmf(af1+bf)*c1;
    float h = o_*tanhfast(c);
    cmat[(size_t)(offCur+n)*256 + t] = c;
    hstage[(size_t)(offCur+n)*256 + t] = h;
    sh[r][cl] = h;
  }
  __syncthreads();

  {
    int j = tid & 255, eh = tid >> 8;
    const uint4* w1 = (const uint4*)(W16 + B16_W1 + (size_t)j*256 + s*64 + eh*32);
    uint4 wv[4];
    #pragma unroll
    for (int k = 0; k < 4; ++k) wv[k] = w1[k];
    float aacc[R];
    #pragma unroll
    for (int r = 0; r < R; ++r){
      float a = 0.f;
      #pragma unroll
      for (int k = 0; k < 4; ++k)
        a += dot8b(wv[k], (const float4*)(&sh[r][eh*32 + k*8]));
      aacc[r] = a;
    }
    #pragma unroll
    for (int r = 0; r < R; ++r){
      sHP[eh][j] = aacc[r];
      __syncthreads();
      if (tid < 256){
        int row = offCur + n0 + r;
        php[(((size_t)p*511 + row)*4 + s)*256 + tid] = sHP[0][tid] + sHP[1][tid];
      }
      __syncthreads();
    }
  }
}

// ---------------------------------------------------------------------------
// Head (verified baseline).
// ---------------------------------------------------------------------------
__global__ void __launch_bounds__(256) k_head(
    const float* __restrict__ W_wh, const float* __restrict__ b_wh,
    const float* __restrict__ W_wp, const float* __restrict__ b_wp,
    const float* __restrict__ matA, const float* __restrict__ matB,
    const float* __restrict__ colA, const float* __restrict__ colB,
    const float* __restrict__ wsumP, const float* __restrict__ esumP,
    const float* __restrict__ hstageC, const float* __restrict__ hstageD,
    float* __restrict__ out)
{
  __shared__ __align__(16) float v[512];
  __shared__ float og[128], lg[5];
  int t = threadIdx.x;
  {
    const float* wpC = wsumP + (((size_t)0*511 + 510)*4)*256;
    const float* epC = esumP + ((size_t)0*511 + 510)*4;
    float wC = wpC[t] + wpC[256+t] + wpC[512+t] + wpC[768+t];
    float eC = epC[0]+epC[1]+epC[2]+epC[3];
    float hCf = colA[t] - wC*rcpf(eC) + hstageC[(size_t)510*256 + t];
    const float* wpD = wsumP + (((size_t)1*511 + 510)*4)*256;
    const float* epD = esumP + ((size_t)1*511 + 510)*4;
    float wD = wpD[t] + wpD[256+t] + wpD[512+t] + wpD[768+t];
    float eD = epD[0]+epD[1]+epD[2]+epD[3];
    float hDf = colB[t] - wD*rcpf(eD) + hstageD[(size_t)510*256 + t];
    float lh = tanhfast(matA[(size_t)510*256 + t] + hDf);
    float rh = tanhfast(hCf + matB[(size_t)510*256 + t]);
    v[t] = lh*rh;
    v[256+t] = fabsf(lh - rh);
  }
  __syncthreads();
  if (t < 128){
    const float4* w = (const float4*)(W_wh + (size_t)t*512);
    const float4* vv = (const float4*)v;
    float a = b_wh[t];
    #pragma unroll 4
    for (int k = 0; k < 128; ++k){
      float4 wv = w[k], x = vv[k];
      a += wv.x*x.x + wv.y*x.y + wv.z*x.z + wv.w*x.w;
    }
    og[t] = sigmf(a);
  }
  __syncthreads();
  if (t < 5){
    const float* wp = W_wp + (size_t)t*128;
    float a = b_wp[t];
    for (int j = 0; j < 128; ++j) a += og[j]*wp[j];
    lg[t] = a;
  }
  __syncthreads();
  if (t == 0){
    float M = -1e30f;
    for (int c = 0; c < 5; ++c) M = fmaxf(M, lg[c]);
    float S = 0.f;
    for (int c = 0; c < 5; ++c) S += __expf(lg[c] - M);
    float L = logf(S);
    for (int c = 0; c < 5; ++c) out[c] = lg[c] - M - L;
  }
}

extern "C" void kernel_launch(void* const* d_in, const int* in_sizes, int n_in,
                              void* d_out, int out_size, void* d_ws, size_t ws_size,
                              hipStream_t stream)
{
  const int*   l_idx   = (const int*)  d_in[0];
  const int*   r_idx   = (const int*)  d_in[1];
  const float* emb     = (const float*)d_in[2];
  const float* W_ioux  = (const float*)d_in[3];
  const float* b_ioux  = (const float*)d_in[4];
  const float* W_iouh  = (const float*)d_in[5];
  const float* b_iouh  = (const float*)d_in[6];
  // d_in[7]=W_fx, d_in[8]=b_fx unused by the forward
  const float* W_fh    = (const float*)d_in[9];
  const float* b_fh    = (const float*)d_in[10];
  const float* Wa      = (const float*)d_in[11];
  const float* W_attnh = (const float*)d_in[12];
  const float* b_attnh = (const float*)d_in[13];
  const float* W_wh    = (const float*)d_in[14];
  const float* b_wh    = (const float*)d_in[15];
  const float* W_wp    = (const float*)d_in[16];
  const float* b_wp    = (const float*)d_in[17];

  float* ws = (float*)d_ws;
  float* cmatA   = ws;               float* cmatB   = cmatA + RC;
  float* cmatC   = cmatB + RC;       float* cmatD   = cmatC + RC;
  float* matA    = cmatD + RC;       float* matB    = matA + RC;
  float* hstageC = matB + RC;        float* hstageD = hstageC + RC;
  float* projA   = hstageD + RC;     float* projB   = projA + RC;
  float* matTA   = projB + RC;       float* matTB   = matTA + 256*MT;
  float* colA    = matTB + 256*MT;   float* colB    = colA + 256;
  float* wsumP   = colB + 256;            // 2*511*4*256
  float* esumP   = wsumP + 2*511*4*256;   // 2*511*4
  float* php     = esumP + 2*511*4;       // 2*511*4*256
  unsigned short* W16 = (unsigned short*)(php + 2*511*4*256);  // 327,680 ushorts

  static const int offs[9] = {0, 256, 384, 448, 480, 496, 504, 508, 510};

  k_init<<<288, 768, 0, stream>>>(l_idx, r_idx, emb, W_ioux, b_ioux, b_iouh,
                                  W_iouh, W_fh, W_attnh,
                                  cmatA, matA, cmatB, matB, (unsigned*)W16);
  // AB levels 1-4 wide, 5-8 fused
  k_levelAB<4><<<(2*128/4)*4, 512, 0, stream>>>(W16, b_iouh, b_fh, 128, offs[0], offs[1],
                                                cmatA, matA, cmatB, matB);
  k_levelAB<2><<<(2*64/2)*4, 512, 0, stream>>>(W16, b_iouh, b_fh, 64, offs[1], offs[2],
                                               cmatA, matA, cmatB, matB);
  k_levelAB<1><<<(2*32)*4, 512, 0, stream>>>(W16, b_iouh, b_fh, 32, offs[2], offs[3],
                                             cmatA, matA, cmatB, matB);
  k_levelAB<1><<<(2*16)*4, 512, 0, stream>>>(W16, b_iouh, b_fh, 16, offs[3], offs[4],
                                             cmatA, matA, cmatB, matB);
  k_ab_tail<<<2, 512, 0, stream>>>(W16, b_iouh, b_fh, cmatA, matA, cmatB, matB);

  k_mid<<<450, 256, 0, stream>>>(W_attnh, b_attnh, matA, matB,
                                 projA, projB, colA, colB, matTA, matTB, php);
  k_scores_t<4><<<2*(256/4)*4, 256, 0, stream>>>(php, projA, projB,
                                                 matTA, matTB, Wa, 256, 0, 1,
                                                 wsumP, esumP);
  for (int i = 1; i <= 8; ++i){
    int Nc = 256 >> i;
    int oP = offs[i-1], oC = offs[i];
    const float* childHC = (i == 1) ? matB  : hstageC;  // C's h0 = pass-B rows
    const float* childHD = (i == 1) ? matA  : hstageD;
    const float* childCC = (i == 1) ? cmatB : cmatC;
    const float* childCD = (i == 1) ? cmatA : cmatD;
    if (Nc >= 128)
      k_cd1<4><<<(2*Nc/4)*4, 512, 0, stream>>>(W16, b_iouh, b_fh, Nc, oP, oC,
                                               colA, colB, wsumP, esumP,
                                               childHC, childHD, childCC, childCD,
                                               cmatC, cmatD, hstageC, hstageD, php);
    else if (Nc >= 64)
      k_cd1<2><<<(2*Nc/2)*4, 512, 0, stream>>>(W16, b_iouh, b_fh, Nc, oP, oC,
                                               colA, colB, wsumP, esumP,
                                               childHC, childHD, childCC, childCD,
                                               cmatC, cmatD, hstageC, hstageD, php);
    else
      k_cd1<1><<<(2*Nc)*4, 512, 0, stream>>>(W16, b_iouh, b_fh, Nc, oP, oC,
                                             colA, colB, wsumP, esumP,
                                             childHC, childHD, childCC, childCD,
                                             cmatC, cmatD, hstageC, hstageD, php);
    if (Nc >= 4)
      k_scores_t<4><<<2*(Nc/4)*4, 256, 0, stream>>>(php, projA, projB,
                                                    matTA, matTB, Wa, Nc, offs[i], 4,
                                                    wsumP, esumP);
    else if (Nc == 2)
      k_scores_t<2><<<2*(Nc/2)*4, 256, 0, stream>>>(php, projA, projB,
                                                    matTA, matTB, Wa, Nc, offs[i], 4,
                                                    wsumP, esumP);
    else
      k_scores_t<1><<<2*Nc*4, 256, 0, stream>>>(php, projA, projB,
                                                matTA, matTB, Wa, Nc, offs[i], 4,
                                                wsumP, esumP);
  }
  k_head<<<1, 256, 0, stream>>>(W_wh, b_wh, W_wp, b_wp, matA, matB,
                                colA, colB, wsumP, esumP, hstageC, hstageD,
                                (float*)d_out);
}

// Round 7
// 605.234 us; speedup vs baseline: 2.1865x; 1.2137x over previous
//
#include <hip/hip_runtime.h>

#define RC 130816   // 511*256
#define MT 512      // matT m-stride (511 zero-padded)

// bf16 weight cache layout (ushort offsets)
#define B16_FH   196608   // after 768*256 iou rows
#define B16_W1   262144   // 256*256 (W_attnh[:, :256])

__device__ __forceinline__ float rcpf(float x){ return __builtin_amdgcn_rcpf(x); }
__device__ __forceinline__ float sigmf(float x){ return rcpf(1.f + __expf(-x)); }
__device__ __forceinline__ float tanhfast(float x){
  return 1.f - 2.f*rcpf(1.f + __expf(2.f*x));
}

// ---- bf16-as-integer helpers ----
__device__ __forceinline__ float bfl(unsigned x){ return __uint_as_float(x << 16); }
__device__ __forceinline__ float bfh(unsigned x){ return __uint_as_float(x & 0xFFFF0000u); }
__device__ __forceinline__ unsigned bpack(float a, float b){
  unsigned ua = __float_as_uint(a), ub = __float_as_uint(b);
  return ((ua + 0x7FFFu + ((ua>>16)&1u)) >> 16)
       | ((ub + 0x7FFFu + ((ub>>16)&1u)) & 0xFFFF0000u);
}
__device__ __forceinline__ float dot8b(uint4 w, const float4* s4){
  float4 s0 = s4[0], s1 = s4[1];
  return bfl(w.x)*s0.x + bfh(w.x)*s0.y + bfl(w.y)*s0.z + bfh(w.y)*s0.w
       + bfl(w.z)*s1.x + bfh(w.z)*s1.y + bfl(w.w)*s1.z + bfh(w.w)*s1.w;
}

// ---------------------------------------------------------------------------
// Per-row attention scores (round-5 verified logic + tanh fold).
// Writes 4-chunk format: wsum chunk 0 = full sum, chunks 1-3 zeroed;
// esum slot 0 = sum, slots 1-3 zeroed. Consumers sum all 4 chunks.
// Fold: tanh(x)=1-2*rcp(1+exp2(CE*x)); constant exp(SumWa) cancels in
// wsum/esum ratio and is dropped (verified round 6, absmax 0.0).
// ---------------------------------------------------------------------------
__device__ void attend_scores_row(
    int tid, int p, int row, const float* sh_h,
    const float* __restrict__ proj, const float* __restrict__ mat,
    const unsigned short* __restrict__ W16, const float* __restrict__ Wa,
    float* __restrict__ wsumP, float* __restrict__ esumP, float* lds)
{
  const float CE = 2.885390082f;   // 2*log2(e)
  float* sHP   = lds;           // 512  [eh][j]
  float* shp   = sHP + 512;     // 256
  float* swa   = shp + 256;     // 256
  float* spart = swa + 256;     // 1024 [(dh*4+ch)*128+ml]
  float* se    = spart + 1024;  // 512
  float* sw    = se + 512;      // 512  [mh][j]
  float* sred  = sw + 512;      // 64

  // hp = W1 (bf16) · h
  {
    int j = tid & 255, eh = tid >> 8;
    const uint4* w1 = (const uint4*)(W16 + B16_W1 + (size_t)j*256 + eh*128);
    float a = 0.f;
    #pragma unroll
    for (int k = 0; k < 16; ++k)
      a += dot8b(w1[k], (const float4*)(sh_h + eh*128 + k*8));
    sHP[eh*256 + j] = a;
  }
  if (tid < 256) swa[tid] = Wa[tid];
  __syncthreads();
  if (tid < 256) shp[tid] = (sHP[tid] + sHP[256 + tid]) * CE;
  __syncthreads();

  {
    int ml = tid & 127, dh = (tid >> 7) & 1, hi = tid >> 8;
    #pragma unroll
    for (int chi = 0; chi < 2; ++chi){
      int ch = hi*2 + chi;
      int m = ch*128 + ml;
      float part = 0.f;
      if (m < 511){
        const float4* pr  = (const float4*)(proj + (size_t)m*256 + dh*128);
        const float4* wa4 = (const float4*)(swa + dh*128);
        #pragma unroll 4
        for (int k = 0; k < 32; ++k){
          float4 pv = pr[k], wv = wa4[k];
          const float* hr = shp + dh*128 + k*4;
          part += wv.x*rcpf(1.f + exp2f(hr[0]+pv.x*CE))
                + wv.y*rcpf(1.f + exp2f(hr[1]+pv.y*CE))
                + wv.z*rcpf(1.f + exp2f(hr[2]+pv.z*CE))
                + wv.w*rcpf(1.f + exp2f(hr[3]+pv.w*CE));
        }
      }
      spart[(dh*4 + ch)*128 + ml] = part;
    }
  }
  __syncthreads();
  {
    int ch = tid >> 7, mml = tid & 127;
    float sv = spart[(0*4+ch)*128 + mml] + spart[(1*4+ch)*128 + mml];
    se[tid] = (tid < 511) ? __expf(-2.f*sv) : 0.f;
  }
  __syncthreads();
  if (tid < 64){
    float s = 0.f;
    #pragma unroll
    for (int i = 0; i < 8; ++i) s += se[tid + 64*i];
    sred[tid] = s;
  }
  __syncthreads();
  if (tid == 0){
    float s = 0.f;
    #pragma unroll
    for (int i = 0; i < 64; ++i) s += sred[i];
    float* ep = esumP + ((size_t)p*511 + row)*4;
    ep[0] = s; ep[1] = 0.f; ep[2] = 0.f; ep[3] = 0.f;
  }
  {
    int j = tid & 255, mh = tid >> 8;
    float acc = 0.f;
    int mbase = mh*256;
    int mcount = mh ? 255 : 256;   // m in [0,511)
    for (int mi = 0; mi < mcount; ++mi){
      int m = mbase + mi;
      acc += se[m] * mat[(size_t)m*256 + j];
    }
    sw[mh*256 + j] = acc;
  }
  __syncthreads();
  if (tid < 256){
    float* wp = wsumP + (((size_t)p*511 + row)*4)*256;
    wp[tid] = sw[tid] + sw[256 + tid];
    wp[256+tid] = 0.f; wp[512+tid] = 0.f; wp[768+tid] = 0.f;
  }
}

// ---------------------------------------------------------------------------
// Init (blocks 0..255) + weight pack (blocks 256..287). 768 threads.
// (verified rounds 5/6)
// ---------------------------------------------------------------------------
__global__ void __launch_bounds__(768) k_init(
    const int* __restrict__ l_idx, const int* __restrict__ r_idx,
    const float* __restrict__ emb, const float* __restrict__ W_ioux,
    const float* __restrict__ b_ioux, const float* __restrict__ b_iouh,
    const float* __restrict__ W_iouh, const float* __restrict__ W_fh,
    const float* __restrict__ W_attnh,
    float* __restrict__ cmatA, float* __restrict__ matA,
    float* __restrict__ cmatB, float* __restrict__ matB,
    unsigned* __restrict__ W16u)
{
  int b = blockIdx.x, tid = threadIdx.x;
  if (b >= 256){
    int gid = (b - 256)*768 + tid, gs = 32*768;
    for (int k = gid; k < 98304; k += gs){
      int i = 2*k; W16u[k] = bpack(W_iouh[i], W_iouh[i+1]);
    }
    for (int k = gid; k < 32768; k += gs){
      int i = 2*k; W16u[98304 + k] = bpack(W_fh[i], W_fh[i+1]);
    }
    for (int k = gid; k < 32768; k += gs){
      int i = 2*k; int t = i>>8, e = i&255;
      const float* r = W_attnh + (size_t)t*512;
      W16u[131072 + k] = bpack(r[e], r[e+1]);
    }
    return;
  }
  int p = b >> 7, n0 = (b & 127) * 2;
  __shared__ __align__(16) float xs[2*304];
  __shared__ float sg[2*768];
  for (int j = tid; j < 600; j += 768){
    int rr = j/300, d = j - rr*300;
    int row = p ? r_idx[n0+rr] : l_idx[n0+rr];
    xs[rr*304 + d] = emb[(size_t)row*300 + d];
  }
  __syncthreads();
  const float4* w = (const float4*)(W_ioux + (size_t)tid*300);
  float a0 = 0.f, a1 = 0.f;
  #pragma unroll 5
  for (int k = 0; k < 75; ++k){
    float4 wv = w[k];
    const float* x0 = xs + 4*k;
    const float* x1 = xs + 304 + 4*k;
    a0 += wv.x*x0[0] + wv.y*x0[1] + wv.z*x0[2] + wv.w*x0[3];
    a1 += wv.x*x1[0] + wv.y*x1[1] + wv.z*x1[2] + wv.w*x1[3];
  }
  float bb = b_ioux[tid] + b_iouh[tid];
  sg[tid] = a0 + bb;
  sg[768 + tid] = a1 + bb;
  __syncthreads();
  if (tid < 512){
    int rr = tid >> 8, t = tid & 255;
    const float* g = sg + rr*768;
    float c = sigmf(g[t]) * tanhfast(g[512+t]);
    float h = sigmf(g[256+t]) * tanhfast(c);
    (p ? cmatB : cmatA)[(size_t)(n0+rr)*256 + t] = c;
    (p ? matB  : matA )[(size_t)(n0+rr)*256 + t] = h;
  }
}

// ---------------------------------------------------------------------------
// A/B tree level (verified baseline).
// ---------------------------------------------------------------------------
template<int R>
__global__ void __launch_bounds__(512) k_levelAB(
    const unsigned short* __restrict__ W16, const float* __restrict__ b_iouh,
    const float* __restrict__ b_fh,
    int Nc, int offPrev, int offCur,
    float* __restrict__ cmatA, float* __restrict__ matA,
    float* __restrict__ cmatB, float* __restrict__ matB)
{
  int bid = blockIdx.x, tid = threadIdx.x;
  int s = bid & 3, g2 = bid >> 2;
  int groups = Nc / R;
  int p = (g2 >= groups) ? 1 : 0;
  int n0 = (g2 - p*groups) * R;
  float* cmat = p ? cmatB : cmatA;
  float* hmat = p ? matB  : matA;

  __shared__ __align__(16) float hs0[R][256], hs1[R][256], hss[R][256];
  __shared__ float sP[10][R][64];

  for (int it = tid; it < R*2*256; it += 512){
    int j = it & 255, ch = (it>>8)&1, r = it>>9;
    float v = hmat[(size_t)(offPrev + 2*(n0+r) + ch)*256 + j];
    if (ch) hs1[r][j] = v; else hs0[r][j] = v;
  }
  __syncthreads();
  for (int it = tid; it < R*256; it += 512){
    int j = it & 255, r = it>>8;
    hss[r][j] = hs0[r][j] + hs1[r][j];
  }
  __syncthreads();

  {
    int role = tid >> 6, cl = tid & 63;
    int gate = role & 3, dh = role >> 2;
    int col = s*64 + cl;
    if (gate < 3){
      const unsigned short* wrow = W16 + (size_t)(col + gate*256)*256;
      const uint4* w4 = (const uint4*)(wrow + dh*128);
      float acc[R];
      #pragma unroll
      for (int r = 0; r < R; ++r) acc[r] = 0.f;
      #pragma unroll 4
      for (int k = 0; k < 16; ++k){
        uint4 w = w4[k];
        #pragma unroll
        for (int r = 0; r < R; ++r)
          acc[r] += dot8b(w, (const float4*)(&hss[r][dh*128 + k*8]));
      }
      #pragma unroll
      for (int r = 0; r < R; ++r) sP[gate*2+dh][r][cl] = acc[r];
    } else {
      const uint4* w4 = (const uint4*)(W16 + B16_FH + (size_t)col*256 + dh*128);
      float a0[R], a1[R];
      #pragma unroll
      for (int r = 0; r < R; ++r){ a0[r] = 0.f; a1[r] = 0.f; }
      #pragma unroll 4
      for (int k = 0; k < 16; ++k){
        uint4 w = w4[k];
        #pragma unroll
        for (int r = 0; r < R; ++r){
          a0[r] += dot8b(w, (const float4*)(&hs0[r][dh*128 + k*8]));
          a1[r] += dot8b(w, (const float4*)(&hs1[r][dh*128 + k*8]));
        }
      }
      #pragma unroll
      for (int r = 0; r < R; ++r){ sP[6+dh][r][cl] = a0[r]; sP[8+dh][r][cl] = a1[r]; }
    }
  }
  __syncthreads();
  if (tid < 64*R){
    int r = tid >> 6, cl = tid & 63;
    int t = s*64 + cl;
    int n = n0 + r;
    float ai  = sP[0][r][cl] + sP[1][r][cl];
    float ao  = sP[2][r][cl] + sP[3][r][cl];
    float au  = sP[4][r][cl] + sP[5][r][cl];
    float af0 = sP[6][r][cl] + sP[7][r][cl];
    float af1 = sP[8][r][cl] + sP[9][r][cl];
    float c0 = cmat[(size_t)(offPrev+2*n)*256 + t];
    float c1 = cmat[(size_t)(offPrev+2*n+1)*256 + t];
    float i_ = sigmf(ai + b_iouh[t]);
    float o_ = sigmf(ao + b_iouh[256+t]);
    float u_ = tanhfast(au + b_iouh[512+t]);
    float bf = b_fh[t];
    float c = i_*u_ + sigmf(af0+bf)*c0 + sigmf(af1+bf)*c1;
    float h = o_*tanhfast(c);
    cmat[(size_t)(offCur+n)*256 + t] = c;
    hmat[(size_t)(offCur+n)*256 + t] = h;
  }
}

// ---------------------------------------------------------------------------
// Mid (verified baseline).
// ---------------------------------------------------------------------------
__global__ void __launch_bounds__(256) k_mid(
    const float* __restrict__ W_attnh, const float* __restrict__ b_attnh,
    const float* __restrict__ matA, const float* __restrict__ matB,
    float* __restrict__ projA, float* __restrict__ projB,
    float* __restrict__ colA, float* __restrict__ colB,
    float* __restrict__ matTA, float* __restrict__ matTB,
    float* __restrict__ php)
{
  int b = blockIdx.x, tid = threadIdx.x;
  if (b < 128){
    int p = b>>6, ch = b&63, m0 = ch*8, mc = min(8, 511-m0);
    const float* mat = p ? matB : matA;
    float* proj = p ? projB : projA;
    __shared__ __align__(16) float ms[256*8];   // ms[e*8+rr]
    for (int j = tid; j < mc*256; j += 256){
      int rr = j>>8, e = j&255;
      ms[e*8+rr] = mat[(size_t)(m0+rr)*256 + e];
    }
    for (int j = tid + mc*256; j < 8*256; j += 256){
      int rr = j>>8, e = j&255; ms[e*8+rr] = 0.f;
    }
    __syncthreads();
    int t = tid;
    const float4* w2 = (const float4*)(W_attnh + (size_t)t*512 + 256);
    float acc[8] = {0,0,0,0,0,0,0,0};
    #pragma unroll 2
    for (int k = 0; k < 64; ++k){
      float4 w = w2[k];
      const float* base = ms + k*32;
      #pragma unroll
      for (int rr = 0; rr < 8; ++rr)
        acc[rr] += w.x*base[rr] + w.y*base[8+rr] + w.z*base[16+rr] + w.w*base[24+rr];
    }
    float ba = b_attnh[t];
    for (int rr = 0; rr < mc; ++rr) proj[(size_t)(m0+rr)*256 + t] = acc[rr] + ba;
  } else if (b < 130){
    int p = b - 128;
    const float* mat = p ? matB : matA;
    float* col = p ? colB : colA;
    float s = 0.f;
    #pragma unroll 8
    for (int m = 0; m < 511; ++m) s += mat[(size_t)m*256 + tid];
    col[tid] = s;
  } else if (b < 386){
    int idx = b - 130;
    int p = idx>>7, rem = idx&127, jt = rem>>4, mt = rem&15;
    const float* mat = p ? matB : matA;
    float* matT = p ? matTB : matTA;
    __shared__ float tile[32][33];
    int c = tid&31, r0 = tid>>5;
    int m0 = mt*32, j0 = jt*32;
    #pragma unroll
    for (int k = 0; k < 4; ++k){
      int m = m0 + r0 + 8*k;
      tile[r0+8*k][c] = (m < 511) ? mat[(size_t)m*256 + j0 + c] : 0.f;
    }
    __syncthreads();
    #pragma unroll
    for (int k = 0; k < 4; ++k){
      int jj = r0 + 8*k;
      matT[(size_t)(j0+jj)*MT + m0 + c] = tile[c][jj];
    }
  } else {
    int idx = b - 386;           // 64 blocks: p (C/D) x 32 chunks of 8 rows
    int p = idx>>5, ch = idx&31, r0 = ch*8;
    const float* hsrc = p ? matA : matB;   // C<-B, D<-A
    __shared__ __align__(16) float ms[256*8];
    for (int j = tid; j < 8*256; j += 256){
      int rr = j>>8, e = j&255;
      ms[e*8+rr] = hsrc[(size_t)(r0+rr)*256 + e];
    }
    __syncthreads();
    int t = tid;
    const float4* w1 = (const float4*)(W_attnh + (size_t)t*512);
    float acc[8] = {0,0,0,0,0,0,0,0};
    #pragma unroll 2
    for (int k = 0; k < 64; ++k){
      float4 w = w1[k];
      const float* base = ms + k*32;
      #pragma unroll
      for (int rr = 0; rr < 8; ++rr)
        acc[rr] += w.x*base[rr] + w.y*base[8+rr] + w.z*base[16+rr] + w.w*base[24+rr];
    }
    #pragma unroll
    for (int rr = 0; rr < 8; ++rr)
      php[(((size_t)p*511 + r0+rr)*4 + 0)*256 + t] = acc[rr];
  }
}

// ---------------------------------------------------------------------------
// Tiled scores (verified + fold, round 6).
// ---------------------------------------------------------------------------
template<int G>
__global__ void __launch_bounds__(256) k_scores_t(
    const float* __restrict__ php,
    const float* __restrict__ projA, const float* __restrict__ projB,
    const float* __restrict__ matTA, const float* __restrict__ matTB,
    const float* __restrict__ Wa, int Nc, int rowOff, int S,
    float* __restrict__ wsumP, float* __restrict__ esumP)
{
  const float CE = 2.885390082f;   // 2*log2(e)
  int b = blockIdx.x, tid = threadIdx.x;
  int groups = Nc / G;
  int per = groups * 4;
  int p = b / per; int rem = b - p*per; int g = rem >> 2, ch = rem & 3;
  int row0 = rowOff + g*G;
  const float* proj = p ? projB : projA;
  const float* matT = p ? matTB : matTA;

  __shared__ __align__(16) float shp[G*256];
  __shared__ __align__(16) float swa[256];
  __shared__ __align__(16) float spart[G*256];
  __shared__ __align__(16) float se[G*128];

  for (int j = tid; j < G*256; j += 256){
    int row = row0 + (j>>8), jj = j&255;
    const float* base = php + (((size_t)p*511 + row)*4)*256 + jj;
    float v = base[0];
    if (S == 4) v += base[256] + base[512] + base[768];
    shp[j] = v * CE;
  }
  swa[tid] = Wa[tid];
  __syncthreads();

  int ml = tid & 127, dh = tid >> 7;
  int m = ch*128 + ml;
  float part[G];
  #pragma unroll
  for (int r = 0; r < G; ++r) part[r] = 0.f;
  if (m < 511){
    const float4* pr  = (const float4*)(proj + (size_t)m*256 + dh*128);
    const float4* wa4 = (const float4*)(swa + dh*128);
    #pragma unroll 4
    for (int k = 0; k < 32; ++k){
      float4 pv = pr[k], wv = wa4[k];
      float p0 = pv.x*CE, p1 = pv.y*CE, p2 = pv.z*CE, p3 = pv.w*CE;
      int dbase = dh*128 + k*4;
      #pragma unroll
      for (int r = 0; r < G; ++r){
        const float* hr = shp + r*256 + dbase;
        part[r] += wv.x*rcpf(1.f + exp2f(hr[0]+p0))
                 + wv.y*rcpf(1.f + exp2f(hr[1]+p1))
                 + wv.z*rcpf(1.f + exp2f(hr[2]+p2))
                 + wv.w*rcpf(1.f + exp2f(hr[3]+p3));
      }
    }
  }
  #pragma unroll
  for (int r = 0; r < G; ++r) spart[r*256 + tid] = part[r];
  __syncthreads();
  if (tid < 128){
    #pragma unroll
    for (int r = 0; r < G; ++r){
      float s = spart[r*256 + ml] + spart[r*256 + 128 + ml];
      se[r*128 + ml] = (ch*128 + ml < 511) ? __expf(-2.f*s) : 0.f;
    }
  }
  __syncthreads();
  {
    const float4* mt = (const float4*)(matT + (size_t)tid*MT + ch*128);
    float acc[G];
    #pragma unroll
    for (int r = 0; r < G; ++r) acc[r] = 0.f;
    #pragma unroll 4
    for (int k = 0; k < 32; ++k){
      float4 mv = mt[k];
      #pragma unroll
      for (int r = 0; r < G; ++r){
        float4 ev = ((const float4*)(se + r*128))[k];
        acc[r] += mv.x*ev.x + mv.y*ev.y + mv.z*ev.z + mv.w*ev.w;
      }
    }
    #pragma unroll
    for (int r = 0; r < G; ++r)
      wsumP[(((size_t)p*511 + row0 + r)*4 + ch)*256 + tid] = acc[r];
  }
  if (tid < G){
    float s = 0.f;
    const float* sr = se + tid*128;
    for (int k = 0; k < 128; ++k) s += sr[k];
    esumP[((size_t)p*511 + row0 + tid)*4 + ch] = s;
  }
}

// ---------------------------------------------------------------------------
// CD spine, batched (verified baseline) — levels 1-3.
// ---------------------------------------------------------------------------
template<int R>
__global__ void __launch_bounds__(512) k_cd1(
    const unsigned short* __restrict__ W16, const float* __restrict__ b_iouh,
    const float* __restrict__ b_fh,
    int Nc, int offPrev, int offCur,
    const float* __restrict__ colA, const float* __restrict__ colB,
    const float* __restrict__ wsumP, const float* __restrict__ esumP,
    const float* __restrict__ childHC, const float* __restrict__ childHD,
    const float* __restrict__ childCC, const float* __restrict__ childCD_,
    float* __restrict__ cmatC, float* __restrict__ cmatD,
    float* __restrict__ hstageC, float* __restrict__ hstageD,
    float* __restrict__ php)
{
  int bid = blockIdx.x, tid = threadIdx.x;
  int s = bid & 3, g2 = bid >> 2;
  int groups = Nc / R;
  int p = (g2 >= groups) ? 1 : 0;
  int n0 = (g2 - p*groups) * R;
  const float* colv   = p ? colB : colA;
  const float* childH = p ? childHD : childHC;
  const float* childC = p ? childCD_ : childCC;
  float* cmat   = p ? cmatD : cmatC;
  float* hstage = p ? hstageD : hstageC;

  __shared__ __align__(16) float hs0[R][256], hs1[R][256], hss[R][256];
  __shared__ float sP[10][R][64];
  __shared__ __align__(16) float sh[R][64];
  __shared__ float sHP[2][256];

  for (int it = tid; it < R*2*256; it += 512){
    int j = it & 255, ch = (it>>8)&1, r = it>>9;
    int rc = offPrev + 2*(n0+r) + ch;
    const float* wp = wsumP + (((size_t)p*511 + rc)*4)*256;
    const float* ep = esumP + ((size_t)p*511 + rc)*4;
    float w = wp[j] + wp[256+j] + wp[512+j] + wp[768+j];
    float esum = ep[0]+ep[1]+ep[2]+ep[3];
    float hatt = colv[j] - w*rcpf(esum) + childH[(size_t)rc*256 + j];
    if (ch) hs1[r][j] = hatt; else hs0[r][j] = hatt;
  }
  __syncthreads();
  for (int it = tid; it < R*256; it += 512){
    int j = it & 255, r = it>>8;
    hss[r][j] = hs0[r][j] + hs1[r][j];
  }
  __syncthreads();

  {
    int role = tid >> 6, cl = tid & 63;
    int gate = role & 3, dh = role >> 2;
    int col = s*64 + cl;
    if (gate < 3){
      const unsigned short* wrow = W16 + (size_t)(col + gate*256)*256;
      const uint4* w4 = (const uint4*)(wrow + dh*128);
      float acc[R];
      #pragma unroll
      for (int r = 0; r < R; ++r) acc[r] = 0.f;
      #pragma unroll 4
      for (int k = 0; k < 16; ++k){
        uint4 w = w4[k];
        #pragma unroll
        for (int r = 0; r < R; ++r)
          acc[r] += dot8b(w, (const float4*)(&hss[r][dh*128 + k*8]));
      }
      #pragma unroll
      for (int r = 0; r < R; ++r) sP[gate*2+dh][r][cl] = acc[r];
    } else {
      const uint4* w4 = (const uint4*)(W16 + B16_FH + (size_t)col*256 + dh*128);
      float a0[R], a1[R];
      #pragma unroll
      for (int r = 0; r < R; ++r){ a0[r] = 0.f; a1[r] = 0.f; }
      #pragma unroll 4
      for (int k = 0; k < 16; ++k){
        uint4 w = w4[k];
        #pragma unroll
        for (int r = 0; r < R; ++r){
          a0[r] += dot8b(w, (const float4*)(&hs0[r][dh*128 + k*8]));
          a1[r] += dot8b(w, (const float4*)(&hs1[r][dh*128 + k*8]));
        }
      }
      #pragma unroll
      for (int r = 0; r < R; ++r){ sP[6+dh][r][cl] = a0[r]; sP[8+dh][r][cl] = a1[r]; }
    }
  }
  __syncthreads();

  if (tid < 64*R){
    int r = tid >> 6, cl = tid & 63;
    int t = s*64 + cl;
    int n = n0 + r;
    float ai  = sP[0][r][cl] + sP[1][r][cl];
    float ao  = sP[2][r][cl] + sP[3][r][cl];
    float au  = sP[4][r][cl] + sP[5][r][cl];
    float af0 = sP[6][r][cl] + sP[7][r][cl];
    float af1 = sP[8][r][cl] + sP[9][r][cl];
    float c0 = childC[(size_t)(offPrev+2*n)*256 + t];
    float c1 = childC[(size_t)(offPrev+2*n+1)*256 + t];
    float i_ = sigmf(ai + b_iouh[t]);
    float o_ = sigmf(ao + b_iouh[256+t]);
    float u_ = tanhfast(au + b_iouh[512+t]);
    float bf = b_fh[t];
    float c = i_*u_ + sigmf(af0+bf)*c0 + sigmf(af1+bf)*c1;
    float h = o_*tanhfast(c);
    cmat[(size_t)(offCur+n)*256 + t] = c;
    hstage[(size_t)(offCur+n)*256 + t] = h;
    sh[r][cl] = h;
  }
  __syncthreads();

  {
    int j = tid & 255, eh = tid >> 8;
    const uint4* w1 = (const uint4*)(W16 + B16_W1 + (size_t)j*256 + s*64 + eh*32);
    uint4 wv[4];
    #pragma unroll
    for (int k = 0; k < 4; ++k) wv[k] = w1[k];
    float aacc[R];
    #pragma unroll
    for (int r = 0; r < R; ++r){
      float a = 0.f;
      #pragma unroll
      for (int k = 0; k < 4; ++k)
        a += dot8b(wv[k], (const float4*)(&sh[r][eh*32 + k*8]));
      aacc[r] = a;
    }
    #pragma unroll
    for (int r = 0; r < R; ++r){
      sHP[eh][j] = aacc[r];
      __syncthreads();
      if (tid < 256){
        int row = offCur + n0 + r;
        php[(((size_t)p*511 + row)*4 + s)*256 + tid] = sHP[0][tid] + sHP[1][tid];
      }
      __syncthreads();
    }
  }
}

// ---------------------------------------------------------------------------
// CD tail level (Nc<=16): one block per output row; gates + in-block scores.
// Round-5-verified per-row logic; parallel width preserved (2*Nc blocks, no
// serial multi-row chain). Writes 4-chunk wsum/esum (chunk 0 + zeros).
// ---------------------------------------------------------------------------
__global__ void __launch_bounds__(512) k_cdtail(
    const unsigned short* __restrict__ W16, const float* __restrict__ b_iouh,
    const float* __restrict__ b_fh,
    int Nc, int offPrev, int offCur,
    const float* __restrict__ colA, const float* __restrict__ colB,
    float* __restrict__ wsumP, float* __restrict__ esumP,
    const float* __restrict__ childHC, const float* __restrict__ childHD,
    const float* __restrict__ childCC, const float* __restrict__ childCD_,
    float* __restrict__ cmatC, float* __restrict__ cmatD,
    float* __restrict__ hstageC, float* __restrict__ hstageD,
    const float* __restrict__ projA, const float* __restrict__ projB,
    const float* __restrict__ matA, const float* __restrict__ matB,
    const float* __restrict__ Wa)
{
  int bid = blockIdx.x, tid = threadIdx.x;
  int p = (bid >= Nc) ? 1 : 0;
  int n0 = bid - p*Nc;
  const float* colv   = p ? colB : colA;
  const float* childH = p ? childHD : childHC;
  const float* childC = p ? childCD_ : childCC;
  float* cmat   = p ? cmatD : cmatC;
  float* hstage = p ? hstageD : hstageC;
  const float* proj = p ? projB : projA;
  const float* mat  = p ? matB  : matA;

  __shared__ __align__(16) float hs0[256], hs1[256], hss[256];
  __shared__ __align__(16) float sP[640];
  __shared__ __align__(16) float sh[256];
  __shared__ __align__(16) float arena[3136];

  // Phase 1: attend-finish both children (4-chunk read)
  {
    int j = tid & 255, ch = tid >> 8;
    int rc = offPrev + 2*n0 + ch;
    const float* wp = wsumP + (((size_t)p*511 + rc)*4)*256;
    const float* ep = esumP + ((size_t)p*511 + rc)*4;
    float w  = wp[j] + wp[256+j] + wp[512+j] + wp[768+j];
    float es = ep[0]+ep[1]+ep[2]+ep[3];
    float hatt = colv[j] - w*rcpf(es) + childH[(size_t)rc*256 + j];
    if (ch) hs1[j] = hatt; else hs0[j] = hatt;
  }
  __syncthreads();
  if (tid < 256) hss[tid] = hs0[tid] + hs1[tid];
  __syncthreads();

  // Phase 2: gates, s-loop over column quarters (round-5 verified)
  {
    int role = tid >> 6, cl = tid & 63;
    int gate = role & 3, dh = role >> 2;
    for (int s = 0; s < 4; ++s){
      int col = s*64 + cl;
      if (gate < 3){
        const uint4* w4 = (const uint4*)(W16 + (size_t)(col + gate*256)*256 + dh*128);
        float acc = 0.f;
        #pragma unroll 4
        for (int k = 0; k < 16; ++k)
          acc += dot8b(w4[k], (const float4*)(hss + dh*128 + k*8));
        sP[(gate*2+dh)*64 + cl] = acc;
      } else {
        const uint4* w4 = (const uint4*)(W16 + B16_FH + (size_t)col*256 + dh*128);
        float a0 = 0.f, a1 = 0.f;
        #pragma unroll 4
        for (int k = 0; k < 16; ++k){
          uint4 w = w4[k];
          a0 += dot8b(w, (const float4*)(hs0 + dh*128 + k*8));
          a1 += dot8b(w, (const float4*)(hs1 + dh*128 + k*8));
        }
        sP[(6+dh)*64 + cl] = a0;
        sP[(8+dh)*64 + cl] = a1;
      }
      __syncthreads();
      if (tid < 64){
        int t = s*64 + tid;
        float ai  = sP[0*64+tid] + sP[1*64+tid];
        float ao  = sP[2*64+tid] + sP[3*64+tid];
        float au  = sP[4*64+tid] + sP[5*64+tid];
        float af0 = sP[6*64+tid] + sP[7*64+tid];
        float af1 = sP[8*64+tid] + sP[9*64+tid];
        float c0 = childC[(size_t)(offPrev+2*n0)*256 + t];
        float c1 = childC[(size_t)(offPrev+2*n0+1)*256 + t];
        float i_ = sigmf(ai + b_iouh[t]);
        float o_ = sigmf(ao + b_iouh[256+t]);
        float u_ = tanhfast(au + b_iouh[512+t]);
        float bf = b_fh[t];
        float c = i_*u_ + sigmf(af0+bf)*c0 + sigmf(af1+bf)*c1;
        float h = o_*tanhfast(c);
        cmat[(size_t)(offCur+n0)*256 + t] = c;
        hstage[(size_t)(offCur+n0)*256 + t] = h;
        sh[t] = h;
      }
      __syncthreads();
    }
  }

  // In-block scores for the new row (disjoint output rows -> no race).
  attend_scores_row(tid, p, offCur + n0, sh, proj, mat, W16, Wa,
                    wsumP, esumP, arena);
}

// ---------------------------------------------------------------------------
// Head (verified baseline).
// ---------------------------------------------------------------------------
__global__ void __launch_bounds__(256) k_head(
    const float* __restrict__ W_wh, const float* __restrict__ b_wh,
    const float* __restrict__ W_wp, const float* __restrict__ b_wp,
    const float* __restrict__ matA, const float* __restrict__ matB,
    const float* __restrict__ colA, const float* __restrict__ colB,
    const float* __restrict__ wsumP, const float* __restrict__ esumP,
    const float* __restrict__ hstageC, const float* __restrict__ hstageD,
    float* __restrict__ out)
{
  __shared__ __align__(16) float v[512];
  __shared__ float og[128], lg[5];
  int t = threadIdx.x;
  {
    const float* wpC = wsumP + (((size_t)0*511 + 510)*4)*256;
    const float* epC = esumP + ((size_t)0*511 + 510)*4;
    float wC = wpC[t] + wpC[256+t] + wpC[512+t] + wpC[768+t];
    float eC = epC[0]+epC[1]+epC[2]+epC[3];
    float hCf = colA[t] - wC*rcpf(eC) + hstageC[(size_t)510*256 + t];
    const float* wpD = wsumP + (((size_t)1*511 + 510)*4)*256;
    const float* epD = esumP + ((size_t)1*511 + 510)*4;
    float wD = wpD[t] + wpD[256+t] + wpD[512+t] + wpD[768+t];
    float eD = epD[0]+epD[1]+epD[2]+epD[3];
    float hDf = colB[t] - wD*rcpf(eD) + hstageD[(size_t)510*256 + t];
    float lh = tanhfast(matA[(size_t)510*256 + t] + hDf);
    float rh = tanhfast(hCf + matB[(size_t)510*256 + t]);
    v[t] = lh*rh;
    v[256+t] = fabsf(lh - rh);
  }
  __syncthreads();
  if (t < 128){
    const float4* w = (const float4*)(W_wh + (size_t)t*512);
    const float4* vv = (const float4*)v;
    float a = b_wh[t];
    #pragma unroll 4
    for (int k = 0; k < 128; ++k){
      float4 wv = w[k], x = vv[k];
      a += wv.x*x.x + wv.y*x.y + wv.z*x.z + wv.w*x.w;
    }
    og[t] = sigmf(a);
  }
  __syncthreads();
  if (t < 5){
    const float* wp = W_wp + (size_t)t*128;
    float a = b_wp[t];
    for (int j = 0; j < 128; ++j) a += og[j]*wp[j];
    lg[t] = a;
  }
  __syncthreads();
  if (t == 0){
    float M = -1e30f;
    for (int c = 0; c < 5; ++c) M = fmaxf(M, lg[c]);
    float S = 0.f;
    for (int c = 0; c < 5; ++c) S += __expf(lg[c] - M);
    float L = logf(S);
    for (int c = 0; c < 5; ++c) out[c] = lg[c] - M - L;
  }
}

extern "C" void kernel_launch(void* const* d_in, const int* in_sizes, int n_in,
                              void* d_out, int out_size, void* d_ws, size_t ws_size,
                              hipStream_t stream)
{
  const int*   l_idx   = (const int*)  d_in[0];
  const int*   r_idx   = (const int*)  d_in[1];
  const float* emb     = (const float*)d_in[2];
  const float* W_ioux  = (const float*)d_in[3];
  const float* b_ioux  = (const float*)d_in[4];
  const float* W_iouh  = (const float*)d_in[5];
  const float* b_iouh  = (const float*)d_in[6];
  // d_in[7]=W_fx, d_in[8]=b_fx unused by the forward
  const float* W_fh    = (const float*)d_in[9];
  const float* b_fh    = (const float*)d_in[10];
  const float* Wa      = (const float*)d_in[11];
  const float* W_attnh = (const float*)d_in[12];
  const float* b_attnh = (const float*)d_in[13];
  const float* W_wh    = (const float*)d_in[14];
  const float* b_wh    = (const float*)d_in[15];
  const float* W_wp    = (const float*)d_in[16];
  const float* b_wp    = (const float*)d_in[17];

  float* ws = (float*)d_ws;
  float* cmatA   = ws;               float* cmatB   = cmatA + RC;
  float* cmatC   = cmatB + RC;       float* cmatD   = cmatC + RC;
  float* matA    = cmatD + RC;       float* matB    = matA + RC;
  float* hstageC = matB + RC;        float* hstageD = hstageC + RC;
  float* projA   = hstageD + RC;     float* projB   = projA + RC;
  float* matTA   = projB + RC;       float* matTB   = matTA + 256*MT;
  float* colA    = matTB + 256*MT;   float* colB    = colA + 256;
  float* wsumP   = colB + 256;            // 2*511*4*256
  float* esumP   = wsumP + 2*511*4*256;   // 2*511*4
  float* php     = esumP + 2*511*4;       // 2*511*4*256
  unsigned short* W16 = (unsigned short*)(php + 2*511*4*256);  // 327,680 ushorts

  static const int offs[9] = {0, 256, 384, 448, 480, 496, 504, 508, 510};

  k_init<<<288, 768, 0, stream>>>(l_idx, r_idx, emb, W_ioux, b_ioux, b_iouh,
                                  W_iouh, W_fh, W_attnh,
                                  cmatA, matA, cmatB, matB, (unsigned*)W16);
  for (int i = 1; i <= 8; ++i){
    int Nc = 256 >> i;
    int oP = offs[i-1], oC = offs[i];
    if (Nc >= 128)
      k_levelAB<4><<<(2*Nc/4)*4, 512, 0, stream>>>(W16, b_iouh, b_fh, Nc, oP, oC,
                                                   cmatA, matA, cmatB, matB);
    else if (Nc >= 64)
      k_levelAB<2><<<(2*Nc/2)*4, 512, 0, stream>>>(W16, b_iouh, b_fh, Nc, oP, oC,
                                                   cmatA, matA, cmatB, matB);
    else
      k_levelAB<1><<<(2*Nc)*4, 512, 0, stream>>>(W16, b_iouh, b_fh, Nc, oP, oC,
                                                 cmatA, matA, cmatB, matB);
  }
  k_mid<<<450, 256, 0, stream>>>(W_attnh, b_attnh, matA, matB,
                                 projA, projB, colA, colB, matTA, matTB, php);
  k_scores_t<4><<<2*(256/4)*4, 256, 0, stream>>>(php, projA, projB,
                                                 matTA, matTB, Wa, 256, 0, 1,
                                                 wsumP, esumP);
  for (int i = 1; i <= 8; ++i){
    int Nc = 256 >> i;
    int oP = offs[i-1], oC = offs[i];
    const float* childHC = (i == 1) ? matB  : hstageC;  // C's h0 = pass-B rows
    const float* childHD = (i == 1) ? matA  : hstageD;
    const float* childCC = (i == 1) ? cmatB : cmatC;
    const float* childCD = (i == 1) ? cmatA : cmatD;
    if (Nc >= 32){
      if (Nc >= 128)
        k_cd1<4><<<(2*Nc/4)*4, 512, 0, stream>>>(W16, b_iouh, b_fh, Nc, oP, oC,
                                                 colA, colB, wsumP, esumP,
                                                 childHC, childHD, childCC, childCD,
                                                 cmatC, cmatD, hstageC, hstageD, php);
      else if (Nc >= 64)
        k_cd1<2><<<(2*Nc/2)*4, 512, 0, stream>>>(W16, b_iouh, b_fh, Nc, oP, oC,
                                                 colA, colB, wsumP, esumP,
                                                 childHC, childHD, childCC, childCD,
                                                 cmatC, cmatD, hstageC, hstageD, php);
      else
        k_cd1<1><<<(2*Nc)*4, 512, 0, stream>>>(W16, b_iouh, b_fh, Nc, oP, oC,
                                               colA, colB, wsumP, esumP,
                                               childHC, childHD, childCC, childCD,
                                               cmatC, cmatD, hstageC, hstageD, php);
      k_scores_t<4><<<2*(Nc/4)*4, 256, 0, stream>>>(php, projA, projB,
                                                    matTA, matTB, Wa, Nc, offs[i], 4,
                                                    wsumP, esumP);
    } else {
      // Nc = 16, 8, 4, 2, 1: per-row cd+scores fused (width preserved)
      k_cdtail<<<2*Nc, 512, 0, stream>>>(W16, b_iouh, b_fh, Nc, oP, oC,
                                         colA, colB, wsumP, esumP,
                                         childHC, childHD, childCC, childCD,
                                         cmatC, cmatD, hstageC, hstageD,
                                         projA, projB, matA, matB, Wa);
    }
  }
  k_head<<<1, 256, 0, stream>>>(W_wh, b_wh, W_wp, b_wp, matA, matB,
                                colA, colB, wsumP, esumP, hstageC, hstageD,
                                (float*)d_out);
}

// Round 8
// 513.227 us; speedup vs baseline: 2.5784x; 1.1793x over previous
//
#include <hip/hip_runtime.h>

#define RC 130816   // 511*256
#define MT 512      // matT m-stride (511 zero-padded)

// bf16 weight cache layout (ushort offsets)
#define B16_FH   196608   // after 768*256 iou rows
#define B16_W1   262144   // 256*256 (W_attnh[:, :256])

__device__ __forceinline__ float rcpf(float x){ return __builtin_amdgcn_rcpf(x); }
__device__ __forceinline__ float sigmf(float x){ return rcpf(1.f + __expf(-x)); }
__device__ __forceinline__ float tanhfast(float x){
  return 1.f - 2.f*rcpf(1.f + __expf(2.f*x));
}

// ---- bf16-as-integer helpers ----
__device__ __forceinline__ float bfl(unsigned x){ return __uint_as_float(x << 16); }
__device__ __forceinline__ float bfh(unsigned x){ return __uint_as_float(x & 0xFFFF0000u); }
__device__ __forceinline__ unsigned bpack(float a, float b){
  unsigned ua = __float_as_uint(a), ub = __float_as_uint(b);
  return ((ua + 0x7FFFu + ((ua>>16)&1u)) >> 16)
       | ((ub + 0x7FFFu + ((ub>>16)&1u)) & 0xFFFF0000u);
}
__device__ __forceinline__ float dot8b(uint4 w, const float4* s4){
  float4 s0 = s4[0], s1 = s4[1];
  return bfl(w.x)*s0.x + bfh(w.x)*s0.y + bfl(w.y)*s0.z + bfh(w.y)*s0.w
       + bfl(w.z)*s1.x + bfh(w.z)*s1.y + bfl(w.w)*s1.z + bfh(w.w)*s1.w;
}

// ---------------------------------------------------------------------------
// Init (blocks 0..255) + weight pack (blocks 256..287). 768 threads.
// (verified rounds 5/6/7)
// ---------------------------------------------------------------------------
__global__ void __launch_bounds__(768) k_init(
    const int* __restrict__ l_idx, const int* __restrict__ r_idx,
    const float* __restrict__ emb, const float* __restrict__ W_ioux,
    const float* __restrict__ b_ioux, const float* __restrict__ b_iouh,
    const float* __restrict__ W_iouh, const float* __restrict__ W_fh,
    const float* __restrict__ W_attnh,
    float* __restrict__ cmatA, float* __restrict__ matA,
    float* __restrict__ cmatB, float* __restrict__ matB,
    unsigned* __restrict__ W16u)
{
  int b = blockIdx.x, tid = threadIdx.x;
  if (b >= 256){
    int gid = (b - 256)*768 + tid, gs = 32*768;
    for (int k = gid; k < 98304; k += gs){
      int i = 2*k; W16u[k] = bpack(W_iouh[i], W_iouh[i+1]);
    }
    for (int k = gid; k < 32768; k += gs){
      int i = 2*k; W16u[98304 + k] = bpack(W_fh[i], W_fh[i+1]);
    }
    for (int k = gid; k < 32768; k += gs){
      int i = 2*k; int t = i>>8, e = i&255;
      const float* r = W_attnh + (size_t)t*512;
      W16u[131072 + k] = bpack(r[e], r[e+1]);
    }
    return;
  }
  int p = b >> 7, n0 = (b & 127) * 2;
  __shared__ __align__(16) float xs[2*304];
  __shared__ float sg[2*768];
  for (int j = tid; j < 600; j += 768){
    int rr = j/300, d = j - rr*300;
    int row = p ? r_idx[n0+rr] : l_idx[n0+rr];
    xs[rr*304 + d] = emb[(size_t)row*300 + d];
  }
  __syncthreads();
  const float4* w = (const float4*)(W_ioux + (size_t)tid*300);
  float a0 = 0.f, a1 = 0.f;
  #pragma unroll 5
  for (int k = 0; k < 75; ++k){
    float4 wv = w[k];
    const float* x0 = xs + 4*k;
    const float* x1 = xs + 304 + 4*k;
    a0 += wv.x*x0[0] + wv.y*x0[1] + wv.z*x0[2] + wv.w*x0[3];
    a1 += wv.x*x1[0] + wv.y*x1[1] + wv.z*x1[2] + wv.w*x1[3];
  }
  float bb = b_ioux[tid] + b_iouh[tid];
  sg[tid] = a0 + bb;
  sg[768 + tid] = a1 + bb;
  __syncthreads();
  if (tid < 512){
    int rr = tid >> 8, t = tid & 255;
    const float* g = sg + rr*768;
    float c = sigmf(g[t]) * tanhfast(g[512+t]);
    float h = sigmf(g[256+t]) * tanhfast(c);
    (p ? cmatB : cmatA)[(size_t)(n0+rr)*256 + t] = c;
    (p ? matB  : matA )[(size_t)(n0+rr)*256 + t] = h;
  }
}

// ---------------------------------------------------------------------------
// A/B tree level (verified baseline).
// ---------------------------------------------------------------------------
template<int R>
__global__ void __launch_bounds__(512) k_levelAB(
    const unsigned short* __restrict__ W16, const float* __restrict__ b_iouh,
    const float* __restrict__ b_fh,
    int Nc, int offPrev, int offCur,
    float* __restrict__ cmatA, float* __restrict__ matA,
    float* __restrict__ cmatB, float* __restrict__ matB)
{
  int bid = blockIdx.x, tid = threadIdx.x;
  int s = bid & 3, g2 = bid >> 2;
  int groups = Nc / R;
  int p = (g2 >= groups) ? 1 : 0;
  int n0 = (g2 - p*groups) * R;
  float* cmat = p ? cmatB : cmatA;
  float* hmat = p ? matB  : matA;

  __shared__ __align__(16) float hs0[R][256], hs1[R][256], hss[R][256];
  __shared__ float sP[10][R][64];

  for (int it = tid; it < R*2*256; it += 512){
    int j = it & 255, ch = (it>>8)&1, r = it>>9;
    float v = hmat[(size_t)(offPrev + 2*(n0+r) + ch)*256 + j];
    if (ch) hs1[r][j] = v; else hs0[r][j] = v;
  }
  __syncthreads();
  for (int it = tid; it < R*256; it += 512){
    int j = it & 255, r = it>>8;
    hss[r][j] = hs0[r][j] + hs1[r][j];
  }
  __syncthreads();

  {
    int role = tid >> 6, cl = tid & 63;
    int gate = role & 3, dh = role >> 2;
    int col = s*64 + cl;
    if (gate < 3){
      const unsigned short* wrow = W16 + (size_t)(col + gate*256)*256;
      const uint4* w4 = (const uint4*)(wrow + dh*128);
      float acc[R];
      #pragma unroll
      for (int r = 0; r < R; ++r) acc[r] = 0.f;
      #pragma unroll 4
      for (int k = 0; k < 16; ++k){
        uint4 w = w4[k];
        #pragma unroll
        for (int r = 0; r < R; ++r)
          acc[r] += dot8b(w, (const float4*)(&hss[r][dh*128 + k*8]));
      }
      #pragma unroll
      for (int r = 0; r < R; ++r) sP[gate*2+dh][r][cl] = acc[r];
    } else {
      const uint4* w4 = (const uint4*)(W16 + B16_FH + (size_t)col*256 + dh*128);
      float a0[R], a1[R];
      #pragma unroll
      for (int r = 0; r < R; ++r){ a0[r] = 0.f; a1[r] = 0.f; }
      #pragma unroll 4
      for (int k = 0; k < 16; ++k){
        uint4 w = w4[k];
        #pragma unroll
        for (int r = 0; r < R; ++r){
          a0[r] += dot8b(w, (const float4*)(&hs0[r][dh*128 + k*8]));
          a1[r] += dot8b(w, (const float4*)(&hs1[r][dh*128 + k*8]));
        }
      }
      #pragma unroll
      for (int r = 0; r < R; ++r){ sP[6+dh][r][cl] = a0[r]; sP[8+dh][r][cl] = a1[r]; }
    }
  }
  __syncthreads();
  if (tid < 64*R){
    int r = tid >> 6, cl = tid & 63;
    int t = s*64 + cl;
    int n = n0 + r;
    float ai  = sP[0][r][cl] + sP[1][r][cl];
    float ao  = sP[2][r][cl] + sP[3][r][cl];
    float au  = sP[4][r][cl] + sP[5][r][cl];
    float af0 = sP[6][r][cl] + sP[7][r][cl];
    float af1 = sP[8][r][cl] + sP[9][r][cl];
    float c0 = cmat[(size_t)(offPrev+2*n)*256 + t];
    float c1 = cmat[(size_t)(offPrev+2*n+1)*256 + t];
    float i_ = sigmf(ai + b_iouh[t]);
    float o_ = sigmf(ao + b_iouh[256+t]);
    float u_ = tanhfast(au + b_iouh[512+t]);
    float bf = b_fh[t];
    float c = i_*u_ + sigmf(af0+bf)*c0 + sigmf(af1+bf)*c1;
    float h = o_*tanhfast(c);
    cmat[(size_t)(offCur+n)*256 + t] = c;
    hmat[(size_t)(offCur+n)*256 + t] = h;
  }
}

// ---------------------------------------------------------------------------
// Mid (verified baseline).
// ---------------------------------------------------------------------------
__global__ void __launch_bounds__(256) k_mid(
    const float* __restrict__ W_attnh, const float* __restrict__ b_attnh,
    const float* __restrict__ matA, const float* __restrict__ matB,
    float* __restrict__ projA, float* __restrict__ projB,
    float* __restrict__ colA, float* __restrict__ colB,
    float* __restrict__ matTA, float* __restrict__ matTB,
    float* __restrict__ php)
{
  int b = blockIdx.x, tid = threadIdx.x;
  if (b < 128){
    int p = b>>6, ch = b&63, m0 = ch*8, mc = min(8, 511-m0);
    const float* mat = p ? matB : matA;
    float* proj = p ? projB : projA;
    __shared__ __align__(16) float ms[256*8];   // ms[e*8+rr]
    for (int j = tid; j < mc*256; j += 256){
      int rr = j>>8, e = j&255;
      ms[e*8+rr] = mat[(size_t)(m0+rr)*256 + e];
    }
    for (int j = tid + mc*256; j < 8*256; j += 256){
      int rr = j>>8, e = j&255; ms[e*8+rr] = 0.f;
    }
    __syncthreads();
    int t = tid;
    const float4* w2 = (const float4*)(W_attnh + (size_t)t*512 + 256);
    float acc[8] = {0,0,0,0,0,0,0,0};
    #pragma unroll 2
    for (int k = 0; k < 64; ++k){
      float4 w = w2[k];
      const float* base = ms + k*32;
      #pragma unroll
      for (int rr = 0; rr < 8; ++rr)
        acc[rr] += w.x*base[rr] + w.y*base[8+rr] + w.z*base[16+rr] + w.w*base[24+rr];
    }
    float ba = b_attnh[t];
    for (int rr = 0; rr < mc; ++rr) proj[(size_t)(m0+rr)*256 + t] = acc[rr] + ba;
  } else if (b < 130){
    int p = b - 128;
    const float* mat = p ? matB : matA;
    float* col = p ? colB : colA;
    float s = 0.f;
    #pragma unroll 8
    for (int m = 0; m < 511; ++m) s += mat[(size_t)m*256 + tid];
    col[tid] = s;
  } else if (b < 386){
    int idx = b - 130;
    int p = idx>>7, rem = idx&127, jt = rem>>4, mt = rem&15;
    const float* mat = p ? matB : matA;
    float* matT = p ? matTB : matTA;
    __shared__ float tile[32][33];
    int c = tid&31, r0 = tid>>5;
    int m0 = mt*32, j0 = jt*32;
    #pragma unroll
    for (int k = 0; k < 4; ++k){
      int m = m0 + r0 + 8*k;
      tile[r0+8*k][c] = (m < 511) ? mat[(size_t)m*256 + j0 + c] : 0.f;
    }
    __syncthreads();
    #pragma unroll
    for (int k = 0; k < 4; ++k){
      int jj = r0 + 8*k;
      matT[(size_t)(j0+jj)*MT + m0 + c] = tile[c][jj];
    }
  } else {
    int idx = b - 386;           // 64 blocks: p (C/D) x 32 chunks of 8 rows
    int p = idx>>5, ch = idx&31, r0 = ch*8;
    const float* hsrc = p ? matA : matB;   // C<-B, D<-A
    __shared__ __align__(16) float ms[256*8];
    for (int j = tid; j < 8*256; j += 256){
      int rr = j>>8, e = j&255;
      ms[e*8+rr] = hsrc[(size_t)(r0+rr)*256 + e];
    }
    __syncthreads();
    int t = tid;
    const float4* w1 = (const float4*)(W_attnh + (size_t)t*512);
    float acc[8] = {0,0,0,0,0,0,0,0};
    #pragma unroll 2
    for (int k = 0; k < 64; ++k){
      float4 w = w1[k];
      const float* base = ms + k*32;
      #pragma unroll
      for (int rr = 0; rr < 8; ++rr)
        acc[rr] += w.x*base[rr] + w.y*base[8+rr] + w.z*base[16+rr] + w.w*base[24+rr];
    }
    #pragma unroll
    for (int rr = 0; rr < 8; ++rr)
      php[(((size_t)p*511 + r0+rr)*4 + 0)*256 + t] = acc[rr];
  }
}

// ---------------------------------------------------------------------------
// Tiled scores (verified + fold, rounds 6/7).
// ---------------------------------------------------------------------------
template<int G>
__global__ void __launch_bounds__(256) k_scores_t(
    const float* __restrict__ php,
    const float* __restrict__ projA, const float* __restrict__ projB,
    const float* __restrict__ matTA, const float* __restrict__ matTB,
    const float* __restrict__ Wa, int Nc, int rowOff, int S,
    float* __restrict__ wsumP, float* __restrict__ esumP)
{
  const float CE = 2.885390082f;   // 2*log2(e)
  int b = blockIdx.x, tid = threadIdx.x;
  int groups = Nc / G;
  int per = groups * 4;
  int p = b / per; int rem = b - p*per; int g = rem >> 2, ch = rem & 3;
  int row0 = rowOff + g*G;
  const float* proj = p ? projB : projA;
  const float* matT = p ? matTB : matTA;

  __shared__ __align__(16) float shp[G*256];
  __shared__ __align__(16) float swa[256];
  __shared__ __align__(16) float spart[G*256];
  __shared__ __align__(16) float se[G*128];

  for (int j = tid; j < G*256; j += 256){
    int row = row0 + (j>>8), jj = j&255;
    const float* base = php + (((size_t)p*511 + row)*4)*256 + jj;
    float v = base[0];
    if (S == 4) v += base[256] + base[512] + base[768];
    shp[j] = v * CE;
  }
  swa[tid] = Wa[tid];
  __syncthreads();

  int ml = tid & 127, dh = tid >> 7;
  int m = ch*128 + ml;
  float part[G];
  #pragma unroll
  for (int r = 0; r < G; ++r) part[r] = 0.f;
  if (m < 511){
    const float4* pr  = (const float4*)(proj + (size_t)m*256 + dh*128);
    const float4* wa4 = (const float4*)(swa + dh*128);
    #pragma unroll 4
    for (int k = 0; k < 32; ++k){
      float4 pv = pr[k], wv = wa4[k];
      float p0 = pv.x*CE, p1 = pv.y*CE, p2 = pv.z*CE, p3 = pv.w*CE;
      int dbase = dh*128 + k*4;
      #pragma unroll
      for (int r = 0; r < G; ++r){
        const float* hr = shp + r*256 + dbase;
        part[r] += wv.x*rcpf(1.f + exp2f(hr[0]+p0))
                 + wv.y*rcpf(1.f + exp2f(hr[1]+p1))
                 + wv.z*rcpf(1.f + exp2f(hr[2]+p2))
                 + wv.w*rcpf(1.f + exp2f(hr[3]+p3));
      }
    }
  }
  #pragma unroll
  for (int r = 0; r < G; ++r) spart[r*256 + tid] = part[r];
  __syncthreads();
  if (tid < 128){
    #pragma unroll
    for (int r = 0; r < G; ++r){
      float s = spart[r*256 + ml] + spart[r*256 + 128 + ml];
      se[r*128 + ml] = (ch*128 + ml < 511) ? __expf(-2.f*s) : 0.f;
    }
  }
  __syncthreads();
  {
    const float4* mt = (const float4*)(matT + (size_t)tid*MT + ch*128);
    float acc[G];
    #pragma unroll
    for (int r = 0; r < G; ++r) acc[r] = 0.f;
    #pragma unroll 4
    for (int k = 0; k < 32; ++k){
      float4 mv = mt[k];
      #pragma unroll
      for (int r = 0; r < G; ++r){
        float4 ev = ((const float4*)(se + r*128))[k];
        acc[r] += mv.x*ev.x + mv.y*ev.y + mv.z*ev.z + mv.w*ev.w;
      }
    }
    #pragma unroll
    for (int r = 0; r < G; ++r)
      wsumP[(((size_t)p*511 + row0 + r)*4 + ch)*256 + tid] = acc[r];
  }
  if (tid < G){
    float s = 0.f;
    const float* sr = se + tid*128;
    for (int k = 0; k < 128; ++k) s += sr[k];
    esumP[((size_t)p*511 + row0 + tid)*4 + ch] = s;
  }
}

// ---------------------------------------------------------------------------
// CD spine, batched (verified baseline) — all levels.
// ---------------------------------------------------------------------------
template<int R>
__global__ void __launch_bounds__(512) k_cd1(
    const unsigned short* __restrict__ W16, const float* __restrict__ b_iouh,
    const float* __restrict__ b_fh,
    int Nc, int offPrev, int offCur,
    const float* __restrict__ colA, const float* __restrict__ colB,
    const float* __restrict__ wsumP, const float* __restrict__ esumP,
    const float* __restrict__ childHC, const float* __restrict__ childHD,
    const float* __restrict__ childCC, const float* __restrict__ childCD_,
    float* __restrict__ cmatC, float* __restrict__ cmatD,
    float* __restrict__ hstageC, float* __restrict__ hstageD,
    float* __restrict__ php)
{
  int bid = blockIdx.x, tid = threadIdx.x;
  int s = bid & 3, g2 = bid >> 2;
  int groups = Nc / R;
  int p = (g2 >= groups) ? 1 : 0;
  int n0 = (g2 - p*groups) * R;
  const float* colv   = p ? colB : colA;
  const float* childH = p ? childHD : childHC;
  const float* childC = p ? childCD_ : childCC;
  float* cmat   = p ? cmatD : cmatC;
  float* hstage = p ? hstageD : hstageC;

  __shared__ __align__(16) float hs0[R][256], hs1[R][256], hss[R][256];
  __shared__ float sP[10][R][64];
  __shared__ __align__(16) float sh[R][64];
  __shared__ float sHP[2][256];

  for (int it = tid; it < R*2*256; it += 512){
    int j = it & 255, ch = (it>>8)&1, r = it>>9;
    int rc = offPrev + 2*(n0+r) + ch;
    const float* wp = wsumP + (((size_t)p*511 + rc)*4)*256;
    const float* ep = esumP + ((size_t)p*511 + rc)*4;
    float w = wp[j] + wp[256+j] + wp[512+j] + wp[768+j];
    float esum = ep[0]+ep[1]+ep[2]+ep[3];
    float hatt = colv[j] - w*rcpf(esum) + childH[(size_t)rc*256 + j];
    if (ch) hs1[r][j] = hatt; else hs0[r][j] = hatt;
  }
  __syncthreads();
  for (int it = tid; it < R*256; it += 512){
    int j = it & 255, r = it>>8;
    hss[r][j] = hs0[r][j] + hs1[r][j];
  }
  __syncthreads();

  {
    int role = tid >> 6, cl = tid & 63;
    int gate = role & 3, dh = role >> 2;
    int col = s*64 + cl;
    if (gate < 3){
      const unsigned short* wrow = W16 + (size_t)(col + gate*256)*256;
      const uint4* w4 = (const uint4*)(wrow + dh*128);
      float acc[R];
      #pragma unroll
      for (int r = 0; r < R; ++r) acc[r] = 0.f;
      #pragma unroll 4
      for (int k = 0; k < 16; ++k){
        uint4 w = w4[k];
        #pragma unroll
        for (int r = 0; r < R; ++r)
          acc[r] += dot8b(w, (const float4*)(&hss[r][dh*128 + k*8]));
      }
      #pragma unroll
      for (int r = 0; r < R; ++r) sP[gate*2+dh][r][cl] = acc[r];
    } else {
      const uint4* w4 = (const uint4*)(W16 + B16_FH + (size_t)col*256 + dh*128);
      float a0[R], a1[R];
      #pragma unroll
      for (int r = 0; r < R; ++r){ a0[r] = 0.f; a1[r] = 0.f; }
      #pragma unroll 4
      for (int k = 0; k < 16; ++k){
        uint4 w = w4[k];
        #pragma unroll
        for (int r = 0; r < R; ++r){
          a0[r] += dot8b(w, (const float4*)(&hs0[r][dh*128 + k*8]));
          a1[r] += dot8b(w, (const float4*)(&hs1[r][dh*128 + k*8]));
        }
      }
      #pragma unroll
      for (int r = 0; r < R; ++r){ sP[6+dh][r][cl] = a0[r]; sP[8+dh][r][cl] = a1[r]; }
    }
  }
  __syncthreads();

  if (tid < 64*R){
    int r = tid >> 6, cl = tid & 63;
    int t = s*64 + cl;
    int n = n0 + r;
    float ai  = sP[0][r][cl] + sP[1][r][cl];
    float ao  = sP[2][r][cl] + sP[3][r][cl];
    float au  = sP[4][r][cl] + sP[5][r][cl];
    float af0 = sP[6][r][cl] + sP[7][r][cl];
    float af1 = sP[8][r][cl] + sP[9][r][cl];
    float c0 = childC[(size_t)(offPrev+2*n)*256 + t];
    float c1 = childC[(size_t)(offPrev+2*n+1)*256 + t];
    float i_ = sigmf(ai + b_iouh[t]);
    float o_ = sigmf(ao + b_iouh[256+t]);
    float u_ = tanhfast(au + b_iouh[512+t]);
    float bf = b_fh[t];
    float c = i_*u_ + sigmf(af0+bf)*c0 + sigmf(af1+bf)*c1;
    float h = o_*tanhfast(c);
    cmat[(size_t)(offCur+n)*256 + t] = c;
    hstage[(size_t)(offCur+n)*256 + t] = h;
    sh[r][cl] = h;
  }
  __syncthreads();

  {
    int j = tid & 255, eh = tid >> 8;
    const uint4* w1 = (const uint4*)(W16 + B16_W1 + (size_t)j*256 + s*64 + eh*32);
    uint4 wv[4];
    #pragma unroll
    for (int k = 0; k < 4; ++k) wv[k] = w1[k];
    float aacc[R];
    #pragma unroll
    for (int r = 0; r < R; ++r){
      float a = 0.f;
      #pragma unroll
      for (int k = 0; k < 4; ++k)
        a += dot8b(wv[k], (const float4*)(&sh[r][eh*32 + k*8]));
      aacc[r] = a;
    }
    #pragma unroll
    for (int r = 0; r < R; ++r){
      sHP[eh][j] = aacc[r];
      __syncthreads();
      if (tid < 256){
        int row = offCur + n0 + r;
        php[(((size_t)p*511 + row)*4 + s)*256 + tid] = sHP[0][tid] + sHP[1][tid];
      }
      __syncthreads();
    }
  }
}

// ---------------------------------------------------------------------------
// Head (verified baseline).
// ---------------------------------------------------------------------------
__global__ void __launch_bounds__(256) k_head(
    const float* __restrict__ W_wh, const float* __restrict__ b_wh,
    const float* __restrict__ W_wp, const float* __restrict__ b_wp,
    const float* __restrict__ matA, const float* __restrict__ matB,
    const float* __restrict__ colA, const float* __restrict__ colB,
    const float* __restrict__ wsumP, const float* __restrict__ esumP,
    const float* __restrict__ hstageC, const float* __restrict__ hstageD,
    float* __restrict__ out)
{
  __shared__ __align__(16) float v[512];
  __shared__ float og[128], lg[5];
  int t = threadIdx.x;
  {
    const float* wpC = wsumP + (((size_t)0*511 + 510)*4)*256;
    const float* epC = esumP + ((size_t)0*511 + 510)*4;
    float wC = wpC[t] + wpC[256+t] + wpC[512+t] + wpC[768+t];
    float eC = epC[0]+epC[1]+epC[2]+epC[3];
    float hCf = colA[t] - wC*rcpf(eC) + hstageC[(size_t)510*256 + t];
    const float* wpD = wsumP + (((size_t)1*511 + 510)*4)*256;
    const float* epD = esumP + ((size_t)1*511 + 510)*4;
    float wD = wpD[t] + wpD[256+t] + wpD[512+t] + wpD[768+t];
    float eD = epD[0]+epD[1]+epD[2]+epD[3];
    float hDf = colB[t] - wD*rcpf(eD) + hstageD[(size_t)510*256 + t];
    float lh = tanhfast(matA[(size_t)510*256 + t] + hDf);
    float rh = tanhfast(hCf + matB[(size_t)510*256 + t]);
    v[t] = lh*rh;
    v[256+t] = fabsf(lh - rh);
  }
  __syncthreads();
  if (t < 128){
    const float4* w = (const float4*)(W_wh + (size_t)t*512);
    const float4* vv = (const float4*)v;
    float a = b_wh[t];
    #pragma unroll 4
    for (int k = 0; k < 128; ++k){
      float4 wv = w[k], x = vv[k];
      a += wv.x*x.x + wv.y*x.y + wv.z*x.z + wv.w*x.w;
    }
    og[t] = sigmf(a);
  }
  __syncthreads();
  if (t < 5){
    const float* wp = W_wp + (size_t)t*128;
    float a = b_wp[t];
    for (int j = 0; j < 128; ++j) a += og[j]*wp[j];
    lg[t] = a;
  }
  __syncthreads();
  if (t == 0){
    float M = -1e30f;
    for (int c = 0; c < 5; ++c) M = fmaxf(M, lg[c]);
    float S = 0.f;
    for (int c = 0; c < 5; ++c) S += __expf(lg[c] - M);
    float L = logf(S);
    for (int c = 0; c < 5; ++c) out[c] = lg[c] - M - L;
  }
}

extern "C" void kernel_launch(void* const* d_in, const int* in_sizes, int n_in,
                              void* d_out, int out_size, void* d_ws, size_t ws_size,
                              hipStream_t stream)
{
  const int*   l_idx   = (const int*)  d_in[0];
  const int*   r_idx   = (const int*)  d_in[1];
  const float* emb     = (const float*)d_in[2];
  const float* W_ioux  = (const float*)d_in[3];
  const float* b_ioux  = (const float*)d_in[4];
  const float* W_iouh  = (const float*)d_in[5];
  const float* b_iouh  = (const float*)d_in[6];
  // d_in[7]=W_fx, d_in[8]=b_fx unused by the forward
  const float* W_fh    = (const float*)d_in[9];
  const float* b_fh    = (const float*)d_in[10];
  const float* Wa      = (const float*)d_in[11];
  const float* W_attnh = (const float*)d_in[12];
  const float* b_attnh = (const float*)d_in[13];
  const float* W_wh    = (const float*)d_in[14];
  const float* b_wh    = (const float*)d_in[15];
  const float* W_wp    = (const float*)d_in[16];
  const float* b_wp    = (const float*)d_in[17];

  float* ws = (float*)d_ws;
  float* cmatA   = ws;               float* cmatB   = cmatA + RC;
  float* cmatC   = cmatB + RC;       float* cmatD   = cmatC + RC;
  float* matA    = cmatD + RC;       float* matB    = matA + RC;
  float* hstageC = matB + RC;        float* hstageD = hstageC + RC;
  float* projA   = hstageD + RC;     float* projB   = projA + RC;
  float* matTA   = projB + RC;       float* matTB   = matTA + 256*MT;
  float* colA    = matTB + 256*MT;   float* colB    = colA + 256;
  float* wsumP   = colB + 256;            // 2*511*4*256
  float* esumP   = wsumP + 2*511*4*256;   // 2*511*4
  float* php     = esumP + 2*511*4;       // 2*511*4*256
  unsigned short* W16 = (unsigned short*)(php + 2*511*4*256);  // 327,680 ushorts

  static const int offs[9] = {0, 256, 384, 448, 480, 496, 504, 508, 510};

  k_init<<<288, 768, 0, stream>>>(l_idx, r_idx, emb, W_ioux, b_ioux, b_iouh,
                                  W_iouh, W_fh, W_attnh,
                                  cmatA, matA, cmatB, matB, (unsigned*)W16);
  for (int i = 1; i <= 8; ++i){
    int Nc = 256 >> i;
    int oP = offs[i-1], oC = offs[i];
    if (Nc >= 128)
      k_levelAB<4><<<(2*Nc/4)*4, 512, 0, stream>>>(W16, b_iouh, b_fh, Nc, oP, oC,
                                                   cmatA, matA, cmatB, matB);
    else if (Nc >= 64)
      k_levelAB<2><<<(2*Nc/2)*4, 512, 0, stream>>>(W16, b_iouh, b_fh, Nc, oP, oC,
                                                   cmatA, matA, cmatB, matB);
    else
      k_levelAB<1><<<(2*Nc)*4, 512, 0, stream>>>(W16, b_iouh, b_fh, Nc, oP, oC,
                                                 cmatA, matA, cmatB, matB);
  }
  k_mid<<<450, 256, 0, stream>>>(W_attnh, b_attnh, matA, matB,
                                 projA, projB, colA, colB, matTA, matTB, php);
  k_scores_t<4><<<2*(256/4)*4, 256, 0, stream>>>(php, projA, projB,
                                                 matTA, matTB, Wa, 256, 0, 1,
                                                 wsumP, esumP);
  for (int i = 1; i <= 8; ++i){
    int Nc = 256 >> i;
    int oP = offs[i-1], oC = offs[i];
    const float* childHC = (i == 1) ? matB  : hstageC;  // C's h0 = pass-B rows
    const float* childHD = (i == 1) ? matA  : hstageD;
    const float* childCC = (i == 1) ? cmatB : cmatC;
    const float* childCD = (i == 1) ? cmatA : cmatD;
    if (Nc >= 128)
      k_cd1<4><<<(2*Nc/4)*4, 512, 0, stream>>>(W16, b_iouh, b_fh, Nc, oP, oC,
                                               colA, colB, wsumP, esumP,
                                               childHC, childHD, childCC, childCD,
                                               cmatC, cmatD, hstageC, hstageD, php);
    else if (Nc >= 64)
      k_cd1<2><<<(2*Nc/2)*4, 512, 0, stream>>>(W16, b_iouh, b_fh, Nc, oP, oC,
                                               colA, colB, wsumP, esumP,
                                               childHC, childHD, childCC, childCD,
                                               cmatC, cmatD, hstageC, hstageD, php);
    else
      k_cd1<1><<<(2*Nc)*4, 512, 0, stream>>>(W16, b_iouh, b_fh, Nc, oP, oC,
                                             colA, colB, wsumP, esumP,
                                             childHC, childHD, childCC, childCD,
                                             cmatC, cmatD, hstageC, hstageD, php);
    if (Nc >= 4)
      k_scores_t<4><<<2*(Nc/4)*4, 256, 0, stream>>>(php, projA, projB,
                                                    matTA, matTB, Wa, Nc, offs[i], 4,
                                                    wsumP, esumP);
    else if (Nc == 2)
      k_scores_t<2><<<2*(Nc/2)*4, 256, 0, stream>>>(php, projA, projB,
                                                    matTA, matTB, Wa, Nc, offs[i], 4,
                                                    wsumP, esumP);
    else
      k_scores_t<1><<<2*Nc*4, 256, 0, stream>>>(php, projA, projB,
                                                matTA, matTB, Wa, Nc, offs[i], 4,
                                                wsumP, esumP);
  }
  k_head<<<1, 256, 0, stream>>>(W_wh, b_wh, W_wp, b_wp, matA, matB,
                                colA, colB, wsumP, esumP, hstageC, hstageD,
                                (float*)d_out);
}

// Round 9
// 494.389 us; speedup vs baseline: 2.6767x; 1.0381x over previous
//
#include <hip/hip_runtime.h>

#define RC 130816   // 511*256
#define MT 512      // matT m-stride (511 zero-padded)

// bf16 weight cache layout (ushort offsets)
#define B16_FH   196608   // after 768*256 iou rows
#define B16_W1   262144   // 256*256 (W_attnh[:, :256])

__device__ __forceinline__ float rcpf(float x){ return __builtin_amdgcn_rcpf(x); }
__device__ __forceinline__ float sigmf(float x){ return rcpf(1.f + __expf(-x)); }
__device__ __forceinline__ float tanhfast(float x){
  return 1.f - 2.f*rcpf(1.f + __expf(2.f*x));
}

// ---- bf16-as-integer helpers ----
__device__ __forceinline__ float bfl(unsigned x){ return __uint_as_float(x << 16); }
__device__ __forceinline__ float bfh(unsigned x){ return __uint_as_float(x & 0xFFFF0000u); }
__device__ __forceinline__ unsigned bpack(float a, float b){
  unsigned ua = __float_as_uint(a), ub = __float_as_uint(b);
  return ((ua + 0x7FFFu + ((ua>>16)&1u)) >> 16)
       | ((ub + 0x7FFFu + ((ub>>16)&1u)) & 0xFFFF0000u);
}
__device__ __forceinline__ float dot8b(uint4 w, const float4* s4){
  float4 s0 = s4[0], s1 = s4[1];
  return bfl(w.x)*s0.x + bfh(w.x)*s0.y + bfl(w.y)*s0.z + bfh(w.y)*s0.w
       + bfl(w.z)*s1.x + bfh(w.z)*s1.y + bfl(w.w)*s1.z + bfh(w.w)*s1.w;
}

// ---------------------------------------------------------------------------
// Init (blocks 0..255) + weight pack (blocks 256..287). 768 threads.
// Pack blocks 256/257 also zero colA/colB (k_mid accumulates via atomics;
// do NOT rely on workspace fill semantics).
// ---------------------------------------------------------------------------
__global__ void __launch_bounds__(768) k_init(
    const int* __restrict__ l_idx, const int* __restrict__ r_idx,
    const float* __restrict__ emb, const float* __restrict__ W_ioux,
    const float* __restrict__ b_ioux, const float* __restrict__ b_iouh,
    const float* __restrict__ W_iouh, const float* __restrict__ W_fh,
    const float* __restrict__ W_attnh,
    float* __restrict__ cmatA, float* __restrict__ matA,
    float* __restrict__ cmatB, float* __restrict__ matB,
    float* __restrict__ colA, float* __restrict__ colB,
    unsigned* __restrict__ W16u)
{
  int b = blockIdx.x, tid = threadIdx.x;
  if (b >= 256){
    if (b == 256 && tid < 256) colA[tid] = 0.f;
    if (b == 257 && tid < 256) colB[tid] = 0.f;
    int gid = (b - 256)*768 + tid, gs = 32*768;
    for (int k = gid; k < 98304; k += gs){
      int i = 2*k; W16u[k] = bpack(W_iouh[i], W_iouh[i+1]);
    }
    for (int k = gid; k < 32768; k += gs){
      int i = 2*k; W16u[98304 + k] = bpack(W_fh[i], W_fh[i+1]);
    }
    for (int k = gid; k < 32768; k += gs){
      int i = 2*k; int t = i>>8, e = i&255;
      const float* r = W_attnh + (size_t)t*512;
      W16u[131072 + k] = bpack(r[e], r[e+1]);
    }
    return;
  }
  int p = b >> 7, n0 = (b & 127) * 2;
  __shared__ __align__(16) float xs[2*304];
  __shared__ float sg[2*768];
  for (int j = tid; j < 600; j += 768){
    int rr = j/300, d = j - rr*300;
    int row = p ? r_idx[n0+rr] : l_idx[n0+rr];
    xs[rr*304 + d] = emb[(size_t)row*300 + d];
  }
  __syncthreads();
  const float4* w = (const float4*)(W_ioux + (size_t)tid*300);
  float a0 = 0.f, a1 = 0.f;
  #pragma unroll 5
  for (int k = 0; k < 75; ++k){
    float4 wv = w[k];
    const float* x0 = xs + 4*k;
    const float* x1 = xs + 304 + 4*k;
    a0 += wv.x*x0[0] + wv.y*x0[1] + wv.z*x0[2] + wv.w*x0[3];
    a1 += wv.x*x1[0] + wv.y*x1[1] + wv.z*x1[2] + wv.w*x1[3];
  }
  float bb = b_ioux[tid] + b_iouh[tid];
  sg[tid] = a0 + bb;
  sg[768 + tid] = a1 + bb;
  __syncthreads();
  if (tid < 512){
    int rr = tid >> 8, t = tid & 255;
    const float* g = sg + rr*768;
    float c = sigmf(g[t]) * tanhfast(g[512+t]);
    float h = sigmf(g[256+t]) * tanhfast(c);
    (p ? cmatB : cmatA)[(size_t)(n0+rr)*256 + t] = c;
    (p ? matB  : matA )[(size_t)(n0+rr)*256 + t] = h;
  }
}

// ---------------------------------------------------------------------------
// A/B tree level (verified baseline).
// ---------------------------------------------------------------------------
template<int R>
__global__ void __launch_bounds__(512) k_levelAB(
    const unsigned short* __restrict__ W16, const float* __restrict__ b_iouh,
    const float* __restrict__ b_fh,
    int Nc, int offPrev, int offCur,
    float* __restrict__ cmatA, float* __restrict__ matA,
    float* __restrict__ cmatB, float* __restrict__ matB)
{
  int bid = blockIdx.x, tid = threadIdx.x;
  int s = bid & 3, g2 = bid >> 2;
  int groups = Nc / R;
  int p = (g2 >= groups) ? 1 : 0;
  int n0 = (g2 - p*groups) * R;
  float* cmat = p ? cmatB : cmatA;
  float* hmat = p ? matB  : matA;

  __shared__ __align__(16) float hs0[R][256], hs1[R][256], hss[R][256];
  __shared__ float sP[10][R][64];

  for (int it = tid; it < R*2*256; it += 512){
    int j = it & 255, ch = (it>>8)&1, r = it>>9;
    float v = hmat[(size_t)(offPrev + 2*(n0+r) + ch)*256 + j];
    if (ch) hs1[r][j] = v; else hs0[r][j] = v;
  }
  __syncthreads();
  for (int it = tid; it < R*256; it += 512){
    int j = it & 255, r = it>>8;
    hss[r][j] = hs0[r][j] + hs1[r][j];
  }
  __syncthreads();

  {
    int role = tid >> 6, cl = tid & 63;
    int gate = role & 3, dh = role >> 2;
    int col = s*64 + cl;
    if (gate < 3){
      const unsigned short* wrow = W16 + (size_t)(col + gate*256)*256;
      const uint4* w4 = (const uint4*)(wrow + dh*128);
      float acc[R];
      #pragma unroll
      for (int r = 0; r < R; ++r) acc[r] = 0.f;
      #pragma unroll 4
      for (int k = 0; k < 16; ++k){
        uint4 w = w4[k];
        #pragma unroll
        for (int r = 0; r < R; ++r)
          acc[r] += dot8b(w, (const float4*)(&hss[r][dh*128 + k*8]));
      }
      #pragma unroll
      for (int r = 0; r < R; ++r) sP[gate*2+dh][r][cl] = acc[r];
    } else {
      const uint4* w4 = (const uint4*)(W16 + B16_FH + (size_t)col*256 + dh*128);
      float a0[R], a1[R];
      #pragma unroll
      for (int r = 0; r < R; ++r){ a0[r] = 0.f; a1[r] = 0.f; }
      #pragma unroll 4
      for (int k = 0; k < 16; ++k){
        uint4 w = w4[k];
        #pragma unroll
        for (int r = 0; r < R; ++r){
          a0[r] += dot8b(w, (const float4*)(&hs0[r][dh*128 + k*8]));
          a1[r] += dot8b(w, (const float4*)(&hs1[r][dh*128 + k*8]));
        }
      }
      #pragma unroll
      for (int r = 0; r < R; ++r){ sP[6+dh][r][cl] = a0[r]; sP[8+dh][r][cl] = a1[r]; }
    }
  }
  __syncthreads();
  if (tid < 64*R){
    int r = tid >> 6, cl = tid & 63;
    int t = s*64 + cl;
    int n = n0 + r;
    float ai  = sP[0][r][cl] + sP[1][r][cl];
    float ao  = sP[2][r][cl] + sP[3][r][cl];
    float au  = sP[4][r][cl] + sP[5][r][cl];
    float af0 = sP[6][r][cl] + sP[7][r][cl];
    float af1 = sP[8][r][cl] + sP[9][r][cl];
    float c0 = cmat[(size_t)(offPrev+2*n)*256 + t];
    float c1 = cmat[(size_t)(offPrev+2*n+1)*256 + t];
    float i_ = sigmf(ai + b_iouh[t]);
    float o_ = sigmf(ao + b_iouh[256+t]);
    float u_ = tanhfast(au + b_iouh[512+t]);
    float bf = b_fh[t];
    float c = i_*u_ + sigmf(af0+bf)*c0 + sigmf(af1+bf)*c1;
    float h = o_*tanhfast(c);
    cmat[(size_t)(offCur+n)*256 + t] = c;
    hmat[(size_t)(offCur+n)*256 + t] = h;
  }
}

// ---------------------------------------------------------------------------
// Mid: proj rows (0..127), matT transposes + colsum partials (128..383),
// leaf php (384..447). Colsum folded into transpose tiles (each tile already
// holds its 32x32 elements in LDS) -> removes the 2-block serial straggler.
// ---------------------------------------------------------------------------
__global__ void __launch_bounds__(256) k_mid(
    const float* __restrict__ W_attnh, const float* __restrict__ b_attnh,
    const float* __restrict__ matA, const float* __restrict__ matB,
    float* __restrict__ projA, float* __restrict__ projB,
    float* __restrict__ colA, float* __restrict__ colB,
    float* __restrict__ matTA, float* __restrict__ matTB,
    float* __restrict__ php)
{
  int b = blockIdx.x, tid = threadIdx.x;
  if (b < 128){
    int p = b>>6, ch = b&63, m0 = ch*8, mc = min(8, 511-m0);
    const float* mat = p ? matB : matA;
    float* proj = p ? projB : projA;
    __shared__ __align__(16) float ms[256*8];   // ms[e*8+rr]
    for (int j = tid; j < mc*256; j += 256){
      int rr = j>>8, e = j&255;
      ms[e*8+rr] = mat[(size_t)(m0+rr)*256 + e];
    }
    for (int j = tid + mc*256; j < 8*256; j += 256){
      int rr = j>>8, e = j&255; ms[e*8+rr] = 0.f;
    }
    __syncthreads();
    int t = tid;
    const float4* w2 = (const float4*)(W_attnh + (size_t)t*512 + 256);
    float acc[8] = {0,0,0,0,0,0,0,0};
    #pragma unroll 2
    for (int k = 0; k < 64; ++k){
      float4 w = w2[k];
      const float* base = ms + k*32;
      #pragma unroll
      for (int rr = 0; rr < 8; ++rr)
        acc[rr] += w.x*base[rr] + w.y*base[8+rr] + w.z*base[16+rr] + w.w*base[24+rr];
    }
    float ba = b_attnh[t];
    for (int rr = 0; rr < mc; ++rr) proj[(size_t)(m0+rr)*256 + t] = acc[rr] + ba;
  } else if (b < 384){
    int idx = b - 128;
    int p = idx>>7, rem = idx&127, jt = rem>>4, mt = rem&15;
    const float* mat = p ? matB : matA;
    float* matT = p ? matTB : matTA;
    float* col  = p ? colB  : colA;
    __shared__ float tile[32][33];
    int c = tid&31, r0 = tid>>5;
    int m0 = mt*32, j0 = jt*32;
    #pragma unroll
    for (int k = 0; k < 4; ++k){
      int m = m0 + r0 + 8*k;
      tile[r0+8*k][c] = (m < 511) ? mat[(size_t)m*256 + j0 + c] : 0.f;
    }
    __syncthreads();
    #pragma unroll
    for (int k = 0; k < 4; ++k){
      int jj = r0 + 8*k;
      matT[(size_t)(j0+jj)*MT + m0 + c] = tile[c][jj];
    }
    if (tid < 32){
      float s = 0.f;
      #pragma unroll
      for (int r = 0; r < 32; ++r) s += tile[r][tid];   // banks (r+tid)%32: conflict-free
      atomicAdd(col + j0 + tid, s);
    }
  } else {
    int idx = b - 384;           // 64 blocks: p (C/D) x 32 chunks of 8 rows
    int p = idx>>5, ch = idx&31, r0 = ch*8;
    const float* hsrc = p ? matA : matB;   // C<-B, D<-A
    __shared__ __align__(16) float ms[256*8];
    for (int j = tid; j < 8*256; j += 256){
      int rr = j>>8, e = j&255;
      ms[e*8+rr] = hsrc[(size_t)(r0+rr)*256 + e];
    }
    __syncthreads();
    int t = tid;
    const float4* w1 = (const float4*)(W_attnh + (size_t)t*512);
    float acc[8] = {0,0,0,0,0,0,0,0};
    #pragma unroll 2
    for (int k = 0; k < 64; ++k){
      float4 w = w1[k];
      const float* base = ms + k*32;
      #pragma unroll
      for (int rr = 0; rr < 8; ++rr)
        acc[rr] += w.x*base[rr] + w.y*base[8+rr] + w.z*base[16+rr] + w.w*base[24+rr];
    }
    #pragma unroll
    for (int rr = 0; rr < 8; ++rr)
      php[(((size_t)p*511 + r0+rr)*4 + 0)*256 + t] = acc[rr];
  }
}

// ---------------------------------------------------------------------------
// Tiled scores (verified + fold, rounds 6-8).
// ---------------------------------------------------------------------------
template<int G>
__global__ void __launch_bounds__(256) k_scores_t(
    const float* __restrict__ php,
    const float* __restrict__ projA, const float* __restrict__ projB,
    const float* __restrict__ matTA, const float* __restrict__ matTB,
    const float* __restrict__ Wa, int Nc, int rowOff, int S,
    float* __restrict__ wsumP, float* __restrict__ esumP)
{
  const float CE = 2.885390082f;   // 2*log2(e)
  int b = blockIdx.x, tid = threadIdx.x;
  int groups = Nc / G;
  int per = groups * 4;
  int p = b / per; int rem = b - p*per; int g = rem >> 2, ch = rem & 3;
  int row0 = rowOff + g*G;
  const float* proj = p ? projB : projA;
  const float* matT = p ? matTB : matTA;

  __shared__ __align__(16) float shp[G*256];
  __shared__ __align__(16) float swa[256];
  __shared__ __align__(16) float spart[G*256];
  __shared__ __align__(16) float se[G*128];

  for (int j = tid; j < G*256; j += 256){
    int row = row0 + (j>>8), jj = j&255;
    const float* base = php + (((size_t)p*511 + row)*4)*256 + jj;
    float v = base[0];
    if (S == 4) v += base[256] + base[512] + base[768];
    shp[j] = v * CE;
  }
  swa[tid] = Wa[tid];
  __syncthreads();

  int ml = tid & 127, dh = tid >> 7;
  int m = ch*128 + ml;
  float part[G];
  #pragma unroll
  for (int r = 0; r < G; ++r) part[r] = 0.f;
  if (m < 511){
    const float4* pr  = (const float4*)(proj + (size_t)m*256 + dh*128);
    const float4* wa4 = (const float4*)(swa + dh*128);
    #pragma unroll 4
    for (int k = 0; k < 32; ++k){
      float4 pv = pr[k], wv = wa4[k];
      float p0 = pv.x*CE, p1 = pv.y*CE, p2 = pv.z*CE, p3 = pv.w*CE;
      int dbase = dh*128 + k*4;
      #pragma unroll
      for (int r = 0; r < G; ++r){
        const float* hr = shp + r*256 + dbase;
        part[r] += wv.x*rcpf(1.f + exp2f(hr[0]+p0))
                 + wv.y*rcpf(1.f + exp2f(hr[1]+p1))
                 + wv.z*rcpf(1.f + exp2f(hr[2]+p2))
                 + wv.w*rcpf(1.f + exp2f(hr[3]+p3));
      }
    }
  }
  #pragma unroll
  for (int r = 0; r < G; ++r) spart[r*256 + tid] = part[r];
  __syncthreads();
  if (tid < 128){
    #pragma unroll
    for (int r = 0; r < G; ++r){
      float s = spart[r*256 + ml] + spart[r*256 + 128 + ml];
      se[r*128 + ml] = (ch*128 + ml < 511) ? __expf(-2.f*s) : 0.f;
    }
  }
  __syncthreads();
  {
    const float4* mt = (const float4*)(matT + (size_t)tid*MT + ch*128);
    float acc[G];
    #pragma unroll
    for (int r = 0; r < G; ++r) acc[r] = 0.f;
    #pragma unroll 4
    for (int k = 0; k < 32; ++k){
      float4 mv = mt[k];
      #pragma unroll
      for (int r = 0; r < G; ++r){
        float4 ev = ((const float4*)(se + r*128))[k];
        acc[r] += mv.x*ev.x + mv.y*ev.y + mv.z*ev.z + mv.w*ev.w;
      }
    }
    #pragma unroll
    for (int r = 0; r < G; ++r)
      wsumP[(((size_t)p*511 + row0 + r)*4 + ch)*256 + tid] = acc[r];
  }
  if (tid < G){
    float s = 0.f;
    const float* sr = se + tid*128;
    for (int k = 0; k < 128; ++k) s += sr[k];
    esumP[((size_t)p*511 + row0 + tid)*4 + ch] = s;
  }
}

// ---------------------------------------------------------------------------
// CD spine, batched (verified baseline) — all levels.
// ---------------------------------------------------------------------------
template<int R>
__global__ void __launch_bounds__(512) k_cd1(
    const unsigned short* __restrict__ W16, const float* __restrict__ b_iouh,
    const float* __restrict__ b_fh,
    int Nc, int offPrev, int offCur,
    const float* __restrict__ colA, const float* __restrict__ colB,
    const float* __restrict__ wsumP, const float* __restrict__ esumP,
    const float* __restrict__ childHC, const float* __restrict__ childHD,
    const float* __restrict__ childCC, const float* __restrict__ childCD_,
    float* __restrict__ cmatC, float* __restrict__ cmatD,
    float* __restrict__ hstageC, float* __restrict__ hstageD,
    float* __restrict__ php)
{
  int bid = blockIdx.x, tid = threadIdx.x;
  int s = bid & 3, g2 = bid >> 2;
  int groups = Nc / R;
  int p = (g2 >= groups) ? 1 : 0;
  int n0 = (g2 - p*groups) * R;
  const float* colv   = p ? colB : colA;
  const float* childH = p ? childHD : childHC;
  const float* childC = p ? childCD_ : childCC;
  float* cmat   = p ? cmatD : cmatC;
  float* hstage = p ? hstageD : hstageC;

  __shared__ __align__(16) float hs0[R][256], hs1[R][256], hss[R][256];
  __shared__ float sP[10][R][64];
  __shared__ __align__(16) float sh[R][64];
  __shared__ float sHP[2][256];

  for (int it = tid; it < R*2*256; it += 512){
    int j = it & 255, ch = (it>>8)&1, r = it>>9;
    int rc = offPrev + 2*(n0+r) + ch;
    const float* wp = wsumP + (((size_t)p*511 + rc)*4)*256;
    const float* ep = esumP + ((size_t)p*511 + rc)*4;
    float w = wp[j] + wp[256+j] + wp[512+j] + wp[768+j];
    float esum = ep[0]+ep[1]+ep[2]+ep[3];
    float hatt = colv[j] - w*rcpf(esum) + childH[(size_t)rc*256 + j];
    if (ch) hs1[r][j] = hatt; else hs0[r][j] = hatt;
  }
  __syncthreads();
  for (int it = tid; it < R*256; it += 512){
    int j = it & 255, r = it>>8;
    hss[r][j] = hs0[r][j] + hs1[r][j];
  }
  __syncthreads();

  {
    int role = tid >> 6, cl = tid & 63;
    int gate = role & 3, dh = role >> 2;
    int col = s*64 + cl;
    if (gate < 3){
      const unsigned short* wrow = W16 + (size_t)(col + gate*256)*256;
      const uint4* w4 = (const uint4*)(wrow + dh*128);
      float acc[R];
      #pragma unroll
      for (int r = 0; r < R; ++r) acc[r] = 0.f;
      #pragma unroll 4
      for (int k = 0; k < 16; ++k){
        uint4 w = w4[k];
        #pragma unroll
        for (int r = 0; r < R; ++r)
          acc[r] += dot8b(w, (const float4*)(&hss[r][dh*128 + k*8]));
      }
      #pragma unroll
      for (int r = 0; r < R; ++r) sP[gate*2+dh][r][cl] = acc[r];
    } else {
      const uint4* w4 = (const uint4*)(W16 + B16_FH + (size_t)col*256 + dh*128);
      float a0[R], a1[R];
      #pragma unroll
      for (int r = 0; r < R; ++r){ a0[r] = 0.f; a1[r] = 0.f; }
      #pragma unroll 4
      for (int k = 0; k < 16; ++k){
        uint4 w = w4[k];
        #pragma unroll
        for (int r = 0; r < R; ++r){
          a0[r] += dot8b(w, (const float4*)(&hs0[r][dh*128 + k*8]));
          a1[r] += dot8b(w, (const float4*)(&hs1[r][dh*128 + k*8]));
        }
      }
      #pragma unroll
      for (int r = 0; r < R; ++r){ sP[6+dh][r][cl] = a0[r]; sP[8+dh][r][cl] = a1[r]; }
    }
  }
  __syncthreads();

  if (tid < 64*R){
    int r = tid >> 6, cl = tid & 63;
    int t = s*64 + cl;
    int n = n0 + r;
    float ai  = sP[0][r][cl] + sP[1][r][cl];
    float ao  = sP[2][r][cl] + sP[3][r][cl];
    float au  = sP[4][r][cl] + sP[5][r][cl];
    float af0 = sP[6][r][cl] + sP[7][r][cl];
    float af1 = sP[8][r][cl] + sP[9][r][cl];
    float c0 = childC[(size_t)(offPrev+2*n)*256 + t];
    float c1 = childC[(size_t)(offPrev+2*n+1)*256 + t];
    float i_ = sigmf(ai + b_iouh[t]);
    float o_ = sigmf(ao + b_iouh[256+t]);
    float u_ = tanhfast(au + b_iouh[512+t]);
    float bf = b_fh[t];
    float c = i_*u_ + sigmf(af0+bf)*c0 + sigmf(af1+bf)*c1;
    float h = o_*tanhfast(c);
    cmat[(size_t)(offCur+n)*256 + t] = c;
    hstage[(size_t)(offCur+n)*256 + t] = h;
    sh[r][cl] = h;
  }
  __syncthreads();

  {
    int j = tid & 255, eh = tid >> 8;
    const uint4* w1 = (const uint4*)(W16 + B16_W1 + (size_t)j*256 + s*64 + eh*32);
    uint4 wv[4];
    #pragma unroll
    for (int k = 0; k < 4; ++k) wv[k] = w1[k];
    float aacc[R];
    #pragma unroll
    for (int r = 0; r < R; ++r){
      float a = 0.f;
      #pragma unroll
      for (int k = 0; k < 4; ++k)
        a += dot8b(wv[k], (const float4*)(&sh[r][eh*32 + k*8]));
      aacc[r] = a;
    }
    #pragma unroll
    for (int r = 0; r < R; ++r){
      sHP[eh][j] = aacc[r];
      __syncthreads();
      if (tid < 256){
        int row = offCur + n0 + r;
        php[(((size_t)p*511 + row)*4 + s)*256 + tid] = sHP[0][tid] + sHP[1][tid];
      }
      __syncthreads();
    }
  }
}

// ---------------------------------------------------------------------------
// Head (verified baseline).
// ---------------------------------------------------------------------------
__global__ void __launch_bounds__(256) k_head(
    const float* __restrict__ W_wh, const float* __restrict__ b_wh,
    const float* __restrict__ W_wp, const float* __restrict__ b_wp,
    const float* __restrict__ matA, const float* __restrict__ matB,
    const float* __restrict__ colA, const float* __restrict__ colB,
    const float* __restrict__ wsumP, const float* __restrict__ esumP,
    const float* __restrict__ hstageC, const float* __restrict__ hstageD,
    float* __restrict__ out)
{
  __shared__ __align__(16) float v[512];
  __shared__ float og[128], lg[5];
  int t = threadIdx.x;
  {
    const float* wpC = wsumP + (((size_t)0*511 + 510)*4)*256;
    const float* epC = esumP + ((size_t)0*511 + 510)*4;
    float wC = wpC[t] + wpC[256+t] + wpC[512+t] + wpC[768+t];
    float eC = epC[0]+epC[1]+epC[2]+epC[3];
    float hCf = colA[t] - wC*rcpf(eC) + hstageC[(size_t)510*256 + t];
    const float* wpD = wsumP + (((size_t)1*511 + 510)*4)*256;
    const float* epD = esumP + ((size_t)1*511 + 510)*4;
    float wD = wpD[t] + wpD[256+t] + wpD[512+t] + wpD[768+t];
    float eD = epD[0]+epD[1]+epD[2]+epD[3];
    float hDf = colB[t] - wD*rcpf(eD) + hstageD[(size_t)510*256 + t];
    float lh = tanhfast(matA[(size_t)510*256 + t] + hDf);
    float rh = tanhfast(hCf + matB[(size_t)510*256 + t]);
    v[t] = lh*rh;
    v[256+t] = fabsf(lh - rh);
  }
  __syncthreads();
  if (t < 128){
    const float4* w = (const float4*)(W_wh + (size_t)t*512);
    const float4* vv = (const float4*)v;
    float a = b_wh[t];
    #pragma unroll 4
    for (int k = 0; k < 128; ++k){
      float4 wv = w[k], x = vv[k];
      a += wv.x*x.x + wv.y*x.y + wv.z*x.z + wv.w*x.w;
    }
    og[t] = sigmf(a);
  }
  __syncthreads();
  if (t < 5){
    const float* wp = W_wp + (size_t)t*128;
    float a = b_wp[t];
    for (int j = 0; j < 128; ++j) a += og[j]*wp[j];
    lg[t] = a;
  }
  __syncthreads();
  if (t == 0){
    float M = -1e30f;
    for (int c = 0; c < 5; ++c) M = fmaxf(M, lg[c]);
    float S = 0.f;
    for (int c = 0; c < 5; ++c) S += __expf(lg[c] - M);
    float L = logf(S);
    for (int c = 0; c < 5; ++c) out[c] = lg[c] - M - L;
  }
}

extern "C" void kernel_launch(void* const* d_in, const int* in_sizes, int n_in,
                              void* d_out, int out_size, void* d_ws, size_t ws_size,
                              hipStream_t stream)
{
  const int*   l_idx   = (const int*)  d_in[0];
  const int*   r_idx   = (const int*)  d_in[1];
  const float* emb     = (const float*)d_in[2];
  const float* W_ioux  = (const float*)d_in[3];
  const float* b_ioux  = (const float*)d_in[4];
  const float* W_iouh  = (const float*)d_in[5];
  const float* b_iouh  = (const float*)d_in[6];
  // d_in[7]=W_fx, d_in[8]=b_fx unused by the forward
  const float* W_fh    = (const float*)d_in[9];
  const float* b_fh    = (const float*)d_in[10];
  const float* Wa      = (const float*)d_in[11];
  const float* W_attnh = (const float*)d_in[12];
  const float* b_attnh = (const float*)d_in[13];
  const float* W_wh    = (const float*)d_in[14];
  const float* b_wh    = (const float*)d_in[15];
  const float* W_wp    = (const float*)d_in[16];
  const float* b_wp    = (const float*)d_in[17];

  float* ws = (float*)d_ws;
  float* cmatA   = ws;               float* cmatB   = cmatA + RC;
  float* cmatC   = cmatB + RC;       float* cmatD   = cmatC + RC;
  float* matA    = cmatD + RC;       float* matB    = matA + RC;
  float* hstageC = matB + RC;        float* hstageD = hstageC + RC;
  float* projA   = hstageD + RC;     float* projB   = projA + RC;
  float* matTA   = projB + RC;       float* matTB   = matTA + 256*MT;
  float* colA    = matTB + 256*MT;   float* colB    = colA + 256;
  float* wsumP   = colB + 256;            // 2*511*4*256
  float* esumP   = wsumP + 2*511*4*256;   // 2*511*4
  float* php     = esumP + 2*511*4;       // 2*511*4*256
  unsigned short* W16 = (unsigned short*)(php + 2*511*4*256);  // 327,680 ushorts

  static const int offs[9] = {0, 256, 384, 448, 480, 496, 504, 508, 510};

  k_init<<<288, 768, 0, stream>>>(l_idx, r_idx, emb, W_ioux, b_ioux, b_iouh,
                                  W_iouh, W_fh, W_attnh,
                                  cmatA, matA, cmatB, matB, colA, colB,
                                  (unsigned*)W16);
  for (int i = 1; i <= 8; ++i){
    int Nc = 256 >> i;
    int oP = offs[i-1], oC = offs[i];
    if (Nc >= 128)
      k_levelAB<4><<<(2*Nc/4)*4, 512, 0, stream>>>(W16, b_iouh, b_fh, Nc, oP, oC,
                                                   cmatA, matA, cmatB, matB);
    else if (Nc >= 64)
      k_levelAB<2><<<(2*Nc/2)*4, 512, 0, stream>>>(W16, b_iouh, b_fh, Nc, oP, oC,
                                                   cmatA, matA, cmatB, matB);
    else
      k_levelAB<1><<<(2*Nc)*4, 512, 0, stream>>>(W16, b_iouh, b_fh, Nc, oP, oC,
                                                 cmatA, matA, cmatB, matB);
  }
  k_mid<<<448, 256, 0, stream>>>(W_attnh, b_attnh, matA, matB,
                                 projA, projB, colA, colB, matTA, matTB, php);
  k_scores_t<4><<<2*(256/4)*4, 256, 0, stream>>>(php, projA, projB,
                                                 matTA, matTB, Wa, 256, 0, 1,
                                                 wsumP, esumP);
  for (int i = 1; i <= 8; ++i){
    int Nc = 256 >> i;
    int oP = offs[i-1], oC = offs[i];
    const float* childHC = (i == 1) ? matB  : hstageC;  // C's h0 = pass-B rows
    const float* childHD = (i == 1) ? matA  : hstageD;
    const float* childCC = (i == 1) ? cmatB : cmatC;
    const float* childCD = (i == 1) ? cmatA : cmatD;
    if (Nc >= 128)
      k_cd1<4><<<(2*Nc/4)*4, 512, 0, stream>>>(W16, b_iouh, b_fh, Nc, oP, oC,
                                               colA, colB, wsumP, esumP,
                                               childHC, childHD, childCC, childCD,
                                               cmatC, cmatD, hstageC, hstageD, php);
    else if (Nc >= 64)
      k_cd1<2><<<(2*Nc/2)*4, 512, 0, stream>>>(W16, b_iouh, b_fh, Nc, oP, oC,
                                               colA, colB, wsumP, esumP,
                                               childHC, childHD, childCC, childCD,
                                               cmatC, cmatD, hstageC, hstageD, php);
    else
      k_cd1<1><<<(2*Nc)*4, 512, 0, stream>>>(W16, b_iouh, b_fh, Nc, oP, oC,
                                             colA, colB, wsumP, esumP,
                                             childHC, childHD, childCC, childCD,
                                             cmatC, cmatD, hstageC, hstageD, php);
    if (Nc >= 4)
      k_scores_t<4><<<2*(Nc/4)*4, 256, 0, stream>>>(php, projA, projB,
                                                    matTA, matTB, Wa, Nc, offs[i], 4,
                                                    wsumP, esumP);
    else if (Nc == 2)
      k_scores_t<2><<<2*(Nc/2)*4, 256, 0, stream>>>(php, projA, projB,
                                                    matTA, matTB, Wa, Nc, offs[i], 4,
                                                    wsumP, esumP);
    else
      k_scores_t<1><<<2*Nc*4, 256, 0, stream>>>(php, projA, projB,
                                                matTA, matTB, Wa, Nc, offs[i], 4,
                                                wsumP, esumP);
  }
  k_head<<<1, 256, 0, stream>>>(W_wh, b_wh, W_wp, b_wp, matA, matB,
                                colA, colB, wsumP, esumP, hstageC, hstageD,
                                (float*)d_out);
}